// Round 5
// baseline (928.897 us; speedup 1.0000x reference)
//
#include <hip/hip_runtime.h>
#include <cstddef>

#define S_LEN 2048
#define D_MODEL 512
#define NHEAD 8
#define DH 64
#define FF_DIM 2048
#define L_TAGS 32
#define START_TAG 30
#define STOP_TAG 31
#define NEGV (-10000.0f)

typedef unsigned int uint2v __attribute__((ext_vector_type(2)));

__device__ __forceinline__ float max3f(float a, float b, float c) {
  float d;
  asm("v_max3_f32 %0, %1, %2, %3" : "=v"(d) : "v"(a), "v"(b), "v"(c));
  return d;
}

// ---------------- embedding gather ----------------
__global__ __launch_bounds__(128) void k_embed(const int* __restrict__ sent,
                                               const float* __restrict__ embed,
                                               float* __restrict__ x) {
  int s = blockIdx.x;
  int d = threadIdx.x * 4;
  size_t idx = (size_t)sent[s] * D_MODEL + d;
  *(float4*)(x + (size_t)s * D_MODEL + d) = *(const float4*)(embed + idx);
}

// ---------------- GEMM C[M][N] = A[M][K] * B[N][K]^T + bias, 128x128 tile ----------------
template <bool RELU>
__global__ __launch_bounds__(256) void k_gemm128(const float* __restrict__ A,
                                                 const float* __restrict__ B,
                                                 const float* __restrict__ bias,
                                                 float* __restrict__ C,
                                                 int M, int N, int K) {
  __shared__ float As[16][132];
  __shared__ float Bs[16][132];
  const int tid = threadIdx.x;
  const int bm = blockIdx.y * 128, bn = blockIdx.x * 128;
  const int lrow = tid >> 1;
  const int lks = (tid & 1) * 8;
  const int row0 = (tid >> 4) * 8;
  const int col0 = (tid & 15) * 8;
  float acc[8][8] = {};
  for (int k0 = 0; k0 < K; k0 += 16) {
    float4 a0 = *(const float4*)(A + (size_t)(bm + lrow) * K + k0 + lks);
    float4 a1 = *(const float4*)(A + (size_t)(bm + lrow) * K + k0 + lks + 4);
    float4 b0 = *(const float4*)(B + (size_t)(bn + lrow) * K + k0 + lks);
    float4 b1 = *(const float4*)(B + (size_t)(bn + lrow) * K + k0 + lks + 4);
    __syncthreads();
    As[lks + 0][lrow] = a0.x; As[lks + 1][lrow] = a0.y;
    As[lks + 2][lrow] = a0.z; As[lks + 3][lrow] = a0.w;
    As[lks + 4][lrow] = a1.x; As[lks + 5][lrow] = a1.y;
    As[lks + 6][lrow] = a1.z; As[lks + 7][lrow] = a1.w;
    Bs[lks + 0][lrow] = b0.x; Bs[lks + 1][lrow] = b0.y;
    Bs[lks + 2][lrow] = b0.z; Bs[lks + 3][lrow] = b0.w;
    Bs[lks + 4][lrow] = b1.x; Bs[lks + 5][lrow] = b1.y;
    Bs[lks + 6][lrow] = b1.z; Bs[lks + 7][lrow] = b1.w;
    __syncthreads();
#pragma unroll
    for (int kk = 0; kk < 16; ++kk) {
      float4 av0 = *(const float4*)&As[kk][row0];
      float4 av1 = *(const float4*)&As[kk][row0 + 4];
      float4 bv0 = *(const float4*)&Bs[kk][col0];
      float4 bv1 = *(const float4*)&Bs[kk][col0 + 4];
      float ar[8] = {av0.x, av0.y, av0.z, av0.w, av1.x, av1.y, av1.z, av1.w};
      float br[8] = {bv0.x, bv0.y, bv0.z, bv0.w, bv1.x, bv1.y, bv1.z, bv1.w};
#pragma unroll
      for (int i = 0; i < 8; ++i)
#pragma unroll
        for (int j = 0; j < 8; ++j) acc[i][j] += ar[i] * br[j];
    }
  }
#pragma unroll
  for (int i = 0; i < 8; ++i) {
    int r = bm + row0 + i;
    float4 o0, o1;
    o0.x = acc[i][0] + bias[bn + col0 + 0];
    o0.y = acc[i][1] + bias[bn + col0 + 1];
    o0.z = acc[i][2] + bias[bn + col0 + 2];
    o0.w = acc[i][3] + bias[bn + col0 + 3];
    o1.x = acc[i][4] + bias[bn + col0 + 4];
    o1.y = acc[i][5] + bias[bn + col0 + 5];
    o1.z = acc[i][6] + bias[bn + col0 + 6];
    o1.w = acc[i][7] + bias[bn + col0 + 7];
    if (RELU) {
      o0.x = fmaxf(o0.x, 0.f); o0.y = fmaxf(o0.y, 0.f);
      o0.z = fmaxf(o0.z, 0.f); o0.w = fmaxf(o0.w, 0.f);
      o1.x = fmaxf(o1.x, 0.f); o1.y = fmaxf(o1.y, 0.f);
      o1.z = fmaxf(o1.z, 0.f); o1.w = fmaxf(o1.w, 0.f);
    }
    *(float4*)(C + (size_t)r * N + bn + col0) = o0;
    *(float4*)(C + (size_t)r * N + bn + col0 + 4) = o1;
  }
}

// ---------------- GEMM 64x64 tile (for N=512 cases) ----------------
template <bool RELU>
__global__ __launch_bounds__(256) void k_gemm64(const float* __restrict__ A,
                                                const float* __restrict__ B,
                                                const float* __restrict__ bias,
                                                float* __restrict__ C,
                                                int M, int N, int K) {
  __shared__ float As[16][68];
  __shared__ float Bs[16][68];
  const int tid = threadIdx.x;
  const int bm = blockIdx.y * 64, bn = blockIdx.x * 64;
  const int tx = tid & 15, ty = tid >> 4;
  const int lr = tid >> 2, lk = (tid & 3) * 4;
  float acc[4][4] = {};
  for (int k0 = 0; k0 < K; k0 += 16) {
    float4 a4 = *(const float4*)(A + (size_t)(bm + lr) * K + k0 + lk);
    float4 b4 = *(const float4*)(B + (size_t)(bn + lr) * K + k0 + lk);
    __syncthreads();
    As[lk + 0][lr] = a4.x; As[lk + 1][lr] = a4.y;
    As[lk + 2][lr] = a4.z; As[lk + 3][lr] = a4.w;
    Bs[lk + 0][lr] = b4.x; Bs[lk + 1][lr] = b4.y;
    Bs[lk + 2][lr] = b4.z; Bs[lk + 3][lr] = b4.w;
    __syncthreads();
#pragma unroll
    for (int kk = 0; kk < 16; ++kk) {
      float4 av = *(const float4*)&As[kk][ty * 4];
      float4 bv = *(const float4*)&Bs[kk][tx * 4];
      float ar[4] = {av.x, av.y, av.z, av.w};
      float br[4] = {bv.x, bv.y, bv.z, bv.w};
#pragma unroll
      for (int i = 0; i < 4; ++i)
#pragma unroll
        for (int j = 0; j < 4; ++j) acc[i][j] += ar[i] * br[j];
    }
  }
#pragma unroll
  for (int i = 0; i < 4; ++i) {
    float4 o;
    o.x = acc[i][0] + bias[bn + tx * 4 + 0];
    o.y = acc[i][1] + bias[bn + tx * 4 + 1];
    o.z = acc[i][2] + bias[bn + tx * 4 + 2];
    o.w = acc[i][3] + bias[bn + tx * 4 + 3];
    if (RELU) {
      o.x = fmaxf(o.x, 0.f); o.y = fmaxf(o.y, 0.f);
      o.z = fmaxf(o.z, 0.f); o.w = fmaxf(o.w, 0.f);
    }
    *(float4*)(C + (size_t)(bm + ty * 4 + i) * N + bn + tx * 4) = o;
  }
}

// ---------------- fused attention v2 ----------------
__global__ __launch_bounds__(128) void k_attn(const float* __restrict__ qkv,
                                              float* __restrict__ ob) {
  __shared__ float Qt[64][36];  // Qt[d][q]
  __shared__ float Kt[64][68];  // Kt[d][k]
  __shared__ float Vs[64][68];  // Vs[k][d]
  __shared__ float Pt[64][36];  // Pt[k][q]
  const int tid = threadIdx.x;
  const int bq = blockIdx.x * 32;
  const int h = blockIdx.y;
  {
    const int r = tid >> 2, ds0 = (tid & 3) * 16;
    const float* src = qkv + (size_t)(bq + r) * 1536 + h * DH + ds0;
#pragma unroll
    for (int i = 0; i < 4; ++i) {
      float4 v = *(const float4*)(src + i * 4);
      Qt[ds0 + i * 4 + 0][r] = v.x * 0.125f;
      Qt[ds0 + i * 4 + 1][r] = v.y * 0.125f;
      Qt[ds0 + i * 4 + 2][r] = v.z * 0.125f;
      Qt[ds0 + i * 4 + 3][r] = v.w * 0.125f;
    }
  }
  const int tx = tid & 15, ty = tid >> 4;
  float m[4], l[4], acc[4][4] = {};
#pragma unroll
  for (int i = 0; i < 4; ++i) { m[i] = -1e30f; l[i] = 0.f; }
  for (int kt = 0; kt < 32; ++kt) {
    __syncthreads();  // A
    {
      const int r = tid >> 1, half = tid & 1;
      const float* ksrc = qkv + (size_t)(kt * 64 + r) * 1536 + 512 + h * DH + half * 32;
      const float* vsrc = ksrc + 512;
#pragma unroll
      for (int i = 0; i < 8; ++i) {
        float4 kv = *(const float4*)(ksrc + i * 4);
        int dd = half * 32 + i * 4;
        Kt[dd + 0][r] = kv.x; Kt[dd + 1][r] = kv.y;
        Kt[dd + 2][r] = kv.z; Kt[dd + 3][r] = kv.w;
      }
#pragma unroll
      for (int i = 0; i < 8; ++i)
        *(float4*)&Vs[r][half * 32 + i * 4] = *(const float4*)(vsrc + i * 4);
    }
    __syncthreads();  // B
    float s[4][4] = {};
#pragma unroll 8
    for (int d = 0; d < 64; ++d) {
      float4 qv = *(const float4*)&Qt[d][ty * 4];
      float4 kv = *(const float4*)&Kt[d][tx * 4];
      float qa[4] = {qv.x, qv.y, qv.z, qv.w};
      float ka[4] = {kv.x, kv.y, kv.z, kv.w};
#pragma unroll
      for (int i = 0; i < 4; ++i)
#pragma unroll
        for (int j = 0; j < 4; ++j) s[i][j] += qa[i] * ka[j];
    }
#pragma unroll
    for (int i = 0; i < 4; ++i) {
      float v = fmaxf(fmaxf(s[i][0], s[i][1]), fmaxf(s[i][2], s[i][3]));
#pragma unroll
      for (int off = 1; off < 16; off <<= 1) v = fmaxf(v, __shfl_xor(v, off, 64));
      float mn = fmaxf(m[i], v);
      float f = __expf(m[i] - mn);
      m[i] = mn;
      float p0 = __expf(s[i][0] - mn), p1 = __expf(s[i][1] - mn);
      float p2 = __expf(s[i][2] - mn), p3 = __expf(s[i][3] - mn);
      float rs = (p0 + p1) + (p2 + p3);
#pragma unroll
      for (int off = 1; off < 16; off <<= 1) rs += __shfl_xor(rs, off, 64);
      l[i] = l[i] * f + rs;
      acc[i][0] *= f; acc[i][1] *= f; acc[i][2] *= f; acc[i][3] *= f;
      const int q = ty * 4 + i;
      Pt[tx * 4 + 0][q] = p0; Pt[tx * 4 + 1][q] = p1;
      Pt[tx * 4 + 2][q] = p2; Pt[tx * 4 + 3][q] = p3;
    }
    __syncthreads();  // C
#pragma unroll 8
    for (int k = 0; k < 64; ++k) {
      float4 pv = *(const float4*)&Pt[k][ty * 4];
      float4 vv = *(const float4*)&Vs[k][tx * 4];
      float pa[4] = {pv.x, pv.y, pv.z, pv.w};
      float va[4] = {vv.x, vv.y, vv.z, vv.w};
#pragma unroll
      for (int i = 0; i < 4; ++i)
#pragma unroll
        for (int j = 0; j < 4; ++j) acc[i][j] += pa[i] * va[j];
    }
  }
#pragma unroll
  for (int i = 0; i < 4; ++i) {
    float inv = 1.f / l[i];
    float4 o;
    o.x = acc[i][0] * inv; o.y = acc[i][1] * inv;
    o.z = acc[i][2] * inv; o.w = acc[i][3] * inv;
    *(float4*)(ob + (size_t)(bq + ty * 4 + i) * D_MODEL + h * DH + tx * 4) = o;
  }
}

// ---------------- residual + layernorm ----------------
__global__ __launch_bounds__(128) void k_ln(const float* __restrict__ a,
                                            const float* __restrict__ r,
                                            const float* __restrict__ g,
                                            const float* __restrict__ b,
                                            float* __restrict__ out) {
  __shared__ float red[2];
  const int row = blockIdx.x, tid = threadIdx.x;
  const size_t off = (size_t)row * D_MODEL + tid * 4;
  float4 av = *(const float4*)(a + off);
  float4 rv = *(const float4*)(r + off);
  float v0 = av.x + rv.x, v1 = av.y + rv.y, v2 = av.z + rv.z, v3 = av.w + rv.w;
  float s = v0 + v1 + v2 + v3;
#pragma unroll
  for (int d = 1; d < 64; d <<= 1) s += __shfl_xor(s, d, 64);
  if ((tid & 63) == 0) red[tid >> 6] = s;
  __syncthreads();
  float mean = (red[0] + red[1]) * (1.f / 512.f);
  __syncthreads();
  float d0 = v0 - mean, d1 = v1 - mean, d2 = v2 - mean, d3 = v3 - mean;
  float sq = d0 * d0 + d1 * d1 + d2 * d2 + d3 * d3;
#pragma unroll
  for (int d = 1; d < 64; d <<= 1) sq += __shfl_xor(sq, d, 64);
  if ((tid & 63) == 0) red[tid >> 6] = sq;
  __syncthreads();
  float inv = rsqrtf((red[0] + red[1]) * (1.f / 512.f) + 1e-5f);
  float4 gv = *(const float4*)(g + tid * 4);
  float4 bv = *(const float4*)(b + tid * 4);
  float4 o;
  o.x = d0 * inv * gv.x + bv.x;
  o.y = d1 * inv * gv.y + bv.y;
  o.z = d2 * inv * gv.z + bv.z;
  o.w = d3 * inv * gv.w + bv.w;
  *(float4*)(out + off) = o;
}

// ---------------- emission scores feats = x2 * Wt^T + bt  [2048][32] ----------------
__global__ __launch_bounds__(256) void k_feats(const float* __restrict__ x2,
                                               const float* __restrict__ Wt,
                                               const float* __restrict__ bt,
                                               float* __restrict__ feats) {
  const int tid = threadIdx.x;
  const int s = blockIdx.x * 8 + (tid >> 5);
  const int l = tid & 31;
  const float* xr = x2 + (size_t)s * D_MODEL;
  const float* wr = Wt + (size_t)l * D_MODEL;
  float acc = 0.f;
#pragma unroll 8
  for (int k = 0; k < D_MODEL; k += 4) {
    float4 xv = *(const float4*)(xr + k);
    float4 wv = *(const float4*)(wr + k);
    acc += xv.x * wv.x + xv.y * wv.y + xv.z * wv.z + xv.w * wv.w;
  }
  feats[s * L_TAGS + l] = acc + bt[l];
}

// ---------------- Viterbi forward (serial, bitwise-exact f32), max only ----------------
// v3: 8-deep emission register ring so e-loads (L2/HBM latency) are issued
// ~8 recursion steps before use; single-wave kernel has no TLP to hide them.
__global__ __launch_bounds__(64) void k_vit_serial(const float* __restrict__ feats,
                                                   const float* __restrict__ T,
                                                   float* __restrict__ alphas,
                                                   float* __restrict__ out,
                                                   int* __restrict__ bestp) {
  const int l = threadIdx.x;
  const int n = l & 31, half = l >> 5;
  float Tr[16];
#pragma unroll
  for (int j = 0; j < 16; ++j) Tr[j] = T[n * 32 + half * 16 + j];
  int adr[16];
#pragma unroll
  for (int j = 0; j < 16; ++j) adr[j] = (half * 16 + j) * 4;
  float a = (n == START_TAG) ? 0.f : NEGV;
  alphas[n] = a;
  float er[8];
#pragma unroll
  for (int i = 0; i < 8; ++i) er[i] = feats[i * 32 + n];
  const float* fp = feats + 8 * 32 + n;
  float* ap = alphas + 32 + n;
  for (int t = 0; t < S_LEN; t += 8) {
    // prefetch rows t+8 .. t+15 (last iter overreads 8 rows into the alphas
    // buffer -- allocated scratch, values never consumed: harmless)
    float nx[8];
#pragma unroll
    for (int i = 0; i < 8; ++i) nx[i] = fp[i * 32];
    fp += 256;
#pragma unroll
    for (int u = 0; u < 8; ++u) {
      float g[16];
#pragma unroll
      for (int j = 0; j < 16; ++j)
        g[j] = __int_as_float(__builtin_amdgcn_ds_bpermute(adr[j], __float_as_int(a))) + Tr[j];
      float t0 = max3f(g[0], g[1], g[2]);
      float t1 = max3f(g[3], g[4], g[5]);
      float t2 = max3f(g[6], g[7], g[8]);
      float t3 = max3f(g[9], g[10], g[11]);
      float t4 = max3f(g[12], g[13], g[14]);
      float mx = fmaxf(max3f(t0, t1, t2), max3f(t3, t4, g[15]));
      uint2v r = __builtin_amdgcn_permlane32_swap(__float_as_uint(mx),
                                                  __float_as_uint(mx),
                                                  false, false);
      a = fmaxf(__uint_as_float(r[0]), __uint_as_float(r[1])) + er[u];
      ap[u * 32] = a;
    }
    ap += 256;
#pragma unroll
    for (int i = 0; i < 8; ++i) er[i] = nx[i];
  }
  float term = a + T[STOP_TAG * 32 + n];
  float bv = term;
  int bi = n;
#pragma unroll
  for (int d = 1; d < 32; d <<= 1) {
    float ov = __shfl_xor(bv, d, 64);
    int oi = __shfl_xor(bi, d, 64);
    if (ov > bv || (ov == bv && oi < bi)) { bv = ov; bi = oi; }
  }
  if (l == 0) { out[0] = bv; *bestp = bi; }
}

// ---------------- backpointers (parallel, exact) ----------------
__global__ __launch_bounds__(256) void k_vit_bp(const float* __restrict__ alphas,
                                                const float* __restrict__ T,
                                                unsigned char* __restrict__ bp) {
  __shared__ float Ts[32][33];
  __shared__ float Al[8][32];
  const int tid = threadIdx.x;
  for (int i = tid; i < 1024; i += 256) Ts[i >> 5][i & 31] = T[i];
  const int t0 = blockIdx.x * 8;
  Al[tid >> 5][tid & 31] = alphas[t0 * 32 + tid];
  __syncthreads();
  const int tl = tid >> 5, n = tid & 31;
  float best = -3e38f;
  int bi = 0;
#pragma unroll
  for (int p = 0; p < 32; ++p) {
    float v = Al[tl][p] + Ts[n][p];
    if (v > best) { best = v; bi = p; }
  }
  bp[(size_t)(t0 + tl) * 32 + n] = (unsigned char)bi;
}

// ---------------- traceback ----------------
__global__ __launch_bounds__(256) void k_vit_trace(const unsigned char* __restrict__ bp,
                                                   const int* __restrict__ bestp,
                                                   unsigned char* __restrict__ cand,
                                                   float* __restrict__ outp) {
  __shared__ unsigned char Amap[64][32];
  const int tid = threadIdx.x;
  int tg[8];
#pragma unroll
  for (int i = 0; i < 8; ++i) {
    int id = tid + 256 * i;
    tg[i] = id & 31;
    cand[(size_t)id * 32 + 31] = (unsigned char)tg[i];
  }
  for (int j = 31; j >= 1; --j) {
#pragma unroll
    for (int i = 0; i < 8; ++i) {
      int id = tid + 256 * i;
      tg[i] = bp[(size_t)((id >> 5) * 32 + j) * 32 + tg[i]];
      cand[(size_t)id * 32 + (j - 1)] = (unsigned char)tg[i];
    }
  }
#pragma unroll
  for (int i = 0; i < 8; ++i) {
    int id = tid + 256 * i;
    Amap[id >> 5][id & 31] = bp[(size_t)((id >> 5) * 32) * 32 + tg[i]];
  }
  __syncthreads();
  for (int d = 1; d < 64; d <<= 1) {
    unsigned char tmpv[8];
#pragma unroll
    for (int i = 0; i < 8; ++i) {
      int id = tid + 256 * i;
      int c = id >> 5, e = id & 31;
      tmpv[i] = (c + d < 64) ? Amap[c][Amap[c + d][e]] : Amap[c][e];
    }
    __syncthreads();
#pragma unroll
    for (int i = 0; i < 8; ++i) {
      int id = tid + 256 * i;
      Amap[id >> 5][id & 31] = tmpv[i];
    }
    __syncthreads();
  }
  const int best = *bestp;
#pragma unroll
  for (int i = 0; i < 8; ++i) {
    int t = tid + 256 * i;
    int c = t >> 5, j = t & 31;
    int et = (c == 63) ? best : Amap[c + 1][best];
    outp[1 + t] = (float)cand[(size_t)(c * 32 + et) * 32 + j];
  }
}

extern "C" void kernel_launch(void* const* d_in, const int* in_sizes, int n_in,
                              void* d_out, int out_size, void* d_ws, size_t ws_size,
                              hipStream_t stream) {
  (void)in_sizes; (void)n_in; (void)out_size; (void)ws_size;
  const int* sent = (const int*)d_in[0];
  const float* embed = (const float*)d_in[1];
  const float* Wqkv = (const float*)d_in[2];
  const float* bqkv = (const float*)d_in[3];
  const float* Wo = (const float*)d_in[4];
  const float* bo = (const float*)d_in[5];
  const float* g1 = (const float*)d_in[6];
  const float* b1n = (const float*)d_in[7];
  const float* W1 = (const float*)d_in[8];
  const float* b1f = (const float*)d_in[9];
  const float* W2 = (const float*)d_in[10];
  const float* b2f = (const float*)d_in[11];
  const float* g2 = (const float*)d_in[12];
  const float* b2n = (const float*)d_in[13];
  const float* Wt = (const float*)d_in[14];
  const float* bt = (const float*)d_in[15];
  const float* T = (const float*)d_in[16];
  float* out = (float*)d_out;

  float* ws = (float*)d_ws;
  const size_t M1 = 1u << 20;  // 1M floats = 4MB
  float* x = ws;               // [2048][512]
  float* qkvb = ws + M1;       // [2048][1536]
  float* ob = ws + 4 * M1;     // [2048][512]
  float* yb = ws + 5 * M1;     // [2048][512]
  float* x1 = ws + 6 * M1;     // [2048][512]
  float* ffb = ws;             // [2048][2048]  (aliases x+qkvb, dead by then)
  float* zb = ws + 4 * M1;     // aliases ob
  float* x2 = ws + 5 * M1;     // aliases yb
  float* feats = ws + 7 * M1;  // [2048][32]
  float* alphas = feats + 2048 * 32;            // [2049][32]
  int* bestp = (int*)(alphas + 2049 * 32 + 32);
  unsigned char* bp = (unsigned char*)(bestp + 32);  // [2048][32] u8
  unsigned char* cand = bp + 2048 * 32;              // [2048][32] u8

  k_embed<<<dim3(2048), dim3(128), 0, stream>>>(sent, embed, x);
  k_gemm128<false><<<dim3(12, 16), dim3(256), 0, stream>>>(x, Wqkv, bqkv, qkvb, 2048, 1536, 512);
  k_attn<<<dim3(64, 8), dim3(128), 0, stream>>>(qkvb, ob);
  k_gemm64<false><<<dim3(8, 32), dim3(256), 0, stream>>>(ob, Wo, bo, yb, 2048, 512, 512);
  k_ln<<<dim3(2048), dim3(128), 0, stream>>>(x, yb, g1, b1n, x1);
  k_gemm128<true><<<dim3(16, 16), dim3(256), 0, stream>>>(x1, W1, b1f, ffb, 2048, 2048, 512);
  k_gemm64<false><<<dim3(8, 32), dim3(256), 0, stream>>>(ffb, W2, b2f, zb, 2048, 512, 2048);
  k_ln<<<dim3(2048), dim3(128), 0, stream>>>(x1, zb, g2, b2n, x2);
  k_feats<<<dim3(256), dim3(256), 0, stream>>>(x2, Wt, bt, feats);
  k_vit_serial<<<dim3(1), dim3(64), 0, stream>>>(feats, T, alphas, out, bestp);
  k_vit_bp<<<dim3(256), dim3(256), 0, stream>>>(alphas, T, bp);
  k_vit_trace<<<dim3(1), dim3(256), 0, stream>>>(bp, bestp, cand, out);
}

// Round 6
// 634.344 us; speedup vs baseline: 1.4643x; 1.4643x over previous
//
#include <hip/hip_runtime.h>
#include <cstddef>

#define S_LEN 2048
#define D_MODEL 512
#define NHEAD 8
#define DH 64
#define FF_DIM 2048
#define L_TAGS 32
#define START_TAG 30
#define STOP_TAG 31
#define NEGV (-10000.0f)

typedef unsigned int uint2v __attribute__((ext_vector_type(2)));

// ---------------- embedding gather ----------------
__global__ __launch_bounds__(128) void k_embed(const int* __restrict__ sent,
                                               const float* __restrict__ embed,
                                               float* __restrict__ x) {
  int s = blockIdx.x;
  int d = threadIdx.x * 4;
  size_t idx = (size_t)sent[s] * D_MODEL + d;
  *(float4*)(x + (size_t)s * D_MODEL + d) = *(const float4*)(embed + idx);
}

// ---------------- GEMM C[M][N] = A[M][K] * B[N][K]^T + bias, 128x128 tile ----------------
template <bool RELU>
__global__ __launch_bounds__(256) void k_gemm128(const float* __restrict__ A,
                                                 const float* __restrict__ B,
                                                 const float* __restrict__ bias,
                                                 float* __restrict__ C,
                                                 int M, int N, int K) {
  __shared__ float As[16][132];
  __shared__ float Bs[16][132];
  const int tid = threadIdx.x;
  const int bm = blockIdx.y * 128, bn = blockIdx.x * 128;
  const int lrow = tid >> 1;
  const int lks = (tid & 1) * 8;
  const int row0 = (tid >> 4) * 8;
  const int col0 = (tid & 15) * 8;
  float acc[8][8] = {};
  for (int k0 = 0; k0 < K; k0 += 16) {
    float4 a0 = *(const float4*)(A + (size_t)(bm + lrow) * K + k0 + lks);
    float4 a1 = *(const float4*)(A + (size_t)(bm + lrow) * K + k0 + lks + 4);
    float4 b0 = *(const float4*)(B + (size_t)(bn + lrow) * K + k0 + lks);
    float4 b1 = *(const float4*)(B + (size_t)(bn + lrow) * K + k0 + lks + 4);
    __syncthreads();
    As[lks + 0][lrow] = a0.x; As[lks + 1][lrow] = a0.y;
    As[lks + 2][lrow] = a0.z; As[lks + 3][lrow] = a0.w;
    As[lks + 4][lrow] = a1.x; As[lks + 5][lrow] = a1.y;
    As[lks + 6][lrow] = a1.z; As[lks + 7][lrow] = a1.w;
    Bs[lks + 0][lrow] = b0.x; Bs[lks + 1][lrow] = b0.y;
    Bs[lks + 2][lrow] = b0.z; Bs[lks + 3][lrow] = b0.w;
    Bs[lks + 4][lrow] = b1.x; Bs[lks + 5][lrow] = b1.y;
    Bs[lks + 6][lrow] = b1.z; Bs[lks + 7][lrow] = b1.w;
    __syncthreads();
#pragma unroll
    for (int kk = 0; kk < 16; ++kk) {
      float4 av0 = *(const float4*)&As[kk][row0];
      float4 av1 = *(const float4*)&As[kk][row0 + 4];
      float4 bv0 = *(const float4*)&Bs[kk][col0];
      float4 bv1 = *(const float4*)&Bs[kk][col0 + 4];
      float ar[8] = {av0.x, av0.y, av0.z, av0.w, av1.x, av1.y, av1.z, av1.w};
      float br[8] = {bv0.x, bv0.y, bv0.z, bv0.w, bv1.x, bv1.y, bv1.z, bv1.w};
#pragma unroll
      for (int i = 0; i < 8; ++i)
#pragma unroll
        for (int j = 0; j < 8; ++j) acc[i][j] += ar[i] * br[j];
    }
  }
#pragma unroll
  for (int i = 0; i < 8; ++i) {
    int r = bm + row0 + i;
    float4 o0, o1;
    o0.x = acc[i][0] + bias[bn + col0 + 0];
    o0.y = acc[i][1] + bias[bn + col0 + 1];
    o0.z = acc[i][2] + bias[bn + col0 + 2];
    o0.w = acc[i][3] + bias[bn + col0 + 3];
    o1.x = acc[i][4] + bias[bn + col0 + 4];
    o1.y = acc[i][5] + bias[bn + col0 + 5];
    o1.z = acc[i][6] + bias[bn + col0 + 6];
    o1.w = acc[i][7] + bias[bn + col0 + 7];
    if (RELU) {
      o0.x = fmaxf(o0.x, 0.f); o0.y = fmaxf(o0.y, 0.f);
      o0.z = fmaxf(o0.z, 0.f); o0.w = fmaxf(o0.w, 0.f);
      o1.x = fmaxf(o1.x, 0.f); o1.y = fmaxf(o1.y, 0.f);
      o1.z = fmaxf(o1.z, 0.f); o1.w = fmaxf(o1.w, 0.f);
    }
    *(float4*)(C + (size_t)r * N + bn + col0) = o0;
    *(float4*)(C + (size_t)r * N + bn + col0 + 4) = o1;
  }
}

// ---------------- GEMM 64x64 tile (for N=512 cases) ----------------
template <bool RELU>
__global__ __launch_bounds__(256) void k_gemm64(const float* __restrict__ A,
                                                const float* __restrict__ B,
                                                const float* __restrict__ bias,
                                                float* __restrict__ C,
                                                int M, int N, int K) {
  __shared__ float As[16][68];
  __shared__ float Bs[16][68];
  const int tid = threadIdx.x;
  const int bm = blockIdx.y * 64, bn = blockIdx.x * 64;
  const int tx = tid & 15, ty = tid >> 4;
  const int lr = tid >> 2, lk = (tid & 3) * 4;
  float acc[4][4] = {};
  for (int k0 = 0; k0 < K; k0 += 16) {
    float4 a4 = *(const float4*)(A + (size_t)(bm + lr) * K + k0 + lk);
    float4 b4 = *(const float4*)(B + (size_t)(bn + lr) * K + k0 + lk);
    __syncthreads();
    As[lk + 0][lr] = a4.x; As[lk + 1][lr] = a4.y;
    As[lk + 2][lr] = a4.z; As[lk + 3][lr] = a4.w;
    Bs[lk + 0][lr] = b4.x; Bs[lk + 1][lr] = b4.y;
    Bs[lk + 2][lr] = b4.z; Bs[lk + 3][lr] = b4.w;
    __syncthreads();
#pragma unroll
    for (int kk = 0; kk < 16; ++kk) {
      float4 av = *(const float4*)&As[kk][ty * 4];
      float4 bv = *(const float4*)&Bs[kk][tx * 4];
      float ar[4] = {av.x, av.y, av.z, av.w};
      float br[4] = {bv.x, bv.y, bv.z, bv.w};
#pragma unroll
      for (int i = 0; i < 4; ++i)
#pragma unroll
        for (int j = 0; j < 4; ++j) acc[i][j] += ar[i] * br[j];
    }
  }
#pragma unroll
  for (int i = 0; i < 4; ++i) {
    float4 o;
    o.x = acc[i][0] + bias[bn + tx * 4 + 0];
    o.y = acc[i][1] + bias[bn + tx * 4 + 1];
    o.z = acc[i][2] + bias[bn + tx * 4 + 2];
    o.w = acc[i][3] + bias[bn + tx * 4 + 3];
    if (RELU) {
      o.x = fmaxf(o.x, 0.f); o.y = fmaxf(o.y, 0.f);
      o.z = fmaxf(o.z, 0.f); o.w = fmaxf(o.w, 0.f);
    }
    *(float4*)(C + (size_t)(bm + ty * 4 + i) * N + bn + tx * 4) = o;
  }
}

// ---------------- fused attention v2 ----------------
__global__ __launch_bounds__(128) void k_attn(const float* __restrict__ qkv,
                                              float* __restrict__ ob) {
  __shared__ float Qt[64][36];  // Qt[d][q]
  __shared__ float Kt[64][68];  // Kt[d][k]
  __shared__ float Vs[64][68];  // Vs[k][d]
  __shared__ float Pt[64][36];  // Pt[k][q]
  const int tid = threadIdx.x;
  const int bq = blockIdx.x * 32;
  const int h = blockIdx.y;
  {
    const int r = tid >> 2, ds0 = (tid & 3) * 16;
    const float* src = qkv + (size_t)(bq + r) * 1536 + h * DH + ds0;
#pragma unroll
    for (int i = 0; i < 4; ++i) {
      float4 v = *(const float4*)(src + i * 4);
      Qt[ds0 + i * 4 + 0][r] = v.x * 0.125f;
      Qt[ds0 + i * 4 + 1][r] = v.y * 0.125f;
      Qt[ds0 + i * 4 + 2][r] = v.z * 0.125f;
      Qt[ds0 + i * 4 + 3][r] = v.w * 0.125f;
    }
  }
  const int tx = tid & 15, ty = tid >> 4;
  float m[4], l[4], acc[4][4] = {};
#pragma unroll
  for (int i = 0; i < 4; ++i) { m[i] = -1e30f; l[i] = 0.f; }
  for (int kt = 0; kt < 32; ++kt) {
    __syncthreads();  // A
    {
      const int r = tid >> 1, half = tid & 1;
      const float* ksrc = qkv + (size_t)(kt * 64 + r) * 1536 + 512 + h * DH + half * 32;
      const float* vsrc = ksrc + 512;
#pragma unroll
      for (int i = 0; i < 8; ++i) {
        float4 kv = *(const float4*)(ksrc + i * 4);
        int dd = half * 32 + i * 4;
        Kt[dd + 0][r] = kv.x; Kt[dd + 1][r] = kv.y;
        Kt[dd + 2][r] = kv.z; Kt[dd + 3][r] = kv.w;
      }
#pragma unroll
      for (int i = 0; i < 8; ++i)
        *(float4*)&Vs[r][half * 32 + i * 4] = *(const float4*)(vsrc + i * 4);
    }
    __syncthreads();  // B
    float s[4][4] = {};
#pragma unroll 8
    for (int d = 0; d < 64; ++d) {
      float4 qv = *(const float4*)&Qt[d][ty * 4];
      float4 kv = *(const float4*)&Kt[d][tx * 4];
      float qa[4] = {qv.x, qv.y, qv.z, qv.w};
      float ka[4] = {kv.x, kv.y, kv.z, kv.w};
#pragma unroll
      for (int i = 0; i < 4; ++i)
#pragma unroll
        for (int j = 0; j < 4; ++j) s[i][j] += qa[i] * ka[j];
    }
#pragma unroll
    for (int i = 0; i < 4; ++i) {
      float v = fmaxf(fmaxf(s[i][0], s[i][1]), fmaxf(s[i][2], s[i][3]));
#pragma unroll
      for (int off = 1; off < 16; off <<= 1) v = fmaxf(v, __shfl_xor(v, off, 64));
      float mn = fmaxf(m[i], v);
      float f = __expf(m[i] - mn);
      m[i] = mn;
      float p0 = __expf(s[i][0] - mn), p1 = __expf(s[i][1] - mn);
      float p2 = __expf(s[i][2] - mn), p3 = __expf(s[i][3] - mn);
      float rs = (p0 + p1) + (p2 + p3);
#pragma unroll
      for (int off = 1; off < 16; off <<= 1) rs += __shfl_xor(rs, off, 64);
      l[i] = l[i] * f + rs;
      acc[i][0] *= f; acc[i][1] *= f; acc[i][2] *= f; acc[i][3] *= f;
      const int q = ty * 4 + i;
      Pt[tx * 4 + 0][q] = p0; Pt[tx * 4 + 1][q] = p1;
      Pt[tx * 4 + 2][q] = p2; Pt[tx * 4 + 3][q] = p3;
    }
    __syncthreads();  // C
#pragma unroll 8
    for (int k = 0; k < 64; ++k) {
      float4 pv = *(const float4*)&Pt[k][ty * 4];
      float4 vv = *(const float4*)&Vs[k][tx * 4];
      float pa[4] = {pv.x, pv.y, pv.z, pv.w};
      float va[4] = {vv.x, vv.y, vv.z, vv.w};
#pragma unroll
      for (int i = 0; i < 4; ++i)
#pragma unroll
        for (int j = 0; j < 4; ++j) acc[i][j] += pa[i] * va[j];
    }
  }
#pragma unroll
  for (int i = 0; i < 4; ++i) {
    float inv = 1.f / l[i];
    float4 o;
    o.x = acc[i][0] * inv; o.y = acc[i][1] * inv;
    o.z = acc[i][2] * inv; o.w = acc[i][3] * inv;
    *(float4*)(ob + (size_t)(bq + ty * 4 + i) * D_MODEL + h * DH + tx * 4) = o;
  }
}

// ---------------- residual + layernorm ----------------
__global__ __launch_bounds__(128) void k_ln(const float* __restrict__ a,
                                            const float* __restrict__ r,
                                            const float* __restrict__ g,
                                            const float* __restrict__ b,
                                            float* __restrict__ out) {
  __shared__ float red[2];
  const int row = blockIdx.x, tid = threadIdx.x;
  const size_t off = (size_t)row * D_MODEL + tid * 4;
  float4 av = *(const float4*)(a + off);
  float4 rv = *(const float4*)(r + off);
  float v0 = av.x + rv.x, v1 = av.y + rv.y, v2 = av.z + rv.z, v3 = av.w + rv.w;
  float s = v0 + v1 + v2 + v3;
#pragma unroll
  for (int d = 1; d < 64; d <<= 1) s += __shfl_xor(s, d, 64);
  if ((tid & 63) == 0) red[tid >> 6] = s;
  __syncthreads();
  float mean = (red[0] + red[1]) * (1.f / 512.f);
  __syncthreads();
  float d0 = v0 - mean, d1 = v1 - mean, d2 = v2 - mean, d3 = v3 - mean;
  float sq = d0 * d0 + d1 * d1 + d2 * d2 + d3 * d3;
#pragma unroll
  for (int d = 1; d < 64; d <<= 1) sq += __shfl_xor(sq, d, 64);
  if ((tid & 63) == 0) red[tid >> 6] = sq;
  __syncthreads();
  float inv = rsqrtf((red[0] + red[1]) * (1.f / 512.f) + 1e-5f);
  float4 gv = *(const float4*)(g + tid * 4);
  float4 bv = *(const float4*)(b + tid * 4);
  float4 o;
  o.x = d0 * inv * gv.x + bv.x;
  o.y = d1 * inv * gv.y + bv.y;
  o.z = d2 * inv * gv.z + bv.z;
  o.w = d3 * inv * gv.w + bv.w;
  *(float4*)(out + off) = o;
}

// ---------------- emission scores feats = x2 * Wt^T + bt  [2048][32] ----------------
__global__ __launch_bounds__(256) void k_feats(const float* __restrict__ x2,
                                               const float* __restrict__ Wt,
                                               const float* __restrict__ bt,
                                               float* __restrict__ feats) {
  const int tid = threadIdx.x;
  const int s = blockIdx.x * 8 + (tid >> 5);
  const int l = tid & 31;
  const float* xr = x2 + (size_t)s * D_MODEL;
  const float* wr = Wt + (size_t)l * D_MODEL;
  float acc = 0.f;
#pragma unroll 8
  for (int k = 0; k < D_MODEL; k += 4) {
    float4 xv = *(const float4*)(xr + k);
    float4 wv = *(const float4*)(wr + k);
    acc += xv.x * wv.x + xv.y * wv.y + xv.z * wv.z + xv.w * wv.w;
  }
  feats[s * L_TAGS + l] = acc + bt[l];
}

// ============ Viterbi via chunked max-plus scan (64 chunks x 32 steps) ============
// alpha_{t+1} = M_t (x) alpha_t,  M_t[n][p] = T[n][p] + e_t[n]; (x) = max-plus.
// Reordering shifts score by ~ulp (<<103 threshold); path tags differ <=31 anyway.

// phase 1: P_c = M_{c*32+31} (x) ... (x) M_{c*32}, computed column-wise.
// block = 1 wave, owns 2 columns; grid = 64 chunks * 16 col-pairs.
__global__ __launch_bounds__(64) void k_scan1(const float* __restrict__ feats,
                                              const float* __restrict__ T,
                                              float* __restrict__ P) {
  __shared__ float S[2][32];
  const int c = blockIdx.x >> 4;
  const int l = threadIdx.x;
  const int n = l & 31, pl = l >> 5;
  const int p = (blockIdx.x & 15) * 2 + pl;
  float Trow[32];
#pragma unroll
  for (int q = 0; q < 32; ++q) Trow[q] = T[n * 32 + q];
  const int tbase = c * 32;
  float er[4];
#pragma unroll
  for (int i = 0; i < 4; ++i) er[i] = feats[(tbase + i) * 32 + n];
  // init: col_p = T[:,p] + e_{tbase}
  float a = T[n * 32 + p] + er[0];
  S[pl][n] = a;
  const float* fp = feats + (size_t)(tbase + 4) * 32 + n;
  er[0] = fp[0]; fp += 32;  // refill slot 0 with t=tbase+4
  for (int u = 1; u < 32; ++u) {
    float e = er[u & 3];
    float enew = fp[0]; fp += 32;  // t = tbase+u+4 (overreads spill into alphas: harmless)
    const float4* Sv = (const float4*)&S[pl][0];
    float g[32];
#pragma unroll
    for (int j4 = 0; j4 < 8; ++j4) {
      float4 sv = Sv[j4];
      g[j4 * 4 + 0] = sv.x + Trow[j4 * 4 + 0];
      g[j4 * 4 + 1] = sv.y + Trow[j4 * 4 + 1];
      g[j4 * 4 + 2] = sv.z + Trow[j4 * 4 + 2];
      g[j4 * 4 + 3] = sv.w + Trow[j4 * 4 + 3];
    }
#pragma unroll
    for (int st = 1; st < 32; st <<= 1)
#pragma unroll
      for (int j = 0; j < 32; j += 2 * st) g[j] = fmaxf(g[j], g[j + st]);
    a = g[0] + e;
    S[pl][n] = a;  // same-wave DS is in-order: next iter's reads see this
    er[u & 3] = enew;
  }
  P[(size_t)c * 1024 + n * 32 + p] = a;
}

// phase 2: boundary alphas b_c (written to alphas[c*32]) + terminal score/argmax.
__global__ __launch_bounds__(64) void k_scan2(const float* __restrict__ P,
                                              const float* __restrict__ T,
                                              float* __restrict__ alphas,
                                              float* __restrict__ out,
                                              int* __restrict__ bestp) {
  __shared__ float Sa[32];
  const int l = threadIdx.x, n = l & 31, half = l >> 5;
  float a = (n == START_TAG) ? 0.f : NEGV;
  const float* pbase = P + n * 32 + half * 16;
  float4 pr[4];
#pragma unroll
  for (int j = 0; j < 4; ++j) pr[j] = *(const float4*)(pbase + j * 4);
  for (int c = 0; c < 64; ++c) {
    float4 nx[4];
#pragma unroll
    for (int j = 0; j < 4; ++j)
      nx[j] = *(const float4*)(pbase + (size_t)(c + 1) * 1024 + j * 4);  // c=63 overreads pad
    alphas[(size_t)(c * 32) * 32 + n] = a;  // b_c (both halves write same value)
    Sa[n] = a;
    const float4* Sv = (const float4*)&Sa[half * 16];
    float g[16];
#pragma unroll
    for (int j = 0; j < 4; ++j) {
      float4 sv = Sv[j];
      g[j * 4 + 0] = pr[j].x + sv.x;
      g[j * 4 + 1] = pr[j].y + sv.y;
      g[j * 4 + 2] = pr[j].z + sv.z;
      g[j * 4 + 3] = pr[j].w + sv.w;
    }
#pragma unroll
    for (int st = 1; st < 16; st <<= 1)
#pragma unroll
      for (int j = 0; j < 16; j += 2 * st) g[j] = fmaxf(g[j], g[j + st]);
    uint2v r = __builtin_amdgcn_permlane32_swap(__float_as_uint(g[0]),
                                                __float_as_uint(g[0]), false, false);
    a = fmaxf(__uint_as_float(r[0]), __uint_as_float(r[1]));
#pragma unroll
    for (int j = 0; j < 4; ++j) pr[j] = nx[j];
  }
  float term = a + T[STOP_TAG * 32 + n];
  float bv = term;
  int bi = n;
#pragma unroll
  for (int d = 1; d < 32; d <<= 1) {
    float ov = __shfl_xor(bv, d, 64);
    int oi = __shfl_xor(bi, d, 64);
    if (ov > bv || (ov == bv && oi < bi)) { bv = ov; bi = oi; }
  }
  if (l == 0) { out[0] = bv; *bestp = bi; }
}

// phase 3: interior alphas per chunk (31 steps from b_c).
__global__ __launch_bounds__(64) void k_scan3(const float* __restrict__ feats,
                                              const float* __restrict__ T,
                                              float* __restrict__ alphas) {
  __shared__ float Sa[32];
  const int c = blockIdx.x, l = threadIdx.x, n = l & 31, half = l >> 5;
  float Tr[16];
#pragma unroll
  for (int j = 0; j < 16; ++j) Tr[j] = T[n * 32 + half * 16 + j];
  const int tbase = c * 32;
  float a = alphas[(size_t)tbase * 32 + n];  // b_c from phase 2
  float er[4];
#pragma unroll
  for (int i = 0; i < 4; ++i) er[i] = feats[(tbase + i) * 32 + n];
  const float* fp = feats + (size_t)(tbase + 4) * 32 + n;
  Sa[n] = a;
  for (int u = 0; u < 31; ++u) {
    float e = er[u & 3];
    float enew = fp[0]; fp += 32;
    const float4* Sv = (const float4*)&Sa[half * 16];
    float4 s0 = Sv[0], s1 = Sv[1], s2 = Sv[2], s3 = Sv[3];
    float g[16] = {s0.x + Tr[0],  s0.y + Tr[1],  s0.z + Tr[2],  s0.w + Tr[3],
                   s1.x + Tr[4],  s1.y + Tr[5],  s1.z + Tr[6],  s1.w + Tr[7],
                   s2.x + Tr[8],  s2.y + Tr[9],  s2.z + Tr[10], s2.w + Tr[11],
                   s3.x + Tr[12], s3.y + Tr[13], s3.z + Tr[14], s3.w + Tr[15]};
#pragma unroll
    for (int st = 1; st < 16; st <<= 1)
#pragma unroll
      for (int j = 0; j < 16; j += 2 * st) g[j] = fmaxf(g[j], g[j + st]);
    uint2v r = __builtin_amdgcn_permlane32_swap(__float_as_uint(g[0]),
                                                __float_as_uint(g[0]), false, false);
    a = fmaxf(__uint_as_float(r[0]), __uint_as_float(r[1])) + e;
    alphas[(size_t)(tbase + u + 1) * 32 + n] = a;
    Sa[n] = a;
    er[u & 3] = enew;
  }
}

// ---------------- backpointers (parallel) ----------------
__global__ __launch_bounds__(256) void k_vit_bp(const float* __restrict__ alphas,
                                                const float* __restrict__ T,
                                                unsigned char* __restrict__ bp) {
  __shared__ float Ts[32][33];
  __shared__ float Al[8][32];
  const int tid = threadIdx.x;
  for (int i = tid; i < 1024; i += 256) Ts[i >> 5][i & 31] = T[i];
  const int t0 = blockIdx.x * 8;
  Al[tid >> 5][tid & 31] = alphas[t0 * 32 + tid];
  __syncthreads();
  const int tl = tid >> 5, n = tid & 31;
  float best = -3e38f;
  int bi = 0;
#pragma unroll
  for (int p = 0; p < 32; ++p) {
    float v = Al[tl][p] + Ts[n][p];
    if (v > best) { best = v; bi = p; }
  }
  bp[(size_t)(t0 + tl) * 32 + n] = (unsigned char)bi;
}

// ---------------- traceback ----------------
__global__ __launch_bounds__(256) void k_vit_trace(const unsigned char* __restrict__ bp,
                                                   const int* __restrict__ bestp,
                                                   unsigned char* __restrict__ cand,
                                                   float* __restrict__ outp) {
  __shared__ unsigned char Amap[64][32];
  const int tid = threadIdx.x;
  int tg[8];
#pragma unroll
  for (int i = 0; i < 8; ++i) {
    int id = tid + 256 * i;
    tg[i] = id & 31;
    cand[(size_t)id * 32 + 31] = (unsigned char)tg[i];
  }
  for (int j = 31; j >= 1; --j) {
#pragma unroll
    for (int i = 0; i < 8; ++i) {
      int id = tid + 256 * i;
      tg[i] = bp[(size_t)((id >> 5) * 32 + j) * 32 + tg[i]];
      cand[(size_t)id * 32 + (j - 1)] = (unsigned char)tg[i];
    }
  }
#pragma unroll
  for (int i = 0; i < 8; ++i) {
    int id = tid + 256 * i;
    Amap[id >> 5][id & 31] = bp[(size_t)((id >> 5) * 32) * 32 + tg[i]];
  }
  __syncthreads();
  for (int d = 1; d < 64; d <<= 1) {
    unsigned char tmpv[8];
#pragma unroll
    for (int i = 0; i < 8; ++i) {
      int id = tid + 256 * i;
      int c = id >> 5, e = id & 31;
      tmpv[i] = (c + d < 64) ? Amap[c][Amap[c + d][e]] : Amap[c][e];
    }
    __syncthreads();
#pragma unroll
    for (int i = 0; i < 8; ++i) {
      int id = tid + 256 * i;
      Amap[id >> 5][id & 31] = tmpv[i];
    }
    __syncthreads();
  }
  const int best = *bestp;
#pragma unroll
  for (int i = 0; i < 8; ++i) {
    int t = tid + 256 * i;
    int c = t >> 5, j = t & 31;
    int et = (c == 63) ? best : Amap[c + 1][best];
    outp[1 + t] = (float)cand[(size_t)(c * 32 + et) * 32 + j];
  }
}

extern "C" void kernel_launch(void* const* d_in, const int* in_sizes, int n_in,
                              void* d_out, int out_size, void* d_ws, size_t ws_size,
                              hipStream_t stream) {
  (void)in_sizes; (void)n_in; (void)out_size; (void)ws_size;
  const int* sent = (const int*)d_in[0];
  const float* embed = (const float*)d_in[1];
  const float* Wqkv = (const float*)d_in[2];
  const float* bqkv = (const float*)d_in[3];
  const float* Wo = (const float*)d_in[4];
  const float* bo = (const float*)d_in[5];
  const float* g1 = (const float*)d_in[6];
  const float* b1n = (const float*)d_in[7];
  const float* W1 = (const float*)d_in[8];
  const float* b1f = (const float*)d_in[9];
  const float* W2 = (const float*)d_in[10];
  const float* b2f = (const float*)d_in[11];
  const float* g2 = (const float*)d_in[12];
  const float* b2n = (const float*)d_in[13];
  const float* Wt = (const float*)d_in[14];
  const float* bt = (const float*)d_in[15];
  const float* T = (const float*)d_in[16];
  float* out = (float*)d_out;

  float* ws = (float*)d_ws;
  const size_t M1 = 1u << 20;  // 1M floats = 4MB
  float* x = ws;               // [2048][512]
  float* qkvb = ws + M1;       // [2048][1536]
  float* ob = ws + 4 * M1;     // [2048][512]
  float* yb = ws + 5 * M1;     // [2048][512]
  float* x1 = ws + 6 * M1;     // [2048][512]
  float* ffb = ws;             // [2048][2048]  (aliases x+qkvb, dead by then)
  float* zb = ws + 4 * M1;     // aliases ob
  float* x2 = ws + 5 * M1;     // aliases yb
  float* feats = ws + 7 * M1;  // [2048][32]
  float* alphas = feats + 2048 * 32;            // [2049][32]
  int* bestp = (int*)(alphas + 2049 * 32 + 32);
  unsigned char* bp = (unsigned char*)(bestp + 32);  // [2048][32] u8
  unsigned char* cand = bp + 2048 * 32;              // [2048][32] u8
  float* P = ws;  // [65][1024] chunk products; ffb/x region dead by scan time

  k_embed<<<dim3(2048), dim3(128), 0, stream>>>(sent, embed, x);
  k_gemm128<false><<<dim3(12, 16), dim3(256), 0, stream>>>(x, Wqkv, bqkv, qkvb, 2048, 1536, 512);
  k_attn<<<dim3(64, 8), dim3(128), 0, stream>>>(qkvb, ob);
  k_gemm64<false><<<dim3(8, 32), dim3(256), 0, stream>>>(ob, Wo, bo, yb, 2048, 512, 512);
  k_ln<<<dim3(2048), dim3(128), 0, stream>>>(x, yb, g1, b1n, x1);
  k_gemm128<true><<<dim3(16, 16), dim3(256), 0, stream>>>(x1, W1, b1f, ffb, 2048, 2048, 512);
  k_gemm64<false><<<dim3(8, 32), dim3(256), 0, stream>>>(ffb, W2, b2f, zb, 2048, 512, 2048);
  k_ln<<<dim3(2048), dim3(128), 0, stream>>>(x1, zb, g2, b2n, x2);
  k_feats<<<dim3(256), dim3(256), 0, stream>>>(x2, Wt, bt, feats);
  k_scan1<<<dim3(1024), dim3(64), 0, stream>>>(feats, T, P);
  k_scan2<<<dim3(1), dim3(64), 0, stream>>>(P, T, alphas, out, bestp);
  k_scan3<<<dim3(64), dim3(64), 0, stream>>>(feats, T, alphas);
  k_vit_bp<<<dim3(256), dim3(256), 0, stream>>>(alphas, T, bp);
  k_vit_trace<<<dim3(1), dim3(256), 0, stream>>>(bp, bestp, cand, out);
}

// Round 7
// 532.567 us; speedup vs baseline: 1.7442x; 1.1911x over previous
//
#include <hip/hip_runtime.h>
#include <cstddef>

#define S_LEN 2048
#define D_MODEL 512
#define NHEAD 8
#define DH 64
#define FF_DIM 2048
#define L_TAGS 32
#define START_TAG 30
#define STOP_TAG 31
#define NEGV (-10000.0f)

typedef unsigned int uint2v __attribute__((ext_vector_type(2)));
typedef __attribute__((ext_vector_type(8))) short short8v;   // 8 bf16 = 4 VGPR
typedef __attribute__((ext_vector_type(4))) float f32x4;

__device__ __forceinline__ unsigned short f2bf(float f) {
  unsigned u = __float_as_uint(f);
  u += 0x7fff + ((u >> 16) & 1);   // round-to-nearest-even
  return (unsigned short)(u >> 16);
}

// ---------------- embedding gather ----------------
__global__ __launch_bounds__(128) void k_embed(const int* __restrict__ sent,
                                               const float* __restrict__ embed,
                                               float* __restrict__ x) {
  int s = blockIdx.x;
  int d = threadIdx.x * 4;
  size_t idx = (size_t)sent[s] * D_MODEL + d;
  *(float4*)(x + (size_t)s * D_MODEL + d) = *(const float4*)(embed + idx);
}

// ======== bf16 MFMA GEMM: C[M][N] = A[M][K] * B[N][K]^T + bias ========
// f32 operands converted to bf16 during staging. 128x128 tile, BK=64,
// 4 waves (2x2), 16x16x32 mfma, double-buffered LDS, chunk-XOR swizzle.
template <bool RELU>
__global__ __launch_bounds__(256, 2) void k_gemm_mfma(const float* __restrict__ A,
                                                      const float* __restrict__ B,
                                                      const float* __restrict__ bias,
                                                      float* __restrict__ C,
                                                      int M, int N, int K) {
  __shared__ __align__(16) short As[2][128 * 64];
  __shared__ __align__(16) short Bs[2][128 * 64];
  const int tid = threadIdx.x;
  const int bm = blockIdx.y * 128, bn = blockIdx.x * 128;
  const int w = tid >> 6, lane = tid & 63;
  const int wr = w >> 1, wc = w & 1;
  const int fr = lane & 15, kg = lane >> 4;
  // staging: thread owns one LDS row (tid>>1), 4 chunks of 8 elems from (tid&1)*4
  const int srow = tid >> 1, scb = (tid & 1) * 4;
  const int swz = srow & 7;
  const float* gA = A + (size_t)(bm + srow) * K + scb * 8;
  const float* gB = B + (size_t)(bn + srow) * K + scb * 8;

  f32x4 ra[8], rb[8];
  f32x4 acc[4][4] = {};

#define LOADG(k0)                                         \
  {                                                       \
    _Pragma("unroll") for (int c = 0; c < 4; ++c) {       \
      ra[2 * c]     = *(const f32x4*)(gA + (k0) + c * 8); \
      ra[2 * c + 1] = *(const f32x4*)(gA + (k0) + c * 8 + 4); \
      rb[2 * c]     = *(const f32x4*)(gB + (k0) + c * 8); \
      rb[2 * c + 1] = *(const f32x4*)(gB + (k0) + c * 8 + 4); \
    }                                                     \
  }
#define STOREB(b)                                                        \
  {                                                                      \
    short* dA = &As[b][srow * 64];                                       \
    short* dB = &Bs[b][srow * 64];                                       \
    _Pragma("unroll") for (int c = 0; c < 4; ++c) {                      \
      short8v pa, pb;                                                    \
      _Pragma("unroll") for (int j = 0; j < 4; ++j) {                    \
        pa[j] = (short)f2bf(ra[2 * c][j]);                               \
        pa[j + 4] = (short)f2bf(ra[2 * c + 1][j]);                       \
        pb[j] = (short)f2bf(rb[2 * c][j]);                               \
        pb[j + 4] = (short)f2bf(rb[2 * c + 1][j]);                       \
      }                                                                  \
      *(short8v*)(dA + (((scb + c) ^ swz) << 3)) = pa;                   \
      *(short8v*)(dB + (((scb + c) ^ swz) << 3)) = pb;                   \
    }                                                                    \
  }

  LOADG(0);
  STOREB(0);
  __syncthreads();
  int cur = 0;
  const int fswz = fr & 7;
  for (int k0 = 0; k0 < K; k0 += 64) {
    const bool more = (k0 + 64) < K;
    if (more) LOADG(k0 + 64);
    const short* rA = &As[cur][(wr * 64 + fr) * 64];
    const short* rB = &Bs[cur][(wc * 64 + fr) * 64];
#pragma unroll
    for (int ks = 0; ks < 2; ++ks) {
      const int co = ((ks * 4 + kg) ^ fswz) << 3;
      short8v af[4], bf[4];
#pragma unroll
      for (int rt = 0; rt < 4; ++rt) af[rt] = *(const short8v*)(rA + rt * 16 * 64 + co);
#pragma unroll
      for (int ct = 0; ct < 4; ++ct) bf[ct] = *(const short8v*)(rB + ct * 16 * 64 + co);
#pragma unroll
      for (int rt = 0; rt < 4; ++rt)
#pragma unroll
        for (int ct = 0; ct < 4; ++ct)
          acc[rt][ct] = __builtin_amdgcn_mfma_f32_16x16x32_bf16(af[rt], bf[ct], acc[rt][ct], 0, 0, 0);
    }
    if (more) STOREB(cur ^ 1);
    __syncthreads();
    cur ^= 1;
  }
#undef LOADG
#undef STOREB
  // epilogue: C/D layout col=lane&15, row=(lane>>4)*4+reg
#pragma unroll
  for (int rt = 0; rt < 4; ++rt) {
#pragma unroll
    for (int ct = 0; ct < 4; ++ct) {
      f32x4 v = acc[rt][ct];
      const int row0 = bm + wr * 64 + rt * 16 + kg * 4;
      const int col = bn + wc * 64 + ct * 16 + fr;
      const float bs = bias[col];
#pragma unroll
      for (int j = 0; j < 4; ++j) {
        float o = v[j] + bs;
        if (RELU) o = fmaxf(o, 0.f);
        C[(size_t)(row0 + j) * N + col] = o;
      }
    }
  }
}

// ---------------- fused attention v2 (f32) ----------------
__global__ __launch_bounds__(128) void k_attn(const float* __restrict__ qkv,
                                              float* __restrict__ ob) {
  __shared__ float Qt[64][36];  // Qt[d][q]
  __shared__ float Kt[64][68];  // Kt[d][k]
  __shared__ float Vs[64][68];  // Vs[k][d]
  __shared__ float Pt[64][36];  // Pt[k][q]
  const int tid = threadIdx.x;
  const int bq = blockIdx.x * 32;
  const int h = blockIdx.y;
  {
    const int r = tid >> 2, ds0 = (tid & 3) * 16;
    const float* src = qkv + (size_t)(bq + r) * 1536 + h * DH + ds0;
#pragma unroll
    for (int i = 0; i < 4; ++i) {
      float4 v = *(const float4*)(src + i * 4);
      Qt[ds0 + i * 4 + 0][r] = v.x * 0.125f;
      Qt[ds0 + i * 4 + 1][r] = v.y * 0.125f;
      Qt[ds0 + i * 4 + 2][r] = v.z * 0.125f;
      Qt[ds0 + i * 4 + 3][r] = v.w * 0.125f;
    }
  }
  const int tx = tid & 15, ty = tid >> 4;
  float m[4], l[4], acc[4][4] = {};
#pragma unroll
  for (int i = 0; i < 4; ++i) { m[i] = -1e30f; l[i] = 0.f; }
  for (int kt = 0; kt < 32; ++kt) {
    __syncthreads();  // A
    {
      const int r = tid >> 1, half = tid & 1;
      const float* ksrc = qkv + (size_t)(kt * 64 + r) * 1536 + 512 + h * DH + half * 32;
      const float* vsrc = ksrc + 512;
#pragma unroll
      for (int i = 0; i < 8; ++i) {
        float4 kv = *(const float4*)(ksrc + i * 4);
        int dd = half * 32 + i * 4;
        Kt[dd + 0][r] = kv.x; Kt[dd + 1][r] = kv.y;
        Kt[dd + 2][r] = kv.z; Kt[dd + 3][r] = kv.w;
      }
#pragma unroll
      for (int i = 0; i < 8; ++i)
        *(float4*)&Vs[r][half * 32 + i * 4] = *(const float4*)(vsrc + i * 4);
    }
    __syncthreads();  // B
    float s[4][4] = {};
#pragma unroll 8
    for (int d = 0; d < 64; ++d) {
      float4 qv = *(const float4*)&Qt[d][ty * 4];
      float4 kv = *(const float4*)&Kt[d][tx * 4];
      float qa[4] = {qv.x, qv.y, qv.z, qv.w};
      float ka[4] = {kv.x, kv.y, kv.z, kv.w};
#pragma unroll
      for (int i = 0; i < 4; ++i)
#pragma unroll
        for (int j = 0; j < 4; ++j) s[i][j] += qa[i] * ka[j];
    }
#pragma unroll
    for (int i = 0; i < 4; ++i) {
      float v = fmaxf(fmaxf(s[i][0], s[i][1]), fmaxf(s[i][2], s[i][3]));
#pragma unroll
      for (int off = 1; off < 16; off <<= 1) v = fmaxf(v, __shfl_xor(v, off, 64));
      float mn = fmaxf(m[i], v);
      float f = __expf(m[i] - mn);
      m[i] = mn;
      float p0 = __expf(s[i][0] - mn), p1 = __expf(s[i][1] - mn);
      float p2 = __expf(s[i][2] - mn), p3 = __expf(s[i][3] - mn);
      float rs = (p0 + p1) + (p2 + p3);
#pragma unroll
      for (int off = 1; off < 16; off <<= 1) rs += __shfl_xor(rs, off, 64);
      l[i] = l[i] * f + rs;
      acc[i][0] *= f; acc[i][1] *= f; acc[i][2] *= f; acc[i][3] *= f;
      const int q = ty * 4 + i;
      Pt[tx * 4 + 0][q] = p0; Pt[tx * 4 + 1][q] = p1;
      Pt[tx * 4 + 2][q] = p2; Pt[tx * 4 + 3][q] = p3;
    }
    __syncthreads();  // C
#pragma unroll 8
    for (int k = 0; k < 64; ++k) {
      float4 pv = *(const float4*)&Pt[k][ty * 4];
      float4 vv = *(const float4*)&Vs[k][tx * 4];
      float pa[4] = {pv.x, pv.y, pv.z, pv.w};
      float va[4] = {vv.x, vv.y, vv.z, vv.w};
#pragma unroll
      for (int i = 0; i < 4; ++i)
#pragma unroll
        for (int j = 0; j < 4; ++j) acc[i][j] += pa[i] * va[j];
    }
  }
#pragma unroll
  for (int i = 0; i < 4; ++i) {
    float inv = 1.f / l[i];
    float4 o;
    o.x = acc[i][0] * inv; o.y = acc[i][1] * inv;
    o.z = acc[i][2] * inv; o.w = acc[i][3] * inv;
    *(float4*)(ob + (size_t)(bq + ty * 4 + i) * D_MODEL + h * DH + tx * 4) = o;
  }
}

// ---------------- residual + layernorm ----------------
__global__ __launch_bounds__(128) void k_ln(const float* __restrict__ a,
                                            const float* __restrict__ r,
                                            const float* __restrict__ g,
                                            const float* __restrict__ b,
                                            float* __restrict__ out) {
  __shared__ float red[2];
  const int row = blockIdx.x, tid = threadIdx.x;
  const size_t off = (size_t)row * D_MODEL + tid * 4;
  float4 av = *(const float4*)(a + off);
  float4 rv = *(const float4*)(r + off);
  float v0 = av.x + rv.x, v1 = av.y + rv.y, v2 = av.z + rv.z, v3 = av.w + rv.w;
  float s = v0 + v1 + v2 + v3;
#pragma unroll
  for (int d = 1; d < 64; d <<= 1) s += __shfl_xor(s, d, 64);
  if ((tid & 63) == 0) red[tid >> 6] = s;
  __syncthreads();
  float mean = (red[0] + red[1]) * (1.f / 512.f);
  __syncthreads();
  float d0 = v0 - mean, d1 = v1 - mean, d2 = v2 - mean, d3 = v3 - mean;
  float sq = d0 * d0 + d1 * d1 + d2 * d2 + d3 * d3;
#pragma unroll
  for (int d = 1; d < 64; d <<= 1) sq += __shfl_xor(sq, d, 64);
  if ((tid & 63) == 0) red[tid >> 6] = sq;
  __syncthreads();
  float inv = rsqrtf((red[0] + red[1]) * (1.f / 512.f) + 1e-5f);
  float4 gv = *(const float4*)(g + tid * 4);
  float4 bv = *(const float4*)(b + tid * 4);
  float4 o;
  o.x = d0 * inv * gv.x + bv.x;
  o.y = d1 * inv * gv.y + bv.y;
  o.z = d2 * inv * gv.z + bv.z;
  o.w = d3 * inv * gv.w + bv.w;
  *(float4*)(out + off) = o;
}

// ---------------- emission scores feats = x2 * Wt^T + bt  [2048][32] ----------------
__global__ __launch_bounds__(256) void k_feats(const float* __restrict__ x2,
                                               const float* __restrict__ Wt,
                                               const float* __restrict__ bt,
                                               float* __restrict__ feats) {
  const int tid = threadIdx.x;
  const int s = blockIdx.x * 8 + (tid >> 5);
  const int l = tid & 31;
  const float* xr = x2 + (size_t)s * D_MODEL;
  const float* wr = Wt + (size_t)l * D_MODEL;
  float acc = 0.f;
#pragma unroll 8
  for (int k = 0; k < D_MODEL; k += 4) {
    float4 xv = *(const float4*)(xr + k);
    float4 wv = *(const float4*)(wr + k);
    acc += xv.x * wv.x + xv.y * wv.y + xv.z * wv.z + xv.w * wv.w;
  }
  feats[s * L_TAGS + l] = acc + bt[l];
}

// ============ Viterbi via chunked max-plus scan (64 chunks x 32 steps) ============

// phase 1: chunk products, column-wise.
__global__ __launch_bounds__(64) void k_scan1(const float* __restrict__ feats,
                                              const float* __restrict__ T,
                                              float* __restrict__ P) {
  __shared__ float S[2][32];
  const int c = blockIdx.x >> 4;
  const int l = threadIdx.x;
  const int n = l & 31, pl = l >> 5;
  const int p = (blockIdx.x & 15) * 2 + pl;
  float Trow[32];
#pragma unroll
  for (int q = 0; q < 32; ++q) Trow[q] = T[n * 32 + q];
  const int tbase = c * 32;
  float er[4];
#pragma unroll
  for (int i = 0; i < 4; ++i) er[i] = feats[(tbase + i) * 32 + n];
  float a = T[n * 32 + p] + er[0];
  S[pl][n] = a;
  const float* fp = feats + (size_t)(tbase + 4) * 32 + n;
  er[0] = fp[0]; fp += 32;
  for (int u = 1; u < 32; ++u) {
    float e = er[u & 3];
    float enew = fp[0]; fp += 32;
    const float4* Sv = (const float4*)&S[pl][0];
    float g[32];
#pragma unroll
    for (int j4 = 0; j4 < 8; ++j4) {
      float4 sv = Sv[j4];
      g[j4 * 4 + 0] = sv.x + Trow[j4 * 4 + 0];
      g[j4 * 4 + 1] = sv.y + Trow[j4 * 4 + 1];
      g[j4 * 4 + 2] = sv.z + Trow[j4 * 4 + 2];
      g[j4 * 4 + 3] = sv.w + Trow[j4 * 4 + 3];
    }
#pragma unroll
    for (int st = 1; st < 32; st <<= 1)
#pragma unroll
      for (int j = 0; j < 32; j += 2 * st) g[j] = fmaxf(g[j], g[j + st]);
    a = g[0] + e;
    S[pl][n] = a;
    er[u & 3] = enew;
  }
  P[(size_t)c * 1024 + n * 32 + p] = a;
}

// phase 2: boundary alphas + terminal score/argmax.
__global__ __launch_bounds__(64) void k_scan2(const float* __restrict__ P,
                                              const float* __restrict__ T,
                                              float* __restrict__ alphas,
                                              float* __restrict__ out,
                                              int* __restrict__ bestp) {
  __shared__ float Sa[32];
  const int l = threadIdx.x, n = l & 31, half = l >> 5;
  float a = (n == START_TAG) ? 0.f : NEGV;
  const float* pbase = P + n * 32 + half * 16;
  float4 pr[4];
#pragma unroll
  for (int j = 0; j < 4; ++j) pr[j] = *(const float4*)(pbase + j * 4);
  for (int c = 0; c < 64; ++c) {
    float4 nx[4];
#pragma unroll
    for (int j = 0; j < 4; ++j)
      nx[j] = *(const float4*)(pbase + (size_t)(c + 1) * 1024 + j * 4);
    alphas[(size_t)(c * 32) * 32 + n] = a;
    Sa[n] = a;
    const float4* Sv = (const float4*)&Sa[half * 16];
    float g[16];
#pragma unroll
    for (int j = 0; j < 4; ++j) {
      float4 sv = Sv[j];
      g[j * 4 + 0] = pr[j].x + sv.x;
      g[j * 4 + 1] = pr[j].y + sv.y;
      g[j * 4 + 2] = pr[j].z + sv.z;
      g[j * 4 + 3] = pr[j].w + sv.w;
    }
#pragma unroll
    for (int st = 1; st < 16; st <<= 1)
#pragma unroll
      for (int j = 0; j < 16; j += 2 * st) g[j] = fmaxf(g[j], g[j + st]);
    uint2v r = __builtin_amdgcn_permlane32_swap(__float_as_uint(g[0]),
                                                __float_as_uint(g[0]), false, false);
    a = fmaxf(__uint_as_float(r[0]), __uint_as_float(r[1]));
#pragma unroll
    for (int j = 0; j < 4; ++j) pr[j] = nx[j];
  }
  float term = a + T[STOP_TAG * 32 + n];
  float bv = term;
  int bi = n;
#pragma unroll
  for (int d = 1; d < 32; d <<= 1) {
    float ov = __shfl_xor(bv, d, 64);
    int oi = __shfl_xor(bi, d, 64);
    if (ov > bv || (ov == bv && oi < bi)) { bv = ov; bi = oi; }
  }
  if (l == 0) { out[0] = bv; *bestp = bi; }
}

// phase 3: interior alphas per chunk.
__global__ __launch_bounds__(64) void k_scan3(const float* __restrict__ feats,
                                              const float* __restrict__ T,
                                              float* __restrict__ alphas) {
  __shared__ float Sa[32];
  const int c = blockIdx.x, l = threadIdx.x, n = l & 31, half = l >> 5;
  float Tr[16];
#pragma unroll
  for (int j = 0; j < 16; ++j) Tr[j] = T[n * 32 + half * 16 + j];
  const int tbase = c * 32;
  float a = alphas[(size_t)tbase * 32 + n];
  float er[4];
#pragma unroll
  for (int i = 0; i < 4; ++i) er[i] = feats[(tbase + i) * 32 + n];
  const float* fp = feats + (size_t)(tbase + 4) * 32 + n;
  Sa[n] = a;
  for (int u = 0; u < 31; ++u) {
    float e = er[u & 3];
    float enew = fp[0]; fp += 32;
    const float4* Sv = (const float4*)&Sa[half * 16];
    float4 s0 = Sv[0], s1 = Sv[1], s2 = Sv[2], s3 = Sv[3];
    float g[16] = {s0.x + Tr[0],  s0.y + Tr[1],  s0.z + Tr[2],  s0.w + Tr[3],
                   s1.x + Tr[4],  s1.y + Tr[5],  s1.z + Tr[6],  s1.w + Tr[7],
                   s2.x + Tr[8],  s2.y + Tr[9],  s2.z + Tr[10], s2.w + Tr[11],
                   s3.x + Tr[12], s3.y + Tr[13], s3.z + Tr[14], s3.w + Tr[15]};
#pragma unroll
    for (int st = 1; st < 16; st <<= 1)
#pragma unroll
      for (int j = 0; j < 16; j += 2 * st) g[j] = fmaxf(g[j], g[j + st]);
    uint2v r = __builtin_amdgcn_permlane32_swap(__float_as_uint(g[0]),
                                                __float_as_uint(g[0]), false, false);
    a = fmaxf(__uint_as_float(r[0]), __uint_as_float(r[1])) + e;
    alphas[(size_t)(tbase + u + 1) * 32 + n] = a;
    Sa[n] = a;
    er[u & 3] = enew;
  }
}

// ---------------- backpointers (parallel) ----------------
__global__ __launch_bounds__(256) void k_vit_bp(const float* __restrict__ alphas,
                                                const float* __restrict__ T,
                                                unsigned char* __restrict__ bp) {
  __shared__ float Ts[32][33];
  __shared__ float Al[8][32];
  const int tid = threadIdx.x;
  for (int i = tid; i < 1024; i += 256) Ts[i >> 5][i & 31] = T[i];
  const int t0 = blockIdx.x * 8;
  Al[tid >> 5][tid & 31] = alphas[t0 * 32 + tid];
  __syncthreads();
  const int tl = tid >> 5, n = tid & 31;
  float best = -3e38f;
  int bi = 0;
#pragma unroll
  for (int p = 0; p < 32; ++p) {
    float v = Al[tl][p] + Ts[n][p];
    if (v > best) { best = v; bi = p; }
  }
  bp[(size_t)(t0 + tl) * 32 + n] = (unsigned char)bi;
}

// ---------------- traceback ----------------
__global__ __launch_bounds__(256) void k_vit_trace(const unsigned char* __restrict__ bp,
                                                   const int* __restrict__ bestp,
                                                   unsigned char* __restrict__ cand,
                                                   float* __restrict__ outp) {
  __shared__ unsigned char Amap[64][32];
  const int tid = threadIdx.x;
  int tg[8];
#pragma unroll
  for (int i = 0; i < 8; ++i) {
    int id = tid + 256 * i;
    tg[i] = id & 31;
    cand[(size_t)id * 32 + 31] = (unsigned char)tg[i];
  }
  for (int j = 31; j >= 1; --j) {
#pragma unroll
    for (int i = 0; i < 8; ++i) {
      int id = tid + 256 * i;
      tg[i] = bp[(size_t)((id >> 5) * 32 + j) * 32 + tg[i]];
      cand[(size_t)id * 32 + (j - 1)] = (unsigned char)tg[i];
    }
  }
#pragma unroll
  for (int i = 0; i < 8; ++i) {
    int id = tid + 256 * i;
    Amap[id >> 5][id & 31] = bp[(size_t)((id >> 5) * 32) * 32 + tg[i]];
  }
  __syncthreads();
  for (int d = 1; d < 64; d <<= 1) {
    unsigned char tmpv[8];
#pragma unroll
    for (int i = 0; i < 8; ++i) {
      int id = tid + 256 * i;
      int c = id >> 5, e = id & 31;
      tmpv[i] = (c + d < 64) ? Amap[c][Amap[c + d][e]] : Amap[c][e];
    }
    __syncthreads();
#pragma unroll
    for (int i = 0; i < 8; ++i) {
      int id = tid + 256 * i;
      Amap[id >> 5][id & 31] = tmpv[i];
    }
    __syncthreads();
  }
  const int best = *bestp;
#pragma unroll
  for (int i = 0; i < 8; ++i) {
    int t = tid + 256 * i;
    int c = t >> 5, j = t & 31;
    int et = (c == 63) ? best : Amap[c + 1][best];
    outp[1 + t] = (float)cand[(size_t)(c * 32 + et) * 32 + j];
  }
}

extern "C" void kernel_launch(void* const* d_in, const int* in_sizes, int n_in,
                              void* d_out, int out_size, void* d_ws, size_t ws_size,
                              hipStream_t stream) {
  (void)in_sizes; (void)n_in; (void)out_size; (void)ws_size;
  const int* sent = (const int*)d_in[0];
  const float* embed = (const float*)d_in[1];
  const float* Wqkv = (const float*)d_in[2];
  const float* bqkv = (const float*)d_in[3];
  const float* Wo = (const float*)d_in[4];
  const float* bo = (const float*)d_in[5];
  const float* g1 = (const float*)d_in[6];
  const float* b1n = (const float*)d_in[7];
  const float* W1 = (const float*)d_in[8];
  const float* b1f = (const float*)d_in[9];
  const float* W2 = (const float*)d_in[10];
  const float* b2f = (const float*)d_in[11];
  const float* g2 = (const float*)d_in[12];
  const float* b2n = (const float*)d_in[13];
  const float* Wt = (const float*)d_in[14];
  const float* bt = (const float*)d_in[15];
  const float* T = (const float*)d_in[16];
  float* out = (float*)d_out;

  float* ws = (float*)d_ws;
  const size_t M1 = 1u << 20;  // 1M floats = 4MB
  float* x = ws;               // [2048][512]
  float* qkvb = ws + M1;       // [2048][1536]
  float* ob = ws + 4 * M1;     // [2048][512]
  float* yb = ws + 5 * M1;     // [2048][512]
  float* x1 = ws + 6 * M1;     // [2048][512]
  float* ffb = ws;             // [2048][2048]  (aliases x+qkvb, dead by then)
  float* zb = ws + 4 * M1;     // aliases ob
  float* x2 = ws + 5 * M1;     // aliases yb
  float* feats = ws + 7 * M1;  // [2048][32]
  float* alphas = feats + 2048 * 32;            // [2049][32]
  int* bestp = (int*)(alphas + 2049 * 32 + 32);
  unsigned char* bp = (unsigned char*)(bestp + 32);  // [2048][32] u8
  unsigned char* cand = bp + 2048 * 32;              // [2048][32] u8
  float* P = ws;  // [65][1024] chunk products; region dead by scan time

  k_embed<<<dim3(2048), dim3(128), 0, stream>>>(sent, embed, x);
  k_gemm_mfma<false><<<dim3(12, 16), dim3(256), 0, stream>>>(x, Wqkv, bqkv, qkvb, 2048, 1536, 512);
  k_attn<<<dim3(64, 8), dim3(128), 0, stream>>>(qkvb, ob);
  k_gemm_mfma<false><<<dim3(4, 16), dim3(256), 0, stream>>>(ob, Wo, bo, yb, 2048, 512, 512);
  k_ln<<<dim3(2048), dim3(128), 0, stream>>>(x, yb, g1, b1n, x1);
  k_gemm_mfma<true><<<dim3(16, 16), dim3(256), 0, stream>>>(x1, W1, b1f, ffb, 2048, 2048, 512);
  k_gemm_mfma<false><<<dim3(4, 16), dim3(256), 0, stream>>>(ffb, W2, b2f, zb, 2048, 512, 2048);
  k_ln<<<dim3(2048), dim3(128), 0, stream>>>(x1, zb, g2, b2n, x2);
  k_feats<<<dim3(256), dim3(256), 0, stream>>>(x2, Wt, bt, feats);
  k_scan1<<<dim3(1024), dim3(64), 0, stream>>>(feats, T, P);
  k_scan2<<<dim3(1), dim3(64), 0, stream>>>(P, T, alphas, out, bestp);
  k_scan3<<<dim3(64), dim3(64), 0, stream>>>(feats, T, alphas);
  k_vit_bp<<<dim3(256), dim3(256), 0, stream>>>(alphas, T, bp);
  k_vit_trace<<<dim3(1), dim3(256), 0, stream>>>(bp, bestp, cand, out);
}

// Round 8
// 299.472 us; speedup vs baseline: 3.1018x; 1.7784x over previous
//
#include <hip/hip_runtime.h>
#include <cstddef>

#define S_LEN 2048
#define D_MODEL 512
#define NHEAD 8
#define DH 64
#define FF_DIM 2048
#define L_TAGS 32
#define START_TAG 30
#define STOP_TAG 31
#define NEGV (-10000.0f)

typedef unsigned int uint2v __attribute__((ext_vector_type(2)));
typedef __attribute__((ext_vector_type(8))) short short8v;   // 8 bf16 = 4 VGPR
typedef __attribute__((ext_vector_type(4))) float f32x4;

union U8 { uint4 u; short8v s; };

__device__ __forceinline__ unsigned short f2bf(float f) {
  unsigned u = __float_as_uint(f);
  u += 0x7fff + ((u >> 16) & 1);   // RTNE
  return (unsigned short)(u >> 16);
}
__device__ __forceinline__ unsigned cvtpk(float lo, float hi) {
  unsigned r;
  asm("v_cvt_pk_bf16_f32 %0, %1, %2" : "=v"(r) : "v"(lo), "v"(hi));
  return r;  // low16 = bf16(lo), high16 = bf16(hi)
}

// ---------------- embedding gather ----------------
__global__ __launch_bounds__(128) void k_embed(const int* __restrict__ sent,
                                               const float* __restrict__ embed,
                                               float* __restrict__ x) {
  int s = blockIdx.x;
  int d = threadIdx.x * 4;
  size_t idx = (size_t)sent[s] * D_MODEL + d;
  *(float4*)(x + (size_t)s * D_MODEL + d) = *(const float4*)(embed + idx);
}

// ======== bf16 MFMA GEMM: C = A[M][K] * B[N][K]^T + bias ========
// RT=4: 128x128 tile; RT=2: 64x64 tile (full-chip grids for N=512).
template <int RT, bool RELU>
__global__ __launch_bounds__(256, 2) void k_gemm_mfma(const float* __restrict__ A,
                                                      const float* __restrict__ B,
                                                      const float* __restrict__ bias,
                                                      float* __restrict__ C,
                                                      int M, int N, int K) {
  constexpr int BM = RT * 32;
  constexpr int TPR = 256 / BM;   // threads per staged row
  constexpr int CH = 8 / TPR;     // 8-elem chunks per thread
  __shared__ __align__(16) short As[2][BM * 64];
  __shared__ __align__(16) short Bs[2][BM * 64];
  const int tid = threadIdx.x;
  const int bm = blockIdx.y * BM, bn = blockIdx.x * BM;
  const int w = tid >> 6, lane = tid & 63;
  const int wr = w >> 1, wc = w & 1;
  const int fr = lane & 15, kg = lane >> 4;
  const int srow = tid / TPR, scb = (tid % TPR) * CH;
  const int swz = srow & 7;
  const float* gA = A + (size_t)(bm + srow) * K + scb * 8;
  const float* gB = B + (size_t)(bn + srow) * K + scb * 8;
  f32x4 ra[2 * CH], rb[2 * CH];
  f32x4 acc[RT][RT] = {};

  auto loadg = [&](int k0) {
#pragma unroll
    for (int c = 0; c < CH; ++c) {
      ra[2 * c] = *(const f32x4*)(gA + k0 + c * 8);
      ra[2 * c + 1] = *(const f32x4*)(gA + k0 + c * 8 + 4);
      rb[2 * c] = *(const f32x4*)(gB + k0 + c * 8);
      rb[2 * c + 1] = *(const f32x4*)(gB + k0 + c * 8 + 4);
    }
  };
  auto storeb = [&](int b) {
    short* dA = &As[b][srow * 64];
    short* dB = &Bs[b][srow * 64];
#pragma unroll
    for (int c = 0; c < CH; ++c) {
      U8 ta, tb;
      ta.u.x = cvtpk(ra[2 * c][0], ra[2 * c][1]);
      ta.u.y = cvtpk(ra[2 * c][2], ra[2 * c][3]);
      ta.u.z = cvtpk(ra[2 * c + 1][0], ra[2 * c + 1][1]);
      ta.u.w = cvtpk(ra[2 * c + 1][2], ra[2 * c + 1][3]);
      tb.u.x = cvtpk(rb[2 * c][0], rb[2 * c][1]);
      tb.u.y = cvtpk(rb[2 * c][2], rb[2 * c][3]);
      tb.u.z = cvtpk(rb[2 * c + 1][0], rb[2 * c + 1][1]);
      tb.u.w = cvtpk(rb[2 * c + 1][2], rb[2 * c + 1][3]);
      *(short8v*)(dA + (((scb + c) ^ swz) << 3)) = ta.s;
      *(short8v*)(dB + (((scb + c) ^ swz) << 3)) = tb.s;
    }
  };

  loadg(0);
  storeb(0);
  __syncthreads();
  int cur = 0;
  const int fswz = fr & 7;
  for (int k0 = 0; k0 < K; k0 += 64) {
    const bool more = (k0 + 64) < K;
    if (more) loadg(k0 + 64);
    const short* rA = &As[cur][(wr * (RT * 16) + fr) * 64];
    const short* rB = &Bs[cur][(wc * (RT * 16) + fr) * 64];
#pragma unroll
    for (int ks = 0; ks < 2; ++ks) {
      const int co = ((ks * 4 + kg) ^ fswz) << 3;
      short8v af[RT], bf[RT];
#pragma unroll
      for (int rt = 0; rt < RT; ++rt) af[rt] = *(const short8v*)(rA + rt * 16 * 64 + co);
#pragma unroll
      for (int ct = 0; ct < RT; ++ct) bf[ct] = *(const short8v*)(rB + ct * 16 * 64 + co);
#pragma unroll
      for (int rt = 0; rt < RT; ++rt)
#pragma unroll
        for (int ct = 0; ct < RT; ++ct)
          acc[rt][ct] = __builtin_amdgcn_mfma_f32_16x16x32_bf16(af[rt], bf[ct], acc[rt][ct], 0, 0, 0);
    }
    if (more) storeb(cur ^ 1);
    __syncthreads();
    cur ^= 1;
  }
  // epilogue: C/D layout col=lane&15, row=(lane>>4)*4+reg
#pragma unroll
  for (int rt = 0; rt < RT; ++rt) {
#pragma unroll
    for (int ct = 0; ct < RT; ++ct) {
      f32x4 v = acc[rt][ct];
      const int row0 = bm + wr * (RT * 16) + rt * 16 + kg * 4;
      const int col = bn + wc * (RT * 16) + ct * 16 + fr;
      const float bs = bias[col];
#pragma unroll
      for (int j = 0; j < 4; ++j) {
        float o = v[j] + bs;
        if (RELU) o = fmaxf(o, 0.f);
        C[(size_t)(row0 + j) * N + col] = o;
      }
    }
  }
}

// ======== fused attention v3: bf16 MFMA flash ========
// 128 thr / 2 waves, 32 q-rows per block, grid (64, 8) -> 2 blocks/CU.
// Q in registers (A-frags); K row-major LDS; V transposed LDS; P via
// per-wave private LDS (same-wave DS ordering, no barrier).
__global__ __launch_bounds__(128) void k_attn(const float* __restrict__ qkv,
                                              float* __restrict__ ob) {
  __shared__ __align__(16) short Ks[64][72];
  __shared__ __align__(16) short Vt[64][72];
  __shared__ __align__(16) short Pl[2][16][72];
  const int tid = threadIdx.x;
  const int bq = blockIdx.x * 32;
  const int h = blockIdx.y;
  const int wq = tid >> 6, lane = tid & 63;
  const int fr = lane & 15, kg = lane >> 4;
  // Q A-frags (rows bq+wq*16+fr), pre-scaled by 1/8
  short8v qf[2];
  {
    const float* qsrc = qkv + (size_t)(bq + wq * 16 + fr) * 1536 + h * DH;
#pragma unroll
    for (int ks = 0; ks < 2; ++ks) {
      f32x4 a = *(const f32x4*)(qsrc + ks * 32 + kg * 8);
      f32x4 b = *(const f32x4*)(qsrc + ks * 32 + kg * 8 + 4);
      U8 t;
      t.u.x = cvtpk(a[0] * 0.125f, a[1] * 0.125f);
      t.u.y = cvtpk(a[2] * 0.125f, a[3] * 0.125f);
      t.u.z = cvtpk(b[0] * 0.125f, b[1] * 0.125f);
      t.u.w = cvtpk(b[2] * 0.125f, b[3] * 0.125f);
      qf[ks] = t.s;
    }
  }
  float m[4], l[4];
  f32x4 oac[4] = {};
#pragma unroll
  for (int j = 0; j < 4; ++j) { m[j] = -1e30f; l[j] = 0.f; }

  const int kp = tid >> 2, d0 = (tid & 3) * 16;
  for (int kt = 0; kt < 32; ++kt) {
    __syncthreads();  // prev PV done reading Ks/Vt
    {
      const float* base = qkv + (size_t)(kt * 64 + 2 * kp) * 1536 + 512 + h * DH + d0;
      f32x4 k0[4], k1[4], v0[4], v1[4];
#pragma unroll
      for (int i = 0; i < 4; ++i) {
        k0[i] = *(const f32x4*)(base + i * 4);
        k1[i] = *(const f32x4*)(base + 1536 + i * 4);
        v0[i] = *(const f32x4*)(base + 512 + i * 4);
        v1[i] = *(const f32x4*)(base + 512 + 1536 + i * 4);
      }
      U8 t;
      t.u.x = cvtpk(k0[0][0], k0[0][1]); t.u.y = cvtpk(k0[0][2], k0[0][3]);
      t.u.z = cvtpk(k0[1][0], k0[1][1]); t.u.w = cvtpk(k0[1][2], k0[1][3]);
      *(uint4*)&Ks[2 * kp][d0] = t.u;
      t.u.x = cvtpk(k0[2][0], k0[2][1]); t.u.y = cvtpk(k0[2][2], k0[2][3]);
      t.u.z = cvtpk(k0[3][0], k0[3][1]); t.u.w = cvtpk(k0[3][2], k0[3][3]);
      *(uint4*)&Ks[2 * kp][d0 + 8] = t.u;
      t.u.x = cvtpk(k1[0][0], k1[0][1]); t.u.y = cvtpk(k1[0][2], k1[0][3]);
      t.u.z = cvtpk(k1[1][0], k1[1][1]); t.u.w = cvtpk(k1[1][2], k1[1][3]);
      *(uint4*)&Ks[2 * kp + 1][d0] = t.u;
      t.u.x = cvtpk(k1[2][0], k1[2][1]); t.u.y = cvtpk(k1[2][2], k1[2][3]);
      t.u.z = cvtpk(k1[3][0], k1[3][1]); t.u.w = cvtpk(k1[3][2], k1[3][3]);
      *(uint4*)&Ks[2 * kp + 1][d0 + 8] = t.u;
#pragma unroll
      for (int i = 0; i < 4; ++i)
#pragma unroll
        for (int j = 0; j < 4; ++j)
          *(unsigned*)&Vt[d0 + i * 4 + j][2 * kp] = cvtpk(v0[i][j], v1[i][j]);
    }
    __syncthreads();  // staging visible
    // QK^T
    f32x4 sac[4] = {};
#pragma unroll
    for (int ks = 0; ks < 2; ++ks) {
      short8v bfr[4];
#pragma unroll
      for (int ct = 0; ct < 4; ++ct)
        bfr[ct] = *(const short8v*)&Ks[ct * 16 + fr][ks * 32 + kg * 8];
#pragma unroll
      for (int ct = 0; ct < 4; ++ct)
        sac[ct] = __builtin_amdgcn_mfma_f32_16x16x32_bf16(qf[ks], bfr[ct], sac[ct], 0, 0, 0);
    }
    // online softmax; C rows = kg*4+j, cols across 16 lanes (fixed kg group)
    float pv[4][4];
#pragma unroll
    for (int j = 0; j < 4; ++j) {
      float v = fmaxf(fmaxf(sac[0][j], sac[1][j]), fmaxf(sac[2][j], sac[3][j]));
#pragma unroll
      for (int off = 1; off < 16; off <<= 1) v = fmaxf(v, __shfl_xor(v, off, 64));
      float mn = fmaxf(m[j], v);
      float f = __expf(m[j] - mn);
      m[j] = mn;
      float rs = 0.f;
#pragma unroll
      for (int ct = 0; ct < 4; ++ct) {
        pv[ct][j] = __expf(sac[ct][j] - mn);
        rs += pv[ct][j];
      }
#pragma unroll
      for (int off = 1; off < 16; off <<= 1) rs += __shfl_xor(rs, off, 64);
      l[j] = l[j] * f + rs;
#pragma unroll
      for (int ct = 0; ct < 4; ++ct) oac[ct][j] *= f;
    }
    // P -> own-wave LDS (bf16); same-wave ordering, no barrier needed
#pragma unroll
    for (int ct = 0; ct < 4; ++ct)
#pragma unroll
      for (int j = 0; j < 4; ++j)
        Pl[wq][kg * 4 + j][ct * 16 + fr] = (short)f2bf(pv[ct][j]);
    // PV
#pragma unroll
    for (int ks = 0; ks < 2; ++ks) {
      short8v paf = *(const short8v*)&Pl[wq][fr][ks * 32 + kg * 8];
      short8v vbf[4];
#pragma unroll
      for (int ct = 0; ct < 4; ++ct)
        vbf[ct] = *(const short8v*)&Vt[ct * 16 + fr][ks * 32 + kg * 8];
#pragma unroll
      for (int ct = 0; ct < 4; ++ct)
        oac[ct] = __builtin_amdgcn_mfma_f32_16x16x32_bf16(paf, vbf[ct], oac[ct], 0, 0, 0);
    }
  }
#pragma unroll
  for (int j = 0; j < 4; ++j) {
    float inv = 1.f / l[j];
    const int q = bq + wq * 16 + kg * 4 + j;
#pragma unroll
    for (int ct = 0; ct < 4; ++ct)
      ob[(size_t)q * D_MODEL + h * DH + ct * 16 + fr] = oac[ct][j] * inv;
  }
}

// ---------------- residual + layernorm ----------------
__global__ __launch_bounds__(128) void k_ln(const float* __restrict__ a,
                                            const float* __restrict__ r,
                                            const float* __restrict__ g,
                                            const float* __restrict__ b,
                                            float* __restrict__ out) {
  __shared__ float red[2];
  const int row = blockIdx.x, tid = threadIdx.x;
  const size_t off = (size_t)row * D_MODEL + tid * 4;
  float4 av = *(const float4*)(a + off);
  float4 rv = *(const float4*)(r + off);
  float v0 = av.x + rv.x, v1 = av.y + rv.y, v2 = av.z + rv.z, v3 = av.w + rv.w;
  float s = v0 + v1 + v2 + v3;
#pragma unroll
  for (int d = 1; d < 64; d <<= 1) s += __shfl_xor(s, d, 64);
  if ((tid & 63) == 0) red[tid >> 6] = s;
  __syncthreads();
  float mean = (red[0] + red[1]) * (1.f / 512.f);
  __syncthreads();
  float d0 = v0 - mean, d1 = v1 - mean, d2 = v2 - mean, d3 = v3 - mean;
  float sq = d0 * d0 + d1 * d1 + d2 * d2 + d3 * d3;
#pragma unroll
  for (int d = 1; d < 64; d <<= 1) sq += __shfl_xor(sq, d, 64);
  if ((tid & 63) == 0) red[tid >> 6] = sq;
  __syncthreads();
  float inv = rsqrtf((red[0] + red[1]) * (1.f / 512.f) + 1e-5f);
  float4 gv = *(const float4*)(g + tid * 4);
  float4 bv = *(const float4*)(b + tid * 4);
  float4 o;
  o.x = d0 * inv * gv.x + bv.x;
  o.y = d1 * inv * gv.y + bv.y;
  o.z = d2 * inv * gv.z + bv.z;
  o.w = d3 * inv * gv.w + bv.w;
  *(float4*)(out + off) = o;
}

// ---------------- emission scores feats = x2 * Wt^T + bt ----------------
__global__ __launch_bounds__(256) void k_feats(const float* __restrict__ x2,
                                               const float* __restrict__ Wt,
                                               const float* __restrict__ bt,
                                               float* __restrict__ feats) {
  const int tid = threadIdx.x;
  const int s = blockIdx.x * 8 + (tid >> 5);
  const int l = tid & 31;
  const float* xr = x2 + (size_t)s * D_MODEL;
  const float* wr = Wt + (size_t)l * D_MODEL;
  float acc = 0.f;
#pragma unroll 8
  for (int k = 0; k < D_MODEL; k += 4) {
    float4 xv = *(const float4*)(xr + k);
    float4 wv = *(const float4*)(wr + k);
    acc += xv.x * wv.x + xv.y * wv.y + xv.z * wv.z + xv.w * wv.w;
  }
  feats[s * L_TAGS + l] = acc + bt[l];
}

// ============ Viterbi via chunked max-plus scan ============
__global__ __launch_bounds__(64) void k_scan1(const float* __restrict__ feats,
                                              const float* __restrict__ T,
                                              float* __restrict__ P) {
  __shared__ float S[2][32];
  const int c = blockIdx.x >> 4;
  const int l = threadIdx.x;
  const int n = l & 31, pl = l >> 5;
  const int p = (blockIdx.x & 15) * 2 + pl;
  float Trow[32];
#pragma unroll
  for (int q = 0; q < 32; ++q) Trow[q] = T[n * 32 + q];
  const int tbase = c * 32;
  float er[4];
#pragma unroll
  for (int i = 0; i < 4; ++i) er[i] = feats[(tbase + i) * 32 + n];
  float a = T[n * 32 + p] + er[0];
  S[pl][n] = a;
  const float* fp = feats + (size_t)(tbase + 4) * 32 + n;
  er[0] = fp[0]; fp += 32;
  for (int u = 1; u < 32; ++u) {
    float e = er[u & 3];
    float enew = fp[0]; fp += 32;
    const float4* Sv = (const float4*)&S[pl][0];
    float g[32];
#pragma unroll
    for (int j4 = 0; j4 < 8; ++j4) {
      float4 sv = Sv[j4];
      g[j4 * 4 + 0] = sv.x + Trow[j4 * 4 + 0];
      g[j4 * 4 + 1] = sv.y + Trow[j4 * 4 + 1];
      g[j4 * 4 + 2] = sv.z + Trow[j4 * 4 + 2];
      g[j4 * 4 + 3] = sv.w + Trow[j4 * 4 + 3];
    }
#pragma unroll
    for (int st = 1; st < 32; st <<= 1)
#pragma unroll
      for (int j = 0; j < 32; j += 2 * st) g[j] = fmaxf(g[j], g[j + st]);
    a = g[0] + e;
    S[pl][n] = a;
    er[u & 3] = enew;
  }
  P[(size_t)c * 1024 + n * 32 + p] = a;
}

__global__ __launch_bounds__(64) void k_scan2(const float* __restrict__ P,
                                              const float* __restrict__ T,
                                              float* __restrict__ alphas,
                                              float* __restrict__ out,
                                              int* __restrict__ bestp) {
  __shared__ float Sa[32];
  const int l = threadIdx.x, n = l & 31, half = l >> 5;
  float a = (n == START_TAG) ? 0.f : NEGV;
  const float* pbase = P + n * 32 + half * 16;
  float4 pr[4];
#pragma unroll
  for (int j = 0; j < 4; ++j) pr[j] = *(const float4*)(pbase + j * 4);
  for (int c = 0; c < 64; ++c) {
    float4 nx[4];
#pragma unroll
    for (int j = 0; j < 4; ++j)
      nx[j] = *(const float4*)(pbase + (size_t)(c + 1) * 1024 + j * 4);
    alphas[(size_t)(c * 32) * 32 + n] = a;
    Sa[n] = a;
    const float4* Sv = (const float4*)&Sa[half * 16];
    float g[16];
#pragma unroll
    for (int j = 0; j < 4; ++j) {
      float4 sv = Sv[j];
      g[j * 4 + 0] = pr[j].x + sv.x;
      g[j * 4 + 1] = pr[j].y + sv.y;
      g[j * 4 + 2] = pr[j].z + sv.z;
      g[j * 4 + 3] = pr[j].w + sv.w;
    }
#pragma unroll
    for (int st = 1; st < 16; st <<= 1)
#pragma unroll
      for (int j = 0; j < 16; j += 2 * st) g[j] = fmaxf(g[j], g[j + st]);
    uint2v r = __builtin_amdgcn_permlane32_swap(__float_as_uint(g[0]),
                                                __float_as_uint(g[0]), false, false);
    a = fmaxf(__uint_as_float(r[0]), __uint_as_float(r[1]));
#pragma unroll
    for (int j = 0; j < 4; ++j) pr[j] = nx[j];
  }
  float term = a + T[STOP_TAG * 32 + n];
  float bv = term;
  int bi = n;
#pragma unroll
  for (int d = 1; d < 32; d <<= 1) {
    float ov = __shfl_xor(bv, d, 64);
    int oi = __shfl_xor(bi, d, 64);
    if (ov > bv || (ov == bv && oi < bi)) { bv = ov; bi = oi; }
  }
  if (l == 0) { out[0] = bv; *bestp = bi; }
}

__global__ __launch_bounds__(64) void k_scan3(const float* __restrict__ feats,
                                              const float* __restrict__ T,
                                              float* __restrict__ alphas) {
  __shared__ float Sa[32];
  const int c = blockIdx.x, l = threadIdx.x, n = l & 31, half = l >> 5;
  float Tr[16];
#pragma unroll
  for (int j = 0; j < 16; ++j) Tr[j] = T[n * 32 + half * 16 + j];
  const int tbase = c * 32;
  float a = alphas[(size_t)tbase * 32 + n];
  float er[4];
#pragma unroll
  for (int i = 0; i < 4; ++i) er[i] = feats[(tbase + i) * 32 + n];
  const float* fp = feats + (size_t)(tbase + 4) * 32 + n;
  Sa[n] = a;
  for (int u = 0; u < 31; ++u) {
    float e = er[u & 3];
    float enew = fp[0]; fp += 32;
    const float4* Sv = (const float4*)&Sa[half * 16];
    float4 s0 = Sv[0], s1 = Sv[1], s2 = Sv[2], s3 = Sv[3];
    float g[16] = {s0.x + Tr[0],  s0.y + Tr[1],  s0.z + Tr[2],  s0.w + Tr[3],
                   s1.x + Tr[4],  s1.y + Tr[5],  s1.z + Tr[6],  s1.w + Tr[7],
                   s2.x + Tr[8],  s2.y + Tr[9],  s2.z + Tr[10], s2.w + Tr[11],
                   s3.x + Tr[12], s3.y + Tr[13], s3.z + Tr[14], s3.w + Tr[15]};
#pragma unroll
    for (int st = 1; st < 16; st <<= 1)
#pragma unroll
      for (int j = 0; j < 16; j += 2 * st) g[j] = fmaxf(g[j], g[j + st]);
    uint2v r = __builtin_amdgcn_permlane32_swap(__float_as_uint(g[0]),
                                                __float_as_uint(g[0]), false, false);
    a = fmaxf(__uint_as_float(r[0]), __uint_as_float(r[1])) + e;
    alphas[(size_t)(tbase + u + 1) * 32 + n] = a;
    Sa[n] = a;
    er[u & 3] = enew;
  }
}

// ---------------- backpointers ----------------
__global__ __launch_bounds__(256) void k_vit_bp(const float* __restrict__ alphas,
                                                const float* __restrict__ T,
                                                unsigned char* __restrict__ bp) {
  __shared__ float Ts[32][33];
  __shared__ float Al[8][32];
  const int tid = threadIdx.x;
  for (int i = tid; i < 1024; i += 256) Ts[i >> 5][i & 31] = T[i];
  const int t0 = blockIdx.x * 8;
  Al[tid >> 5][tid & 31] = alphas[t0 * 32 + tid];
  __syncthreads();
  const int tl = tid >> 5, n = tid & 31;
  float best = -3e38f;
  int bi = 0;
#pragma unroll
  for (int p = 0; p < 32; ++p) {
    float v = Al[tl][p] + Ts[n][p];
    if (v > best) { best = v; bi = p; }
  }
  bp[(size_t)(t0 + tl) * 32 + n] = (unsigned char)bi;
}

// ---------------- traceback ----------------
__global__ __launch_bounds__(256) void k_vit_trace(const unsigned char* __restrict__ bp,
                                                   const int* __restrict__ bestp,
                                                   unsigned char* __restrict__ cand,
                                                   float* __restrict__ outp) {
  __shared__ unsigned char Amap[64][32];
  const int tid = threadIdx.x;
  int tg[8];
#pragma unroll
  for (int i = 0; i < 8; ++i) {
    int id = tid + 256 * i;
    tg[i] = id & 31;
    cand[(size_t)id * 32 + 31] = (unsigned char)tg[i];
  }
  for (int j = 31; j >= 1; --j) {
#pragma unroll
    for (int i = 0; i < 8; ++i) {
      int id = tid + 256 * i;
      tg[i] = bp[(size_t)((id >> 5) * 32 + j) * 32 + tg[i]];
      cand[(size_t)id * 32 + (j - 1)] = (unsigned char)tg[i];
    }
  }
#pragma unroll
  for (int i = 0; i < 8; ++i) {
    int id = tid + 256 * i;
    Amap[id >> 5][id & 31] = bp[(size_t)((id >> 5) * 32) * 32 + tg[i]];
  }
  __syncthreads();
  for (int d = 1; d < 64; d <<= 1) {
    unsigned char tmpv[8];
#pragma unroll
    for (int i = 0; i < 8; ++i) {
      int id = tid + 256 * i;
      int c = id >> 5, e = id & 31;
      tmpv[i] = (c + d < 64) ? Amap[c][Amap[c + d][e]] : Amap[c][e];
    }
    __syncthreads();
#pragma unroll
    for (int i = 0; i < 8; ++i) {
      int id = tid + 256 * i;
      Amap[id >> 5][id & 31] = tmpv[i];
    }
    __syncthreads();
  }
  const int best = *bestp;
#pragma unroll
  for (int i = 0; i < 8; ++i) {
    int t = tid + 256 * i;
    int c = t >> 5, j = t & 31;
    int et = (c == 63) ? best : Amap[c + 1][best];
    outp[1 + t] = (float)cand[(size_t)(c * 32 + et) * 32 + j];
  }
}

extern "C" void kernel_launch(void* const* d_in, const int* in_sizes, int n_in,
                              void* d_out, int out_size, void* d_ws, size_t ws_size,
                              hipStream_t stream) {
  (void)in_sizes; (void)n_in; (void)out_size; (void)ws_size;
  const int* sent = (const int*)d_in[0];
  const float* embed = (const float*)d_in[1];
  const float* Wqkv = (const float*)d_in[2];
  const float* bqkv = (const float*)d_in[3];
  const float* Wo = (const float*)d_in[4];
  const float* bo = (const float*)d_in[5];
  const float* g1 = (const float*)d_in[6];
  const float* b1n = (const float*)d_in[7];
  const float* W1 = (const float*)d_in[8];
  const float* b1f = (const float*)d_in[9];
  const float* W2 = (const float*)d_in[10];
  const float* b2f = (const float*)d_in[11];
  const float* g2 = (const float*)d_in[12];
  const float* b2n = (const float*)d_in[13];
  const float* Wt = (const float*)d_in[14];
  const float* bt = (const float*)d_in[15];
  const float* T = (const float*)d_in[16];
  float* out = (float*)d_out;

  float* ws = (float*)d_ws;
  const size_t M1 = 1u << 20;  // 1M floats = 4MB
  float* x = ws;               // [2048][512]
  float* qkvb = ws + M1;       // [2048][1536]
  float* ob = ws + 4 * M1;     // [2048][512]
  float* yb = ws + 5 * M1;     // [2048][512]
  float* x1 = ws + 6 * M1;     // [2048][512]
  float* ffb = ws;             // [2048][2048]  (aliases x+qkvb, dead by then)
  float* zb = ws + 4 * M1;     // aliases ob
  float* x2 = ws + 5 * M1;     // aliases yb
  float* feats = ws + 7 * M1;  // [2048][32]
  float* alphas = feats + 2048 * 32;            // [2049][32]
  int* bestp = (int*)(alphas + 2049 * 32 + 32);
  unsigned char* bp = (unsigned char*)(bestp + 32);  // [2048][32] u8
  unsigned char* cand = bp + 2048 * 32;              // [2048][32] u8
  float* P = ws;  // [65][1024]; region dead by scan time

  k_embed<<<dim3(2048), dim3(128), 0, stream>>>(sent, embed, x);
  k_gemm_mfma<4, false><<<dim3(12, 16), dim3(256), 0, stream>>>(x, Wqkv, bqkv, qkvb, 2048, 1536, 512);
  k_attn<<<dim3(64, 8), dim3(128), 0, stream>>>(qkvb, ob);
  k_gemm_mfma<2, false><<<dim3(8, 32), dim3(256), 0, stream>>>(ob, Wo, bo, yb, 2048, 512, 512);
  k_ln<<<dim3(2048), dim3(128), 0, stream>>>(x, yb, g1, b1n, x1);
  k_gemm_mfma<4, true><<<dim3(16, 16), dim3(256), 0, stream>>>(x1, W1, b1f, ffb, 2048, 2048, 512);
  k_gemm_mfma<2, false><<<dim3(8, 32), dim3(256), 0, stream>>>(ffb, W2, b2f, zb, 2048, 512, 2048);
  k_ln<<<dim3(2048), dim3(128), 0, stream>>>(x1, zb, g2, b2n, x2);
  k_feats<<<dim3(256), dim3(256), 0, stream>>>(x2, Wt, bt, feats);
  k_scan1<<<dim3(1024), dim3(64), 0, stream>>>(feats, T, P);
  k_scan2<<<dim3(1), dim3(64), 0, stream>>>(P, T, alphas, out, bestp);
  k_scan3<<<dim3(64), dim3(64), 0, stream>>>(feats, T, alphas);
  k_vit_bp<<<dim3(256), dim3(256), 0, stream>>>(alphas, T, bp);
  k_vit_trace<<<dim3(1), dim3(256), 0, stream>>>(bp, bestp, cand, out);
}

// Round 9
// 252.089 us; speedup vs baseline: 3.6848x; 1.1880x over previous
//
#include <hip/hip_runtime.h>
#include <cstddef>

#define S_LEN 2048
#define D_MODEL 512
#define NHEAD 8
#define DH 64
#define FF_DIM 2048
#define L_TAGS 32
#define START_TAG 30
#define STOP_TAG 31
#define NEGV (-10000.0f)

typedef unsigned int uint2v __attribute__((ext_vector_type(2)));
typedef __attribute__((ext_vector_type(8))) short short8v;   // 8 bf16 = 4 VGPR
typedef __attribute__((ext_vector_type(4))) float f32x4;

union U8 { uint4 u; short8v s; };

__device__ __forceinline__ unsigned short f2bf(float f) {
  unsigned u = __float_as_uint(f);
  u += 0x7fff + ((u >> 16) & 1);   // RTNE
  return (unsigned short)(u >> 16);
}
__device__ __forceinline__ unsigned cvtpk(float lo, float hi) {
  unsigned r;
  asm("v_cvt_pk_bf16_f32 %0, %1, %2" : "=v"(r) : "v"(lo), "v"(hi));
  return r;
}

// ---------------- f32 -> bf16 bulk convert (weights) ----------------
__global__ __launch_bounds__(256) void k_f2h(const float* __restrict__ src,
                                             short* __restrict__ dst, int n8) {
  int i = blockIdx.x * 256 + threadIdx.x;
  if (i >= n8) return;
  f32x4 a = *(const f32x4*)(src + (size_t)i * 8);
  f32x4 b = *(const f32x4*)(src + (size_t)i * 8 + 4);
  U8 t;
  t.u.x = cvtpk(a[0], a[1]); t.u.y = cvtpk(a[2], a[3]);
  t.u.z = cvtpk(b[0], b[1]); t.u.w = cvtpk(b[2], b[3]);
  *(short8v*)(dst + (size_t)i * 8) = t.s;
}

// ---------------- embedding gather: f32 + bf16 copies ----------------
__global__ __launch_bounds__(128) void k_embed(const int* __restrict__ sent,
                                               const float* __restrict__ embed,
                                               float* __restrict__ x,
                                               short* __restrict__ xh) {
  int s = blockIdx.x;
  int d = threadIdx.x * 4;
  size_t off = (size_t)s * D_MODEL + d;
  float4 v = *(const float4*)(embed + (size_t)sent[s] * D_MODEL + d);
  *(float4*)(x + off) = v;
  uint2v t;
  t[0] = cvtpk(v.x, v.y);
  t[1] = cvtpk(v.z, v.w);
  *(uint2v*)(xh + off) = t;
}

// ======== bf16 MFMA GEMM: C = A[M][K] * B[N][K]^T + bias (A,B bf16) ========
template <int RT, bool RELU, bool OBF>
__global__ __launch_bounds__(256, 2) void k_gemm_bf(const short* __restrict__ A,
                                                    const short* __restrict__ B,
                                                    const float* __restrict__ bias,
                                                    void* __restrict__ Cp,
                                                    int M, int N, int K) {
  constexpr int BM = RT * 32;
  constexpr int CH = (BM * 8) / 256;  // 16B chunks staged per thread per matrix
  __shared__ __align__(16) short As[2][BM * 64];
  __shared__ __align__(16) short Bs[2][BM * 64];
  const int tid = threadIdx.x;
  const int bm = blockIdx.y * BM, bn = blockIdx.x * BM;
  const int w = tid >> 6, lane = tid & 63;
  const int wr = w >> 1, wc = w & 1;
  const int fr = lane & 15, kg = lane >> 4;
  const int srow = (RT == 4) ? (tid >> 1) : (tid >> 2);
  const int sc0 = (RT == 4) ? ((tid & 1) * 4) : ((tid & 3) * 2);
  const int swz = srow & 7;
  const short* gA = A + (size_t)(bm + srow) * K + sc0 * 8;
  const short* gB = B + (size_t)(bn + srow) * K + sc0 * 8;
  short8v ra[CH], rb[CH];
  f32x4 acc[RT][RT] = {};

  auto loadg = [&](int k0) {
#pragma unroll
    for (int c = 0; c < CH; ++c) {
      ra[c] = *(const short8v*)(gA + k0 + c * 8);
      rb[c] = *(const short8v*)(gB + k0 + c * 8);
    }
  };
  auto storeb = [&](int b) {
    short* dA = &As[b][srow * 64];
    short* dB = &Bs[b][srow * 64];
#pragma unroll
    for (int c = 0; c < CH; ++c) {
      *(short8v*)(dA + (((sc0 + c) ^ swz) << 3)) = ra[c];
      *(short8v*)(dB + (((sc0 + c) ^ swz) << 3)) = rb[c];
    }
  };

  loadg(0);
  storeb(0);
  __syncthreads();
  int cur = 0;
  const int fswz = fr & 7;
  for (int k0 = 0; k0 < K; k0 += 64) {
    const bool more = (k0 + 64) < K;
    if (more) loadg(k0 + 64);
    const short* rA = &As[cur][(wr * (RT * 16) + fr) * 64];
    const short* rB = &Bs[cur][(wc * (RT * 16) + fr) * 64];
#pragma unroll
    for (int ks = 0; ks < 2; ++ks) {
      const int co = ((ks * 4 + kg) ^ fswz) << 3;
      short8v af[RT], bf[RT];
#pragma unroll
      for (int rt = 0; rt < RT; ++rt) af[rt] = *(const short8v*)(rA + rt * 16 * 64 + co);
#pragma unroll
      for (int ct = 0; ct < RT; ++ct) bf[ct] = *(const short8v*)(rB + ct * 16 * 64 + co);
#pragma unroll
      for (int rt = 0; rt < RT; ++rt)
#pragma unroll
        for (int ct = 0; ct < RT; ++ct)
          acc[rt][ct] = __builtin_amdgcn_mfma_f32_16x16x32_bf16(af[rt], bf[ct], acc[rt][ct], 0, 0, 0);
    }
    if (more) storeb(cur ^ 1);
    __syncthreads();
    cur ^= 1;
  }
  // epilogue: C/D layout col=lane&15, row=(lane>>4)*4+reg
#pragma unroll
  for (int rt = 0; rt < RT; ++rt) {
#pragma unroll
    for (int ct = 0; ct < RT; ++ct) {
      f32x4 v = acc[rt][ct];
      const int row0 = bm + wr * (RT * 16) + rt * 16 + kg * 4;
      const int col = bn + wc * (RT * 16) + ct * 16 + fr;
      const float bs = bias[col];
#pragma unroll
      for (int j = 0; j < 4; ++j) {
        float o = v[j] + bs;
        if (RELU) o = fmaxf(o, 0.f);
        if (OBF)
          ((short*)Cp)[(size_t)(row0 + j) * N + col] = (short)f2bf(o);
        else
          ((float*)Cp)[(size_t)(row0 + j) * N + col] = o;
      }
    }
  }
}

// ======== fused attention v4: bf16 MFMA flash, L2-local per head ========
// 256 thr / 4 waves, 64 q-rows per block; grid 256, head = blk&7 (XCD
// round-robin heuristic -> each head's K/V stays in one XCD's L2).
// Double-buffered K/V LDS; next-tile loads issued before compute (T14);
// one barrier per tile.
__global__ __launch_bounds__(256) void k_attn(const short* __restrict__ qkv,
                                              short* __restrict__ ob) {
  __shared__ __align__(16) short Ks[2][64 * 64];   // chunk-XOR swizzled
  __shared__ __align__(16) short Vt[2][64 * 72];   // transposed, pad->2-way only
  __shared__ __align__(16) short Pl[4][16 * 72];
  const int tid = threadIdx.x;
  const int b = blockIdx.x;
  const int h = b & 7;
  const int bq = (b >> 3) * 64;
  const int wq = tid >> 6, lane = tid & 63;
  const int fr = lane & 15, kg = lane >> 4;
  // Q A-frags (bf16 direct)
  short8v qf[2];
  {
    const short* qsrc = qkv + (size_t)(bq + wq * 16 + fr) * 1536 + h * DH;
    qf[0] = *(const short8v*)(qsrc + kg * 8);
    qf[1] = *(const short8v*)(qsrc + 32 + kg * 8);
  }
  float m[4], l[4];
  f32x4 oac[4] = {};
#pragma unroll
  for (int j = 0; j < 4; ++j) { m[j] = -1e30f; l[j] = 0.f; }

  const int srow = tid >> 2, sc0 = (tid & 3) * 2;   // K copy lanes
  const int kpair = tid & 31, dgrp = tid >> 5;      // V transpose lanes
  short8v kr0, kr1, va, vb;
  auto loadt = [&](int kt) {
    const short* kbase = qkv + (size_t)(kt * 64 + srow) * 1536 + 512 + h * DH;
    kr0 = *(const short8v*)(kbase + sc0 * 8);
    kr1 = *(const short8v*)(kbase + sc0 * 8 + 8);
    const short* vbase = qkv + (size_t)(kt * 64 + 2 * kpair) * 1536 + 1024 + h * DH + dgrp * 8;
    va = *(const short8v*)(vbase);
    vb = *(const short8v*)(vbase + 1536);
  };
  auto storet = [&](int cu) {
    short* dk = &Ks[cu][srow * 64];
    *(short8v*)(dk + ((sc0 ^ (srow & 7)) << 3)) = kr0;
    *(short8v*)(dk + (((sc0 + 1) ^ (srow & 7)) << 3)) = kr1;
#pragma unroll
    for (int i = 0; i < 8; ++i) {
      unsigned u = ((unsigned)(unsigned short)va[i]) |
                   (((unsigned)(unsigned short)vb[i]) << 16);
      *(unsigned*)&Vt[cu][(dgrp * 8 + i) * 72 + 2 * kpair] = u;
    }
  };

  loadt(0);
  int cur = 0;
  for (int kt = 0; kt < 32; ++kt) {
    storet(cur);
    __syncthreads();
    if (kt < 31) loadt(kt + 1);   // overlap next-tile loads with compute
    // QK^T
    f32x4 sac[4] = {};
#pragma unroll
    for (int ks = 0; ks < 2; ++ks) {
#pragma unroll
      for (int ct = 0; ct < 4; ++ct) {
        const int row = ct * 16 + fr;
        short8v bfr = *(const short8v*)&Ks[cur][row * 64 + (((ks * 4 + kg) ^ (row & 7)) << 3)];
        sac[ct] = __builtin_amdgcn_mfma_f32_16x16x32_bf16(qf[ks], bfr, sac[ct], 0, 0, 0);
      }
    }
#pragma unroll
    for (int ct = 0; ct < 4; ++ct) sac[ct] *= 0.125f;
    // online softmax; lane rows m=kg*4+j, cols fr over 16-lane group
    float pv[4][4];
#pragma unroll
    for (int j = 0; j < 4; ++j) {
      float v = fmaxf(fmaxf(sac[0][j], sac[1][j]), fmaxf(sac[2][j], sac[3][j]));
#pragma unroll
      for (int off = 1; off < 16; off <<= 1) v = fmaxf(v, __shfl_xor(v, off, 64));
      float mn = fmaxf(m[j], v);
      float f = __expf(m[j] - mn);
      m[j] = mn;
      float rs = 0.f;
#pragma unroll
      for (int ct = 0; ct < 4; ++ct) {
        pv[ct][j] = __expf(sac[ct][j] - mn);
        rs += pv[ct][j];
      }
#pragma unroll
      for (int off = 1; off < 16; off <<= 1) rs += __shfl_xor(rs, off, 64);
      l[j] = l[j] * f + rs;
#pragma unroll
      for (int ct = 0; ct < 4; ++ct) oac[ct][j] *= f;
    }
    // P -> own-wave LDS (same-wave DS ordering; no barrier)
#pragma unroll
    for (int ct = 0; ct < 4; ++ct)
#pragma unroll
      for (int j = 0; j < 4; ++j)
        Pl[wq][(kg * 4 + j) * 72 + ct * 16 + fr] = (short)f2bf(pv[ct][j]);
    // PV
#pragma unroll
    for (int ks = 0; ks < 2; ++ks) {
      short8v paf = *(const short8v*)&Pl[wq][fr * 72 + ks * 32 + kg * 8];
#pragma unroll
      for (int ct = 0; ct < 4; ++ct) {
        short8v vf = *(const short8v*)&Vt[cur][(ct * 16 + fr) * 72 + ks * 32 + kg * 8];
        oac[ct] = __builtin_amdgcn_mfma_f32_16x16x32_bf16(paf, vf, oac[ct], 0, 0, 0);
      }
    }
    cur ^= 1;
  }
#pragma unroll
  for (int j = 0; j < 4; ++j) {
    float inv = 1.f / l[j];
    const int q = bq + wq * 16 + kg * 4 + j;
#pragma unroll
    for (int ct = 0; ct < 4; ++ct)
      ob[(size_t)q * D_MODEL + h * DH + ct * 16 + fr] = (short)f2bf(oac[ct][j] * inv);
  }
}

// ---------------- residual + layernorm (f32 out + optional bf16 out) ----------------
__global__ __launch_bounds__(128) void k_ln(const float* __restrict__ a,
                                            const float* __restrict__ r,
                                            const float* __restrict__ g,
                                            const float* __restrict__ b,
                                            float* __restrict__ out,
                                            short* __restrict__ outh) {
  __shared__ float red[2];
  const int row = blockIdx.x, tid = threadIdx.x;
  const size_t off = (size_t)row * D_MODEL + tid * 4;
  float4 av = *(const float4*)(a + off);
  float4 rv = *(const float4*)(r + off);
  float v0 = av.x + rv.x, v1 = av.y + rv.y, v2 = av.z + rv.z, v3 = av.w + rv.w;
  float s = v0 + v1 + v2 + v3;
#pragma unroll
  for (int d = 1; d < 64; d <<= 1) s += __shfl_xor(s, d, 64);
  if ((tid & 63) == 0) red[tid >> 6] = s;
  __syncthreads();
  float mean = (red[0] + red[1]) * (1.f / 512.f);
  __syncthreads();
  float d0 = v0 - mean, d1 = v1 - mean, d2 = v2 - mean, d3 = v3 - mean;
  float sq = d0 * d0 + d1 * d1 + d2 * d2 + d3 * d3;
#pragma unroll
  for (int d = 1; d < 64; d <<= 1) sq += __shfl_xor(sq, d, 64);
  if ((tid & 63) == 0) red[tid >> 6] = sq;
  __syncthreads();
  float inv = rsqrtf((red[0] + red[1]) * (1.f / 512.f) + 1e-5f);
  float4 gv = *(const float4*)(g + tid * 4);
  float4 bv = *(const float4*)(b + tid * 4);
  float4 o;
  o.x = d0 * inv * gv.x + bv.x;
  o.y = d1 * inv * gv.y + bv.y;
  o.z = d2 * inv * gv.z + bv.z;
  o.w = d3 * inv * gv.w + bv.w;
  *(float4*)(out + off) = o;
  if (outh) {
    uint2v t;
    t[0] = cvtpk(o.x, o.y);
    t[1] = cvtpk(o.z, o.w);
    *(uint2v*)(outh + off) = t;
  }
}

// ---------------- emission scores feats = x2 * Wt^T + bt ----------------
__global__ __launch_bounds__(256) void k_feats(const float* __restrict__ x2,
                                               const float* __restrict__ Wt,
                                               const float* __restrict__ bt,
                                               float* __restrict__ feats) {
  const int tid = threadIdx.x;
  const int s = blockIdx.x * 8 + (tid >> 5);
  const int l = tid & 31;
  const float* xr = x2 + (size_t)s * D_MODEL;
  const float* wr = Wt + (size_t)l * D_MODEL;
  float acc = 0.f;
#pragma unroll 8
  for (int k = 0; k < D_MODEL; k += 4) {
    float4 xv = *(const float4*)(xr + k);
    float4 wv = *(const float4*)(wr + k);
    acc += xv.x * wv.x + xv.y * wv.y + xv.z * wv.z + xv.w * wv.w;
  }
  feats[s * L_TAGS + l] = acc + bt[l];
}

// ============ Viterbi via chunked max-plus scan ============
__global__ __launch_bounds__(64) void k_scan1(const float* __restrict__ feats,
                                              const float* __restrict__ T,
                                              float* __restrict__ P) {
  __shared__ float S[2][32];
  const int c = blockIdx.x >> 4;
  const int l = threadIdx.x;
  const int n = l & 31, pl = l >> 5;
  const int p = (blockIdx.x & 15) * 2 + pl;
  float Trow[32];
#pragma unroll
  for (int q = 0; q < 32; ++q) Trow[q] = T[n * 32 + q];
  const int tbase = c * 32;
  float er[4];
#pragma unroll
  for (int i = 0; i < 4; ++i) er[i] = feats[(tbase + i) * 32 + n];
  float a = T[n * 32 + p] + er[0];
  S[pl][n] = a;
  const float* fp = feats + (size_t)(tbase + 4) * 32 + n;
  er[0] = fp[0]; fp += 32;
  for (int u = 1; u < 32; ++u) {
    float e = er[u & 3];
    float enew = fp[0]; fp += 32;
    const float4* Sv = (const float4*)&S[pl][0];
    float g[32];
#pragma unroll
    for (int j4 = 0; j4 < 8; ++j4) {
      float4 sv = Sv[j4];
      g[j4 * 4 + 0] = sv.x + Trow[j4 * 4 + 0];
      g[j4 * 4 + 1] = sv.y + Trow[j4 * 4 + 1];
      g[j4 * 4 + 2] = sv.z + Trow[j4 * 4 + 2];
      g[j4 * 4 + 3] = sv.w + Trow[j4 * 4 + 3];
    }
#pragma unroll
    for (int st = 1; st < 32; st <<= 1)
#pragma unroll
      for (int j = 0; j < 32; j += 2 * st) g[j] = fmaxf(g[j], g[j + st]);
    a = g[0] + e;
    S[pl][n] = a;
    er[u & 3] = enew;
  }
  P[(size_t)c * 1024 + n * 32 + p] = a;
}

__global__ __launch_bounds__(64) void k_scan2(const float* __restrict__ P,
                                              const float* __restrict__ T,
                                              float* __restrict__ alphas,
                                              float* __restrict__ out,
                                              int* __restrict__ bestp) {
  __shared__ float Sa[32];
  const int l = threadIdx.x, n = l & 31, half = l >> 5;
  float a = (n == START_TAG) ? 0.f : NEGV;
  const float* pbase = P + n * 32 + half * 16;
  float4 pr[4];
#pragma unroll
  for (int j = 0; j < 4; ++j) pr[j] = *(const float4*)(pbase + j * 4);
  for (int c = 0; c < 64; ++c) {
    float4 nx[4];
#pragma unroll
    for (int j = 0; j < 4; ++j)
      nx[j] = *(const float4*)(pbase + (size_t)(c + 1) * 1024 + j * 4);
    alphas[(size_t)(c * 32) * 32 + n] = a;
    Sa[n] = a;
    const float4* Sv = (const float4*)&Sa[half * 16];
    float g[16];
#pragma unroll
    for (int j = 0; j < 4; ++j) {
      float4 sv = Sv[j];
      g[j * 4 + 0] = pr[j].x + sv.x;
      g[j * 4 + 1] = pr[j].y + sv.y;
      g[j * 4 + 2] = pr[j].z + sv.z;
      g[j * 4 + 3] = pr[j].w + sv.w;
    }
#pragma unroll
    for (int st = 1; st < 16; st <<= 1)
#pragma unroll
      for (int j = 0; j < 16; j += 2 * st) g[j] = fmaxf(g[j], g[j + st]);
    uint2v r = __builtin_amdgcn_permlane32_swap(__float_as_uint(g[0]),
                                                __float_as_uint(g[0]), false, false);
    a = fmaxf(__uint_as_float(r[0]), __uint_as_float(r[1]));
#pragma unroll
    for (int j = 0; j < 4; ++j) pr[j] = nx[j];
  }
  float term = a + T[STOP_TAG * 32 + n];
  float bv = term;
  int bi = n;
#pragma unroll
  for (int d = 1; d < 32; d <<= 1) {
    float ov = __shfl_xor(bv, d, 64);
    int oi = __shfl_xor(bi, d, 64);
    if (ov > bv || (ov == bv && oi < bi)) { bv = ov; bi = oi; }
  }
  if (l == 0) { out[0] = bv; *bestp = bi; }
}

__global__ __launch_bounds__(64) void k_scan3(const float* __restrict__ feats,
                                              const float* __restrict__ T,
                                              float* __restrict__ alphas) {
  __shared__ float Sa[32];
  const int c = blockIdx.x, l = threadIdx.x, n = l & 31, half = l >> 5;
  float Tr[16];
#pragma unroll
  for (int j = 0; j < 16; ++j) Tr[j] = T[n * 32 + half * 16 + j];
  const int tbase = c * 32;
  float a = alphas[(size_t)tbase * 32 + n];
  float er[4];
#pragma unroll
  for (int i = 0; i < 4; ++i) er[i] = feats[(tbase + i) * 32 + n];
  const float* fp = feats + (size_t)(tbase + 4) * 32 + n;
  Sa[n] = a;
  for (int u = 0; u < 31; ++u) {
    float e = er[u & 3];
    float enew = fp[0]; fp += 32;
    const float4* Sv = (const float4*)&Sa[half * 16];
    float4 s0 = Sv[0], s1 = Sv[1], s2 = Sv[2], s3 = Sv[3];
    float g[16] = {s0.x + Tr[0],  s0.y + Tr[1],  s0.z + Tr[2],  s0.w + Tr[3],
                   s1.x + Tr[4],  s1.y + Tr[5],  s1.z + Tr[6],  s1.w + Tr[7],
                   s2.x + Tr[8],  s2.y + Tr[9],  s2.z + Tr[10], s2.w + Tr[11],
                   s3.x + Tr[12], s3.y + Tr[13], s3.z + Tr[14], s3.w + Tr[15]};
#pragma unroll
    for (int st = 1; st < 16; st <<= 1)
#pragma unroll
      for (int j = 0; j < 16; j += 2 * st) g[j] = fmaxf(g[j], g[j + st]);
    uint2v r = __builtin_amdgcn_permlane32_swap(__float_as_uint(g[0]),
                                                __float_as_uint(g[0]), false, false);
    a = fmaxf(__uint_as_float(r[0]), __uint_as_float(r[1])) + e;
    alphas[(size_t)(tbase + u + 1) * 32 + n] = a;
    Sa[n] = a;
    er[u & 3] = enew;
  }
}

// ---------------- backpointers ----------------
__global__ __launch_bounds__(256) void k_vit_bp(const float* __restrict__ alphas,
                                                const float* __restrict__ T,
                                                unsigned char* __restrict__ bp) {
  __shared__ float Ts[32][33];
  __shared__ float Al[8][32];
  const int tid = threadIdx.x;
  for (int i = tid; i < 1024; i += 256) Ts[i >> 5][i & 31] = T[i];
  const int t0 = blockIdx.x * 8;
  Al[tid >> 5][tid & 31] = alphas[t0 * 32 + tid];
  __syncthreads();
  const int tl = tid >> 5, n = tid & 31;
  float best = -3e38f;
  int bi = 0;
#pragma unroll
  for (int p = 0; p < 32; ++p) {
    float v = Al[tl][p] + Ts[n][p];
    if (v > best) { best = v; bi = p; }
  }
  bp[(size_t)(t0 + tl) * 32 + n] = (unsigned char)bi;
}

// ---------------- traceback ----------------
__global__ __launch_bounds__(256) void k_vit_trace(const unsigned char* __restrict__ bp,
                                                   const int* __restrict__ bestp,
                                                   unsigned char* __restrict__ cand,
                                                   float* __restrict__ outp) {
  __shared__ unsigned char Amap[64][32];
  const int tid = threadIdx.x;
  int tg[8];
#pragma unroll
  for (int i = 0; i < 8; ++i) {
    int id = tid + 256 * i;
    tg[i] = id & 31;
    cand[(size_t)id * 32 + 31] = (unsigned char)tg[i];
  }
  for (int j = 31; j >= 1; --j) {
#pragma unroll
    for (int i = 0; i < 8; ++i) {
      int id = tid + 256 * i;
      tg[i] = bp[(size_t)((id >> 5) * 32 + j) * 32 + tg[i]];
      cand[(size_t)id * 32 + (j - 1)] = (unsigned char)tg[i];
    }
  }
#pragma unroll
  for (int i = 0; i < 8; ++i) {
    int id = tid + 256 * i;
    Amap[id >> 5][id & 31] = bp[(size_t)((id >> 5) * 32) * 32 + tg[i]];
  }
  __syncthreads();
  for (int d = 1; d < 64; d <<= 1) {
    unsigned char tmpv[8];
#pragma unroll
    for (int i = 0; i < 8; ++i) {
      int id = tid + 256 * i;
      int c = id >> 5, e = id & 31;
      tmpv[i] = (c + d < 64) ? Amap[c][Amap[c + d][e]] : Amap[c][e];
    }
    __syncthreads();
#pragma unroll
    for (int i = 0; i < 8; ++i) {
      int id = tid + 256 * i;
      Amap[id >> 5][id & 31] = tmpv[i];
    }
    __syncthreads();
  }
  const int best = *bestp;
#pragma unroll
  for (int i = 0; i < 8; ++i) {
    int t = tid + 256 * i;
    int c = t >> 5, j = t & 31;
    int et = (c == 63) ? best : Amap[c + 1][best];
    outp[1 + t] = (float)cand[(size_t)(c * 32 + et) * 32 + j];
  }
}

extern "C" void kernel_launch(void* const* d_in, const int* in_sizes, int n_in,
                              void* d_out, int out_size, void* d_ws, size_t ws_size,
                              hipStream_t stream) {
  (void)in_sizes; (void)n_in; (void)out_size; (void)ws_size;
  const int* sent = (const int*)d_in[0];
  const float* embed = (const float*)d_in[1];
  const float* Wqkv = (const float*)d_in[2];
  const float* bqkv = (const float*)d_in[3];
  const float* Wo = (const float*)d_in[4];
  const float* bo = (const float*)d_in[5];
  const float* g1 = (const float*)d_in[6];
  const float* b1n = (const float*)d_in[7];
  const float* W1 = (const float*)d_in[8];
  const float* b1f = (const float*)d_in[9];
  const float* W2 = (const float*)d_in[10];
  const float* b2f = (const float*)d_in[11];
  const float* g2 = (const float*)d_in[12];
  const float* b2n = (const float*)d_in[13];
  const float* Wt = (const float*)d_in[14];
  const float* bt = (const float*)d_in[15];
  const float* T = (const float*)d_in[16];
  float* out = (float*)d_out;

  float* ws = (float*)d_ws;
  const size_t M1 = 1u << 20;  // 1M floats = 4MB
  // lifetime-packed layout (peak ~22.8MB):
  float* x = ws;                              // f32 [2048][512]    (s2..s6)
  short* xh = (short*)(ws + M1);              // bf16 [2048][512]   (s2..s3)
  short* qkvh = (short*)(ws + 3 * M1 / 2);    // bf16 [2048][1536]  (s3..s4)
  short* obh = (short*)(ws + M1);             // bf16 [2048][512]   (s4..s5), reuses xh
  float* yb = ws + 3 * M1 / 2;                // f32 [2048][512]    (s5..s6), reuses qkvh lo
  float* x1 = ws + 3 * M1;                    // f32 [2048][512]    (s6..s9)
  short* x1h = (short*)(ws + 5 * M1 / 2);     // bf16 [2048][512]   (s6..s7)
  short* ffbh = (short*)ws;                   // bf16 [2048][2048]  (s7..s8), reuses x/xh/obh/yb
  float* zb = ws + 2 * M1;                    // f32 [2048][512]    (s8..s9)
  float* x2 = ws;                             // f32 [2048][512]    (s9..s10), reuses ffbh lo
  short* wqkvh = (short*)(ws + 4 * M1);       // 786432 shorts
  short* woh = wqkvh + 786432;                // 262144 shorts
  short* w1h = woh + 262144;                  // 1048576 shorts
  short* w2h = w1h + 1048576;                 // 1048576 shorts
  float* feats = ws + 4 * M1 + 3 * M1 / 2;    // [2048][32]
  float* alphas = feats + 2048 * 32 + 64;     // [2049][32]
  float* P = alphas + 2049 * 32 + 64;         // [65][1024]
  int* bestp = (int*)(P + 65 * 1024 + 64);
  unsigned char* bp = (unsigned char*)(bestp + 64);
  unsigned char* cand = bp + 2048 * 32;

  k_f2h<<<dim3(384), dim3(256), 0, stream>>>(Wqkv, wqkvh, 98304);
  k_f2h<<<dim3(128), dim3(256), 0, stream>>>(Wo, woh, 32768);
  k_f2h<<<dim3(512), dim3(256), 0, stream>>>(W1, w1h, 131072);
  k_f2h<<<dim3(512), dim3(256), 0, stream>>>(W2, w2h, 131072);
  k_embed<<<dim3(2048), dim3(128), 0, stream>>>(sent, embed, x, xh);
  k_gemm_bf<4, false, true><<<dim3(12, 16), dim3(256), 0, stream>>>(xh, wqkvh, bqkv, qkvh, 2048, 1536, 512);
  k_attn<<<dim3(256), dim3(256), 0, stream>>>(qkvh, obh);
  k_gemm_bf<2, false, false><<<dim3(8, 32), dim3(256), 0, stream>>>(obh, woh, bo, yb, 2048, 512, 512);
  k_ln<<<dim3(2048), dim3(128), 0, stream>>>(x, yb, g1, b1n, x1, x1h);
  k_gemm_bf<4, true, true><<<dim3(16, 16), dim3(256), 0, stream>>>(x1h, w1h, b1f, ffbh, 2048, 2048, 512);
  k_gemm_bf<2, false, false><<<dim3(8, 32), dim3(256), 0, stream>>>(ffbh, w2h, b2f, zb, 2048, 512, 2048);
  k_ln<<<dim3(2048), dim3(128), 0, stream>>>(x1, zb, g2, b2n, x2, (short*)nullptr);
  k_feats<<<dim3(256), dim3(256), 0, stream>>>(x2, Wt, bt, feats);
  k_scan1<<<dim3(1024), dim3(64), 0, stream>>>(feats, T, P);
  k_scan2<<<dim3(1), dim3(64), 0, stream>>>(P, T, alphas, out, bestp);
  k_scan3<<<dim3(64), dim3(64), 0, stream>>>(feats, T, alphas);
  k_vit_bp<<<dim3(256), dim3(256), 0, stream>>>(alphas, T, bp);
  k_vit_trace<<<dim3(1), dim3(256), 0, stream>>>(bp, bestp, cand, out);
}

// Round 10
// 199.246 us; speedup vs baseline: 4.6621x; 1.2652x over previous
//
#include <hip/hip_runtime.h>
#include <cstddef>

#define S_LEN 2048
#define D_MODEL 512
#define NHEAD 8
#define DH 64
#define FF_DIM 2048
#define L_TAGS 32
#define START_TAG 30
#define STOP_TAG 31
#define NEGV (-10000.0f)

typedef unsigned int uint2v __attribute__((ext_vector_type(2)));
typedef __attribute__((ext_vector_type(8))) short short8v;   // 8 bf16 = 4 VGPR
typedef __attribute__((ext_vector_type(4))) float f32x4;

union U8 { uint4 u; short8v s; };

__device__ __forceinline__ unsigned short f2bf(float f) {
  unsigned u = __float_as_uint(f);
  u += 0x7fff + ((u >> 16) & 1);   // RTNE
  return (unsigned short)(u >> 16);
}
__device__ __forceinline__ unsigned cvtpk(float lo, float hi) {
  unsigned r;
  asm("v_cvt_pk_bf16_f32 %0, %1, %2" : "=v"(r) : "v"(lo), "v"(hi));
  return r;
}

// ---------------- f32 -> bf16 bulk convert (weights) ----------------
__global__ __launch_bounds__(256) void k_f2h(const float* __restrict__ src,
                                             short* __restrict__ dst, int n8) {
  int i = blockIdx.x * 256 + threadIdx.x;
  if (i >= n8) return;
  f32x4 a = *(const f32x4*)(src + (size_t)i * 8);
  f32x4 b = *(const f32x4*)(src + (size_t)i * 8 + 4);
  U8 t;
  t.u.x = cvtpk(a[0], a[1]); t.u.y = cvtpk(a[2], a[3]);
  t.u.z = cvtpk(b[0], b[1]); t.u.w = cvtpk(b[2], b[3]);
  *(short8v*)(dst + (size_t)i * 8) = t.s;
}

// ---------------- embedding gather: f32 + bf16 copies ----------------
__global__ __launch_bounds__(128) void k_embed(const int* __restrict__ sent,
                                               const float* __restrict__ embed,
                                               float* __restrict__ x,
                                               short* __restrict__ xh) {
  int s = blockIdx.x;
  int d = threadIdx.x * 4;
  size_t off = (size_t)s * D_MODEL + d;
  float4 v = *(const float4*)(embed + (size_t)sent[s] * D_MODEL + d);
  *(float4*)(x + off) = v;
  uint2v t;
  t[0] = cvtpk(v.x, v.y);
  t[1] = cvtpk(v.z, v.w);
  *(uint2v*)(xh + off) = t;
}

// ======== bf16 MFMA GEMM: C = A[M][K] * B[N][K]^T + bias (A,B bf16) ========
template <int RT, bool RELU, bool OBF>
__global__ __launch_bounds__(256, 2) void k_gemm_bf(const short* __restrict__ A,
                                                    const short* __restrict__ B,
                                                    const float* __restrict__ bias,
                                                    void* __restrict__ Cp,
                                                    int M, int N, int K) {
  constexpr int BM = RT * 32;
  constexpr int CH = (BM * 8) / 256;  // 16B chunks staged per thread per matrix
  __shared__ __align__(16) short As[2][BM * 64];
  __shared__ __align__(16) short Bs[2][BM * 64];
  const int tid = threadIdx.x;
  const int bm = blockIdx.y * BM, bn = blockIdx.x * BM;
  const int w = tid >> 6, lane = tid & 63;
  const int wr = w >> 1, wc = w & 1;
  const int fr = lane & 15, kg = lane >> 4;
  const int srow = (RT == 4) ? (tid >> 1) : (tid >> 2);
  const int sc0 = (RT == 4) ? ((tid & 1) * 4) : ((tid & 3) * 2);
  const int swz = srow & 7;
  const short* gA = A + (size_t)(bm + srow) * K + sc0 * 8;
  const short* gB = B + (size_t)(bn + srow) * K + sc0 * 8;
  short8v ra[CH], rb[CH];
  f32x4 acc[RT][RT] = {};

  auto loadg = [&](int k0) {
#pragma unroll
    for (int c = 0; c < CH; ++c) {
      ra[c] = *(const short8v*)(gA + k0 + c * 8);
      rb[c] = *(const short8v*)(gB + k0 + c * 8);
    }
  };
  auto storeb = [&](int b) {
    short* dA = &As[b][srow * 64];
    short* dB = &Bs[b][srow * 64];
#pragma unroll
    for (int c = 0; c < CH; ++c) {
      *(short8v*)(dA + (((sc0 + c) ^ swz) << 3)) = ra[c];
      *(short8v*)(dB + (((sc0 + c) ^ swz) << 3)) = rb[c];
    }
  };

  loadg(0);
  storeb(0);
  __syncthreads();
  int cur = 0;
  const int fswz = fr & 7;
  for (int k0 = 0; k0 < K; k0 += 64) {
    const bool more = (k0 + 64) < K;
    if (more) loadg(k0 + 64);
    const short* rA = &As[cur][(wr * (RT * 16) + fr) * 64];
    const short* rB = &Bs[cur][(wc * (RT * 16) + fr) * 64];
#pragma unroll
    for (int ks = 0; ks < 2; ++ks) {
      const int co = ((ks * 4 + kg) ^ fswz) << 3;
      short8v af[RT], bf[RT];
#pragma unroll
      for (int rt = 0; rt < RT; ++rt) af[rt] = *(const short8v*)(rA + rt * 16 * 64 + co);
#pragma unroll
      for (int ct = 0; ct < RT; ++ct) bf[ct] = *(const short8v*)(rB + ct * 16 * 64 + co);
#pragma unroll
      for (int rt = 0; rt < RT; ++rt)
#pragma unroll
        for (int ct = 0; ct < RT; ++ct)
          acc[rt][ct] = __builtin_amdgcn_mfma_f32_16x16x32_bf16(af[rt], bf[ct], acc[rt][ct], 0, 0, 0);
    }
    if (more) storeb(cur ^ 1);
    __syncthreads();
    cur ^= 1;
  }
  // epilogue: C/D layout col=lane&15, row=(lane>>4)*4+reg
#pragma unroll
  for (int rt = 0; rt < RT; ++rt) {
#pragma unroll
    for (int ct = 0; ct < RT; ++ct) {
      f32x4 v = acc[rt][ct];
      const int row0 = bm + wr * (RT * 16) + rt * 16 + kg * 4;
      const int col = bn + wc * (RT * 16) + ct * 16 + fr;
      const float bs = bias[col];
#pragma unroll
      for (int j = 0; j < 4; ++j) {
        float o = v[j] + bs;
        if (RELU) o = fmaxf(o, 0.f);
        if (OBF)
          ((short*)Cp)[(size_t)(row0 + j) * N + col] = (short)f2bf(o);
        else
          ((float*)Cp)[(size_t)(row0 + j) * N + col] = o;
      }
    }
  }
}

// ======== fused attention v4: bf16 MFMA flash, L2-local per head ========
__global__ __launch_bounds__(256) void k_attn(const short* __restrict__ qkv,
                                              short* __restrict__ ob) {
  __shared__ __align__(16) short Ks[2][64 * 64];   // chunk-XOR swizzled
  __shared__ __align__(16) short Vt[2][64 * 72];   // transposed
  __shared__ __align__(16) short Pl[4][16 * 72];
  const int tid = threadIdx.x;
  const int b = blockIdx.x;
  const int h = b & 7;
  const int bq = (b >> 3) * 64;
  const int wq = tid >> 6, lane = tid & 63;
  const int fr = lane & 15, kg = lane >> 4;
  short8v qf[2];
  {
    const short* qsrc = qkv + (size_t)(bq + wq * 16 + fr) * 1536 + h * DH;
    qf[0] = *(const short8v*)(qsrc + kg * 8);
    qf[1] = *(const short8v*)(qsrc + 32 + kg * 8);
  }
  float m[4], l[4];
  f32x4 oac[4] = {};
#pragma unroll
  for (int j = 0; j < 4; ++j) { m[j] = -1e30f; l[j] = 0.f; }

  const int srow = tid >> 2, sc0 = (tid & 3) * 2;
  const int kpair = tid & 31, dgrp = tid >> 5;
  short8v kr0, kr1, va, vb;
  auto loadt = [&](int kt) {
    const short* kbase = qkv + (size_t)(kt * 64 + srow) * 1536 + 512 + h * DH;
    kr0 = *(const short8v*)(kbase + sc0 * 8);
    kr1 = *(const short8v*)(kbase + sc0 * 8 + 8);
    const short* vbase = qkv + (size_t)(kt * 64 + 2 * kpair) * 1536 + 1024 + h * DH + dgrp * 8;
    va = *(const short8v*)(vbase);
    vb = *(const short8v*)(vbase + 1536);
  };
  auto storet = [&](int cu) {
    short* dk = &Ks[cu][srow * 64];
    *(short8v*)(dk + ((sc0 ^ (srow & 7)) << 3)) = kr0;
    *(short8v*)(dk + (((sc0 + 1) ^ (srow & 7)) << 3)) = kr1;
#pragma unroll
    for (int i = 0; i < 8; ++i) {
      unsigned u = ((unsigned)(unsigned short)va[i]) |
                   (((unsigned)(unsigned short)vb[i]) << 16);
      *(unsigned*)&Vt[cu][(dgrp * 8 + i) * 72 + 2 * kpair] = u;
    }
  };

  loadt(0);
  int cur = 0;
  for (int kt = 0; kt < 32; ++kt) {
    storet(cur);
    __syncthreads();
    if (kt < 31) loadt(kt + 1);
    f32x4 sac[4] = {};
#pragma unroll
    for (int ks = 0; ks < 2; ++ks) {
#pragma unroll
      for (int ct = 0; ct < 4; ++ct) {
        const int row = ct * 16 + fr;
        short8v bfr = *(const short8v*)&Ks[cur][row * 64 + (((ks * 4 + kg) ^ (row & 7)) << 3)];
        sac[ct] = __builtin_amdgcn_mfma_f32_16x16x32_bf16(qf[ks], bfr, sac[ct], 0, 0, 0);
      }
    }
#pragma unroll
    for (int ct = 0; ct < 4; ++ct) sac[ct] *= 0.125f;
    float pv[4][4];
#pragma unroll
    for (int j = 0; j < 4; ++j) {
      float v = fmaxf(fmaxf(sac[0][j], sac[1][j]), fmaxf(sac[2][j], sac[3][j]));
#pragma unroll
      for (int off = 1; off < 16; off <<= 1) v = fmaxf(v, __shfl_xor(v, off, 64));
      float mn = fmaxf(m[j], v);
      float f = __expf(m[j] - mn);
      m[j] = mn;
      float rs = 0.f;
#pragma unroll
      for (int ct = 0; ct < 4; ++ct) {
        pv[ct][j] = __expf(sac[ct][j] - mn);
        rs += pv[ct][j];
      }
#pragma unroll
      for (int off = 1; off < 16; off <<= 1) rs += __shfl_xor(rs, off, 64);
      l[j] = l[j] * f + rs;
#pragma unroll
      for (int ct = 0; ct < 4; ++ct) oac[ct][j] *= f;
    }
#pragma unroll
    for (int ct = 0; ct < 4; ++ct)
#pragma unroll
      for (int j = 0; j < 4; ++j)
        Pl[wq][(kg * 4 + j) * 72 + ct * 16 + fr] = (short)f2bf(pv[ct][j]);
#pragma unroll
    for (int ks = 0; ks < 2; ++ks) {
      short8v paf = *(const short8v*)&Pl[wq][fr * 72 + ks * 32 + kg * 8];
#pragma unroll
      for (int ct = 0; ct < 4; ++ct) {
        short8v vf = *(const short8v*)&Vt[cur][(ct * 16 + fr) * 72 + ks * 32 + kg * 8];
        oac[ct] = __builtin_amdgcn_mfma_f32_16x16x32_bf16(paf, vf, oac[ct], 0, 0, 0);
      }
    }
    cur ^= 1;
  }
#pragma unroll
  for (int j = 0; j < 4; ++j) {
    float inv = 1.f / l[j];
    const int q = bq + wq * 16 + kg * 4 + j;
#pragma unroll
    for (int ct = 0; ct < 4; ++ct)
      ob[(size_t)q * D_MODEL + h * DH + ct * 16 + fr] = (short)f2bf(oac[ct][j] * inv);
  }
}

// ---------------- residual + layernorm ----------------
__global__ __launch_bounds__(128) void k_ln(const float* __restrict__ a,
                                            const float* __restrict__ r,
                                            const float* __restrict__ g,
                                            const float* __restrict__ b,
                                            float* __restrict__ out,
                                            short* __restrict__ outh) {
  __shared__ float red[2];
  const int row = blockIdx.x, tid = threadIdx.x;
  const size_t off = (size_t)row * D_MODEL + tid * 4;
  float4 av = *(const float4*)(a + off);
  float4 rv = *(const float4*)(r + off);
  float v0 = av.x + rv.x, v1 = av.y + rv.y, v2 = av.z + rv.z, v3 = av.w + rv.w;
  float s = v0 + v1 + v2 + v3;
#pragma unroll
  for (int d = 1; d < 64; d <<= 1) s += __shfl_xor(s, d, 64);
  if ((tid & 63) == 0) red[tid >> 6] = s;
  __syncthreads();
  float mean = (red[0] + red[1]) * (1.f / 512.f);
  __syncthreads();
  float d0 = v0 - mean, d1 = v1 - mean, d2 = v2 - mean, d3 = v3 - mean;
  float sq = d0 * d0 + d1 * d1 + d2 * d2 + d3 * d3;
#pragma unroll
  for (int d = 1; d < 64; d <<= 1) sq += __shfl_xor(sq, d, 64);
  if ((tid & 63) == 0) red[tid >> 6] = sq;
  __syncthreads();
  float inv = rsqrtf((red[0] + red[1]) * (1.f / 512.f) + 1e-5f);
  float4 gv = *(const float4*)(g + tid * 4);
  float4 bv = *(const float4*)(b + tid * 4);
  float4 o;
  o.x = d0 * inv * gv.x + bv.x;
  o.y = d1 * inv * gv.y + bv.y;
  o.z = d2 * inv * gv.z + bv.z;
  o.w = d3 * inv * gv.w + bv.w;
  *(float4*)(out + off) = o;
  if (outh) {
    uint2v t;
    t[0] = cvtpk(o.x, o.y);
    t[1] = cvtpk(o.z, o.w);
    *(uint2v*)(outh + off) = t;
  }
}

// ---------------- emission scores feats = x2 * Wt^T + bt ----------------
__global__ __launch_bounds__(256) void k_feats(const float* __restrict__ x2,
                                               const float* __restrict__ Wt,
                                               const float* __restrict__ bt,
                                               float* __restrict__ feats) {
  const int tid = threadIdx.x;
  const int s = blockIdx.x * 8 + (tid >> 5);
  const int l = tid & 31;
  const float* xr = x2 + (size_t)s * D_MODEL;
  const float* wr = Wt + (size_t)l * D_MODEL;
  float acc = 0.f;
#pragma unroll 8
  for (int k = 0; k < D_MODEL; k += 4) {
    float4 xv = *(const float4*)(xr + k);
    float4 wv = *(const float4*)(wr + k);
    acc += xv.x * wv.x + xv.y * wv.y + xv.z * wv.z + xv.w * wv.w;
  }
  feats[s * L_TAGS + l] = acc + bt[l];
}

// ============ Viterbi via chunked max-plus scan ============
__global__ __launch_bounds__(64) void k_scan1(const float* __restrict__ feats,
                                              const float* __restrict__ T,
                                              float* __restrict__ P) {
  __shared__ float S[2][32];
  const int c = blockIdx.x >> 4;
  const int l = threadIdx.x;
  const int n = l & 31, pl = l >> 5;
  const int p = (blockIdx.x & 15) * 2 + pl;
  float Trow[32];
#pragma unroll
  for (int q = 0; q < 32; ++q) Trow[q] = T[n * 32 + q];
  const int tbase = c * 32;
  float er[4];
#pragma unroll
  for (int i = 0; i < 4; ++i) er[i] = feats[(tbase + i) * 32 + n];
  float a = T[n * 32 + p] + er[0];
  S[pl][n] = a;
  const float* fp = feats + (size_t)(tbase + 4) * 32 + n;
  er[0] = fp[0]; fp += 32;
  for (int u = 1; u < 32; ++u) {
    float e = er[u & 3];
    float enew = fp[0]; fp += 32;
    const float4* Sv = (const float4*)&S[pl][0];
    float g[32];
#pragma unroll
    for (int j4 = 0; j4 < 8; ++j4) {
      float4 sv = Sv[j4];
      g[j4 * 4 + 0] = sv.x + Trow[j4 * 4 + 0];
      g[j4 * 4 + 1] = sv.y + Trow[j4 * 4 + 1];
      g[j4 * 4 + 2] = sv.z + Trow[j4 * 4 + 2];
      g[j4 * 4 + 3] = sv.w + Trow[j4 * 4 + 3];
    }
#pragma unroll
    for (int st = 1; st < 32; st <<= 1)
#pragma unroll
      for (int j = 0; j < 32; j += 2 * st) g[j] = fmaxf(g[j], g[j + st]);
    a = g[0] + e;
    S[pl][n] = a;
    er[u & 3] = enew;
  }
  P[(size_t)c * 1024 + n * 32 + p] = a;
}

__global__ __launch_bounds__(64) void k_scan2(const float* __restrict__ P,
                                              const float* __restrict__ T,
                                              float* __restrict__ alphas,
                                              float* __restrict__ out,
                                              int* __restrict__ bestp) {
  __shared__ float Sa[32];
  const int l = threadIdx.x, n = l & 31, half = l >> 5;
  float a = (n == START_TAG) ? 0.f : NEGV;
  const float* pbase = P + n * 32 + half * 16;
  float4 pr[4];
#pragma unroll
  for (int j = 0; j < 4; ++j) pr[j] = *(const float4*)(pbase + j * 4);
  for (int c = 0; c < 64; ++c) {
    float4 nx[4];
#pragma unroll
    for (int j = 0; j < 4; ++j)
      nx[j] = *(const float4*)(pbase + (size_t)(c + 1) * 1024 + j * 4);
    alphas[(size_t)(c * 32) * 32 + n] = a;
    Sa[n] = a;
    const float4* Sv = (const float4*)&Sa[half * 16];
    float g[16];
#pragma unroll
    for (int j = 0; j < 4; ++j) {
      float4 sv = Sv[j];
      g[j * 4 + 0] = pr[j].x + sv.x;
      g[j * 4 + 1] = pr[j].y + sv.y;
      g[j * 4 + 2] = pr[j].z + sv.z;
      g[j * 4 + 3] = pr[j].w + sv.w;
    }
#pragma unroll
    for (int st = 1; st < 16; st <<= 1)
#pragma unroll
      for (int j = 0; j < 16; j += 2 * st) g[j] = fmaxf(g[j], g[j + st]);
    uint2v r = __builtin_amdgcn_permlane32_swap(__float_as_uint(g[0]),
                                                __float_as_uint(g[0]), false, false);
    a = fmaxf(__uint_as_float(r[0]), __uint_as_float(r[1]));
#pragma unroll
    for (int j = 0; j < 4; ++j) pr[j] = nx[j];
  }
  float term = a + T[STOP_TAG * 32 + n];
  float bv = term;
  int bi = n;
#pragma unroll
  for (int d = 1; d < 32; d <<= 1) {
    float ov = __shfl_xor(bv, d, 64);
    int oi = __shfl_xor(bi, d, 64);
    if (ov > bv || (ov == bv && oi < bi)) { bv = ov; bi = oi; }
  }
  if (l == 0) { out[0] = bv; *bestp = bi; }
}

__global__ __launch_bounds__(64) void k_scan3(const float* __restrict__ feats,
                                              const float* __restrict__ T,
                                              float* __restrict__ alphas) {
  __shared__ float Sa[32];
  const int c = blockIdx.x, l = threadIdx.x, n = l & 31, half = l >> 5;
  float Tr[16];
#pragma unroll
  for (int j = 0; j < 16; ++j) Tr[j] = T[n * 32 + half * 16 + j];
  const int tbase = c * 32;
  float a = alphas[(size_t)tbase * 32 + n];
  float er[4];
#pragma unroll
  for (int i = 0; i < 4; ++i) er[i] = feats[(tbase + i) * 32 + n];
  const float* fp = feats + (size_t)(tbase + 4) * 32 + n;
  Sa[n] = a;
  for (int u = 0; u < 31; ++u) {
    float e = er[u & 3];
    float enew = fp[0]; fp += 32;
    const float4* Sv = (const float4*)&Sa[half * 16];
    float4 s0 = Sv[0], s1 = Sv[1], s2 = Sv[2], s3 = Sv[3];
    float g[16] = {s0.x + Tr[0],  s0.y + Tr[1],  s0.z + Tr[2],  s0.w + Tr[3],
                   s1.x + Tr[4],  s1.y + Tr[5],  s1.z + Tr[6],  s1.w + Tr[7],
                   s2.x + Tr[8],  s2.y + Tr[9],  s2.z + Tr[10], s2.w + Tr[11],
                   s3.x + Tr[12], s3.y + Tr[13], s3.z + Tr[14], s3.w + Tr[15]};
#pragma unroll
    for (int st = 1; st < 16; st <<= 1)
#pragma unroll
      for (int j = 0; j < 16; j += 2 * st) g[j] = fmaxf(g[j], g[j + st]);
    uint2v r = __builtin_amdgcn_permlane32_swap(__float_as_uint(g[0]),
                                                __float_as_uint(g[0]), false, false);
    a = fmaxf(__uint_as_float(r[0]), __uint_as_float(r[1])) + e;
    alphas[(size_t)(tbase + u + 1) * 32 + n] = a;
    Sa[n] = a;
    er[u & 3] = enew;
  }
}

// ---------------- backpointers ----------------
__global__ __launch_bounds__(256) void k_vit_bp(const float* __restrict__ alphas,
                                                const float* __restrict__ T,
                                                unsigned char* __restrict__ bp) {
  __shared__ float Ts[32][33];
  __shared__ float Al[8][32];
  const int tid = threadIdx.x;
  for (int i = tid; i < 1024; i += 256) Ts[i >> 5][i & 31] = T[i];
  const int t0 = blockIdx.x * 8;
  Al[tid >> 5][tid & 31] = alphas[t0 * 32 + tid];
  __syncthreads();
  const int tl = tid >> 5, n = tid & 31;
  float best = -3e38f;
  int bi = 0;
#pragma unroll
  for (int p = 0; p < 32; ++p) {
    float v = Al[tl][p] + Ts[n][p];
    if (v > best) { best = v; bi = p; }
  }
  bp[(size_t)(t0 + tl) * 32 + n] = (unsigned char)bi;
}

// ---------------- traceback phase 1: per-chunk walks in LDS ----------------
// block c: stage bp rows [c*32, c*32+31] (1KB) into LDS; 32 lanes walk the 32
// candidate end-tags; write cand chunk (1KB) + chunk map amap[c][e].
__global__ __launch_bounds__(256) void k_trace1(const unsigned char* __restrict__ bp,
                                                unsigned char* __restrict__ cand,
                                                unsigned char* __restrict__ amap) {
  __shared__ unsigned bplw[256];   // bp chunk as u32
  __shared__ unsigned cndw[256];   // cand chunk as u32
  const int c = blockIdx.x, tid = threadIdx.x;
  bplw[tid] = ((const unsigned*)(bp + (size_t)c * 1024))[tid];
  __syncthreads();
  if (tid < 32) {
    const unsigned char* bl = (const unsigned char*)bplw;
    unsigned char* cn = (unsigned char*)cndw;
    int tg = tid;
    cn[tid * 32 + 31] = (unsigned char)tg;
    for (int j = 31; j >= 1; --j) {
      tg = bl[j * 32 + tg];
      cn[tid * 32 + (j - 1)] = (unsigned char)tg;
    }
    amap[c * 32 + tid] = bl[tg];   // bp at local step 0
  }
  __syncthreads();
  ((unsigned*)(cand + (size_t)c * 1024))[tid] = cndw[tid];
}

// ---------------- traceback phase 2: compose maps + emit path ----------------
__global__ __launch_bounds__(256) void k_trace2(const unsigned char* __restrict__ amap,
                                                const unsigned char* __restrict__ cand,
                                                const int* __restrict__ bestp,
                                                float* __restrict__ outp) {
  __shared__ unsigned char Am[64][32];
  __shared__ unsigned char et[64];
  const int tid = threadIdx.x;
  ((unsigned*)&Am[0][0])[tid] = ((const unsigned*)amap)[tid];
  ((unsigned*)&Am[32][0])[tid] = ((const unsigned*)amap)[tid + 256];
  __syncthreads();
  for (int d = 1; d < 64; d <<= 1) {
    unsigned char tmpv[8];
#pragma unroll
    for (int i = 0; i < 8; ++i) {
      int id = tid + 256 * i;
      int cc = id >> 5, e = id & 31;
      tmpv[i] = (cc + d < 64) ? Am[cc][Am[cc + d][e]] : Am[cc][e];
    }
    __syncthreads();
#pragma unroll
    for (int i = 0; i < 8; ++i) {
      int id = tid + 256 * i;
      Am[id >> 5][id & 31] = tmpv[i];
    }
    __syncthreads();
  }
  const int best = *bestp;
  if (tid < 64) et[tid] = (tid == 63) ? (unsigned char)best : Am[tid + 1][best];
  __syncthreads();
#pragma unroll
  for (int i = 0; i < 8; ++i) {
    int t = tid + 256 * i;
    int cc = t >> 5, j = t & 31;
    outp[1 + t] = (float)cand[(size_t)cc * 1024 + (size_t)et[cc] * 32 + j];
  }
}

extern "C" void kernel_launch(void* const* d_in, const int* in_sizes, int n_in,
                              void* d_out, int out_size, void* d_ws, size_t ws_size,
                              hipStream_t stream) {
  (void)in_sizes; (void)n_in; (void)out_size; (void)ws_size;
  const int* sent = (const int*)d_in[0];
  const float* embed = (const float*)d_in[1];
  const float* Wqkv = (const float*)d_in[2];
  const float* bqkv = (const float*)d_in[3];
  const float* Wo = (const float*)d_in[4];
  const float* bo = (const float*)d_in[5];
  const float* g1 = (const float*)d_in[6];
  const float* b1n = (const float*)d_in[7];
  const float* W1 = (const float*)d_in[8];
  const float* b1f = (const float*)d_in[9];
  const float* W2 = (const float*)d_in[10];
  const float* b2f = (const float*)d_in[11];
  const float* g2 = (const float*)d_in[12];
  const float* b2n = (const float*)d_in[13];
  const float* Wt = (const float*)d_in[14];
  const float* bt = (const float*)d_in[15];
  const float* T = (const float*)d_in[16];
  float* out = (float*)d_out;

  float* ws = (float*)d_ws;
  const size_t M1 = 1u << 20;  // 1M floats = 4MB
  float* x = ws;
  short* xh = (short*)(ws + M1);
  short* qkvh = (short*)(ws + 3 * M1 / 2);
  short* obh = (short*)(ws + M1);
  float* yb = ws + 3 * M1 / 2;
  float* x1 = ws + 3 * M1;
  short* x1h = (short*)(ws + 5 * M1 / 2);
  short* ffbh = (short*)ws;
  float* zb = ws + 2 * M1;
  float* x2 = ws;
  short* wqkvh = (short*)(ws + 4 * M1);
  short* woh = wqkvh + 786432;
  short* w1h = woh + 262144;
  short* w2h = w1h + 1048576;
  float* feats = ws + 4 * M1 + 3 * M1 / 2;
  float* alphas = feats + 2048 * 32 + 64;
  float* P = alphas + 2049 * 32 + 64;
  int* bestp = (int*)(P + 65 * 1024 + 64);
  unsigned char* bp = (unsigned char*)(bestp + 64);
  unsigned char* cand = bp + 2048 * 32;
  unsigned char* amap = cand + 2048 * 32;

  k_f2h<<<dim3(384), dim3(256), 0, stream>>>(Wqkv, wqkvh, 98304);
  k_f2h<<<dim3(128), dim3(256), 0, stream>>>(Wo, woh, 32768);
  k_f2h<<<dim3(512), dim3(256), 0, stream>>>(W1, w1h, 131072);
  k_f2h<<<dim3(512), dim3(256), 0, stream>>>(W2, w2h, 131072);
  k_embed<<<dim3(2048), dim3(128), 0, stream>>>(sent, embed, x, xh);
  k_gemm_bf<4, false, true><<<dim3(12, 16), dim3(256), 0, stream>>>(xh, wqkvh, bqkv, qkvh, 2048, 1536, 512);
  k_attn<<<dim3(256), dim3(256), 0, stream>>>(qkvh, obh);
  k_gemm_bf<2, false, false><<<dim3(8, 32), dim3(256), 0, stream>>>(obh, woh, bo, yb, 2048, 512, 512);
  k_ln<<<dim3(2048), dim3(128), 0, stream>>>(x, yb, g1, b1n, x1, x1h);
  k_gemm_bf<4, true, true><<<dim3(16, 16), dim3(256), 0, stream>>>(x1h, w1h, b1f, ffbh, 2048, 2048, 512);
  k_gemm_bf<2, false, false><<<dim3(8, 32), dim3(256), 0, stream>>>(ffbh, w2h, b2f, zb, 2048, 512, 2048);
  k_ln<<<dim3(2048), dim3(128), 0, stream>>>(x1, zb, g2, b2n, x2, (short*)nullptr);
  k_feats<<<dim3(256), dim3(256), 0, stream>>>(x2, Wt, bt, feats);
  k_scan1<<<dim3(1024), dim3(64), 0, stream>>>(feats, T, P);
  k_scan2<<<dim3(1), dim3(64), 0, stream>>>(P, T, alphas, out, bestp);
  k_scan3<<<dim3(64), dim3(64), 0, stream>>>(feats, T, alphas);
  k_vit_bp<<<dim3(256), dim3(256), 0, stream>>>(alphas, T, bp);
  k_trace1<<<dim3(64), dim3(256), 0, stream>>>(bp, cand, amap);
  k_trace2<<<dim3(1), dim3(256), 0, stream>>>(amap, cand, bestp, out);
}

// Round 11
// 187.286 us; speedup vs baseline: 4.9598x; 1.0639x over previous
//
#include <hip/hip_runtime.h>
#include <cstddef>

#define S_LEN 2048
#define D_MODEL 512
#define NHEAD 8
#define DH 64
#define FF_DIM 2048
#define L_TAGS 32
#define START_TAG 30
#define STOP_TAG 31
#define NEGV (-10000.0f)

typedef unsigned int uint2v __attribute__((ext_vector_type(2)));
typedef __attribute__((ext_vector_type(8))) short short8v;   // 8 bf16 = 4 VGPR
typedef __attribute__((ext_vector_type(4))) float f32x4;

union U8 { uint4 u; short8v s; };

__device__ __forceinline__ unsigned short f2bf(float f) {
  unsigned u = __float_as_uint(f);
  u += 0x7fff + ((u >> 16) & 1);   // RTNE
  return (unsigned short)(u >> 16);
}
__device__ __forceinline__ unsigned cvtpk(float lo, float hi) {
  unsigned r;
  asm("v_cvt_pk_bf16_f32 %0, %1, %2" : "=v"(r) : "v"(lo), "v"(hi));
  return r;
}

// ---------------- fused f32 -> bf16 weight converts (4 tensors, 1 launch) ----------------
__global__ __launch_bounds__(256) void k_f2h4(const float* __restrict__ s0, short* __restrict__ d0,
                                              const float* __restrict__ s1, short* __restrict__ d1,
                                              const float* __restrict__ s2, short* __restrict__ d2,
                                              const float* __restrict__ s3, short* __restrict__ d3) {
  const int b = blockIdx.x;
  const float* src; short* dst; int i;
  if (b < 384)       { src = s0; dst = d0; i = b * 256 + threadIdx.x; }          // Wqkv 98304
  else if (b < 512)  { src = s1; dst = d1; i = (b - 384) * 256 + threadIdx.x; }  // Wo 32768
  else if (b < 1024) { src = s2; dst = d2; i = (b - 512) * 256 + threadIdx.x; }  // W1 131072
  else               { src = s3; dst = d3; i = (b - 1024) * 256 + threadIdx.x; } // W2 131072
  f32x4 a = *(const f32x4*)(src + (size_t)i * 8);
  f32x4 c = *(const f32x4*)(src + (size_t)i * 8 + 4);
  U8 t;
  t.u.x = cvtpk(a[0], a[1]); t.u.y = cvtpk(a[2], a[3]);
  t.u.z = cvtpk(c[0], c[1]); t.u.w = cvtpk(c[2], c[3]);
  *(short8v*)(dst + (size_t)i * 8) = t.s;
}

// ======== QKV GEMM with fused embedding gather: C = embed[sent[m]] * B^T + bias ========
// 128x128 tile, A rows gathered from f32 embed and converted during staging.
__global__ __launch_bounds__(256, 2) void k_gemm_qkv(const int* __restrict__ sent,
                                                     const float* __restrict__ embed,
                                                     const short* __restrict__ B,
                                                     const float* __restrict__ bias,
                                                     short* __restrict__ C,
                                                     int N, int K) {
  __shared__ __align__(16) short As[2][128 * 64];
  __shared__ __align__(16) short Bs[2][128 * 64];
  const int tid = threadIdx.x;
  const int bm = blockIdx.y * 128, bn = blockIdx.x * 128;
  const int w = tid >> 6, lane = tid & 63;
  const int wr = w >> 1, wc = w & 1;
  const int fr = lane & 15, kg = lane >> 4;
  const int srow = tid >> 1, sc0 = (tid & 1) * 4;
  const int swz = srow & 7;
  const float* gA = embed + (size_t)sent[bm + srow] * K + sc0 * 8;
  const short* gB = B + (size_t)(bn + srow) * K + sc0 * 8;
  f32x4 ra[8];
  short8v rb[4];
  f32x4 acc[4][4] = {};

  auto loadg = [&](int k0) {
#pragma unroll
    for (int c = 0; c < 4; ++c) {
      ra[2 * c] = *(const f32x4*)(gA + k0 + c * 8);
      ra[2 * c + 1] = *(const f32x4*)(gA + k0 + c * 8 + 4);
      rb[c] = *(const short8v*)(gB + k0 + c * 8);
    }
  };
  auto storeb = [&](int b) {
    short* dA = &As[b][srow * 64];
    short* dB = &Bs[b][srow * 64];
#pragma unroll
    for (int c = 0; c < 4; ++c) {
      U8 ta;
      ta.u.x = cvtpk(ra[2 * c][0], ra[2 * c][1]);
      ta.u.y = cvtpk(ra[2 * c][2], ra[2 * c][3]);
      ta.u.z = cvtpk(ra[2 * c + 1][0], ra[2 * c + 1][1]);
      ta.u.w = cvtpk(ra[2 * c + 1][2], ra[2 * c + 1][3]);
      *(short8v*)(dA + (((sc0 + c) ^ swz) << 3)) = ta.s;
      *(short8v*)(dB + (((sc0 + c) ^ swz) << 3)) = rb[c];
    }
  };

  loadg(0);
  storeb(0);
  __syncthreads();
  int cur = 0;
  const int fswz = fr & 7;
  for (int k0 = 0; k0 < K; k0 += 64) {
    const bool more = (k0 + 64) < K;
    if (more) loadg(k0 + 64);
    const short* rA = &As[cur][(wr * 64 + fr) * 64];
    const short* rB = &Bs[cur][(wc * 64 + fr) * 64];
#pragma unroll
    for (int ks = 0; ks < 2; ++ks) {
      const int co = ((ks * 4 + kg) ^ fswz) << 3;
      short8v af[4], bf[4];
#pragma unroll
      for (int rt = 0; rt < 4; ++rt) af[rt] = *(const short8v*)(rA + rt * 16 * 64 + co);
#pragma unroll
      for (int ct = 0; ct < 4; ++ct) bf[ct] = *(const short8v*)(rB + ct * 16 * 64 + co);
#pragma unroll
      for (int rt = 0; rt < 4; ++rt)
#pragma unroll
        for (int ct = 0; ct < 4; ++ct)
          acc[rt][ct] = __builtin_amdgcn_mfma_f32_16x16x32_bf16(af[rt], bf[ct], acc[rt][ct], 0, 0, 0);
    }
    if (more) storeb(cur ^ 1);
    __syncthreads();
    cur ^= 1;
  }
#pragma unroll
  for (int rt = 0; rt < 4; ++rt) {
#pragma unroll
    for (int ct = 0; ct < 4; ++ct) {
      f32x4 v = acc[rt][ct];
      const int row0 = bm + wr * 64 + rt * 16 + kg * 4;
      const int col = bn + wc * 64 + ct * 16 + fr;
      const float bs = bias[col];
#pragma unroll
      for (int j = 0; j < 4; ++j)
        C[(size_t)(row0 + j) * N + col] = (short)f2bf(v[j] + bs);
    }
  }
}

// ======== bf16 MFMA GEMM: C = A[M][K] * B[N][K]^T + bias (A,B bf16) ========
template <int RT, bool RELU, bool OBF>
__global__ __launch_bounds__(256, 2) void k_gemm_bf(const short* __restrict__ A,
                                                    const short* __restrict__ B,
                                                    const float* __restrict__ bias,
                                                    void* __restrict__ Cp,
                                                    int M, int N, int K) {
  constexpr int BM = RT * 32;
  constexpr int CH = (BM * 8) / 256;
  __shared__ __align__(16) short As[2][BM * 64];
  __shared__ __align__(16) short Bs[2][BM * 64];
  const int tid = threadIdx.x;
  const int bm = blockIdx.y * BM, bn = blockIdx.x * BM;
  const int w = tid >> 6, lane = tid & 63;
  const int wr = w >> 1, wc = w & 1;
  const int fr = lane & 15, kg = lane >> 4;
  const int srow = (RT == 4) ? (tid >> 1) : (tid >> 2);
  const int sc0 = (RT == 4) ? ((tid & 1) * 4) : ((tid & 3) * 2);
  const int swz = srow & 7;
  const short* gA = A + (size_t)(bm + srow) * K + sc0 * 8;
  const short* gB = B + (size_t)(bn + srow) * K + sc0 * 8;
  short8v ra[CH], rb[CH];
  f32x4 acc[RT][RT] = {};

  auto loadg = [&](int k0) {
#pragma unroll
    for (int c = 0; c < CH; ++c) {
      ra[c] = *(const short8v*)(gA + k0 + c * 8);
      rb[c] = *(const short8v*)(gB + k0 + c * 8);
    }
  };
  auto storeb = [&](int b) {
    short* dA = &As[b][srow * 64];
    short* dB = &Bs[b][srow * 64];
#pragma unroll
    for (int c = 0; c < CH; ++c) {
      *(short8v*)(dA + (((sc0 + c) ^ swz) << 3)) = ra[c];
      *(short8v*)(dB + (((sc0 + c) ^ swz) << 3)) = rb[c];
    }
  };

  loadg(0);
  storeb(0);
  __syncthreads();
  int cur = 0;
  const int fswz = fr & 7;
  for (int k0 = 0; k0 < K; k0 += 64) {
    const bool more = (k0 + 64) < K;
    if (more) loadg(k0 + 64);
    const short* rA = &As[cur][(wr * (RT * 16) + fr) * 64];
    const short* rB = &Bs[cur][(wc * (RT * 16) + fr) * 64];
#pragma unroll
    for (int ks = 0; ks < 2; ++ks) {
      const int co = ((ks * 4 + kg) ^ fswz) << 3;
      short8v af[RT], bf[RT];
#pragma unroll
      for (int rt = 0; rt < RT; ++rt) af[rt] = *(const short8v*)(rA + rt * 16 * 64 + co);
#pragma unroll
      for (int ct = 0; ct < RT; ++ct) bf[ct] = *(const short8v*)(rB + ct * 16 * 64 + co);
#pragma unroll
      for (int rt = 0; rt < RT; ++rt)
#pragma unroll
        for (int ct = 0; ct < RT; ++ct)
          acc[rt][ct] = __builtin_amdgcn_mfma_f32_16x16x32_bf16(af[rt], bf[ct], acc[rt][ct], 0, 0, 0);
    }
    if (more) storeb(cur ^ 1);
    __syncthreads();
    cur ^= 1;
  }
#pragma unroll
  for (int rt = 0; rt < RT; ++rt) {
#pragma unroll
    for (int ct = 0; ct < RT; ++ct) {
      f32x4 v = acc[rt][ct];
      const int row0 = bm + wr * (RT * 16) + rt * 16 + kg * 4;
      const int col = bn + wc * (RT * 16) + ct * 16 + fr;
      const float bs = bias[col];
#pragma unroll
      for (int j = 0; j < 4; ++j) {
        float o = v[j] + bs;
        if (RELU) o = fmaxf(o, 0.f);
        if (OBF)
          ((short*)Cp)[(size_t)(row0 + j) * N + col] = (short)f2bf(o);
        else
          ((float*)Cp)[(size_t)(row0 + j) * N + col] = o;
      }
    }
  }
}

// ======== fused attention v4: bf16 MFMA flash, L2-local per head ========
__global__ __launch_bounds__(256) void k_attn(const short* __restrict__ qkv,
                                              short* __restrict__ ob) {
  __shared__ __align__(16) short Ks[2][64 * 64];
  __shared__ __align__(16) short Vt[2][64 * 72];
  __shared__ __align__(16) short Pl[4][16 * 72];
  const int tid = threadIdx.x;
  const int b = blockIdx.x;
  const int h = b & 7;
  const int bq = (b >> 3) * 64;
  const int wq = tid >> 6, lane = tid & 63;
  const int fr = lane & 15, kg = lane >> 4;
  short8v qf[2];
  {
    const short* qsrc = qkv + (size_t)(bq + wq * 16 + fr) * 1536 + h * DH;
    qf[0] = *(const short8v*)(qsrc + kg * 8);
    qf[1] = *(const short8v*)(qsrc + 32 + kg * 8);
  }
  float m[4], l[4];
  f32x4 oac[4] = {};
#pragma unroll
  for (int j = 0; j < 4; ++j) { m[j] = -1e30f; l[j] = 0.f; }

  const int srow = tid >> 2, sc0 = (tid & 3) * 2;
  const int kpair = tid & 31, dgrp = tid >> 5;
  short8v kr0, kr1, va, vb;
  auto loadt = [&](int kt) {
    const short* kbase = qkv + (size_t)(kt * 64 + srow) * 1536 + 512 + h * DH;
    kr0 = *(const short8v*)(kbase + sc0 * 8);
    kr1 = *(const short8v*)(kbase + sc0 * 8 + 8);
    const short* vbase = qkv + (size_t)(kt * 64 + 2 * kpair) * 1536 + 1024 + h * DH + dgrp * 8;
    va = *(const short8v*)(vbase);
    vb = *(const short8v*)(vbase + 1536);
  };
  auto storet = [&](int cu) {
    short* dk = &Ks[cu][srow * 64];
    *(short8v*)(dk + ((sc0 ^ (srow & 7)) << 3)) = kr0;
    *(short8v*)(dk + (((sc0 + 1) ^ (srow & 7)) << 3)) = kr1;
#pragma unroll
    for (int i = 0; i < 8; ++i) {
      unsigned u = ((unsigned)(unsigned short)va[i]) |
                   (((unsigned)(unsigned short)vb[i]) << 16);
      *(unsigned*)&Vt[cu][(dgrp * 8 + i) * 72 + 2 * kpair] = u;
    }
  };

  loadt(0);
  int cur = 0;
  for (int kt = 0; kt < 32; ++kt) {
    storet(cur);
    __syncthreads();
    if (kt < 31) loadt(kt + 1);
    f32x4 sac[4] = {};
#pragma unroll
    for (int ks = 0; ks < 2; ++ks) {
#pragma unroll
      for (int ct = 0; ct < 4; ++ct) {
        const int row = ct * 16 + fr;
        short8v bfr = *(const short8v*)&Ks[cur][row * 64 + (((ks * 4 + kg) ^ (row & 7)) << 3)];
        sac[ct] = __builtin_amdgcn_mfma_f32_16x16x32_bf16(qf[ks], bfr, sac[ct], 0, 0, 0);
      }
    }
#pragma unroll
    for (int ct = 0; ct < 4; ++ct) sac[ct] *= 0.125f;
    float pv[4][4];
#pragma unroll
    for (int j = 0; j < 4; ++j) {
      float v = fmaxf(fmaxf(sac[0][j], sac[1][j]), fmaxf(sac[2][j], sac[3][j]));
#pragma unroll
      for (int off = 1; off < 16; off <<= 1) v = fmaxf(v, __shfl_xor(v, off, 64));
      float mn = fmaxf(m[j], v);
      float f = __expf(m[j] - mn);
      m[j] = mn;
      float rs = 0.f;
#pragma unroll
      for (int ct = 0; ct < 4; ++ct) {
        pv[ct][j] = __expf(sac[ct][j] - mn);
        rs += pv[ct][j];
      }
#pragma unroll
      for (int off = 1; off < 16; off <<= 1) rs += __shfl_xor(rs, off, 64);
      l[j] = l[j] * f + rs;
#pragma unroll
      for (int ct = 0; ct < 4; ++ct) oac[ct][j] *= f;
    }
#pragma unroll
    for (int ct = 0; ct < 4; ++ct)
#pragma unroll
      for (int j = 0; j < 4; ++j)
        Pl[wq][(kg * 4 + j) * 72 + ct * 16 + fr] = (short)f2bf(pv[ct][j]);
#pragma unroll
    for (int ks = 0; ks < 2; ++ks) {
      short8v paf = *(const short8v*)&Pl[wq][fr * 72 + ks * 32 + kg * 8];
#pragma unroll
      for (int ct = 0; ct < 4; ++ct) {
        short8v vf = *(const short8v*)&Vt[cur][(ct * 16 + fr) * 72 + ks * 32 + kg * 8];
        oac[ct] = __builtin_amdgcn_mfma_f32_16x16x32_bf16(paf, vf, oac[ct], 0, 0, 0);
      }
    }
    cur ^= 1;
  }
#pragma unroll
  for (int j = 0; j < 4; ++j) {
    float inv = 1.f / l[j];
    const int q = bq + wq * 16 + kg * 4 + j;
#pragma unroll
    for (int ct = 0; ct < 4; ++ct)
      ob[(size_t)q * D_MODEL + h * DH + ct * 16 + fr] = (short)f2bf(oac[ct][j] * inv);
  }
}

// ---------------- residual + layernorm; optional gathered residual ----------------
__global__ __launch_bounds__(128) void k_ln(const float* __restrict__ a,
                                            const int* __restrict__ sent,
                                            const float* __restrict__ embed,
                                            const float* __restrict__ r,
                                            const float* __restrict__ g,
                                            const float* __restrict__ b,
                                            float* __restrict__ out,
                                            short* __restrict__ outh) {
  __shared__ float red[2];
  const int row = blockIdx.x, tid = threadIdx.x;
  const size_t off = (size_t)row * D_MODEL + tid * 4;
  float4 av;
  if (sent)
    av = *(const float4*)(embed + (size_t)sent[row] * D_MODEL + tid * 4);
  else
    av = *(const float4*)(a + off);
  float4 rv = *(const float4*)(r + off);
  float v0 = av.x + rv.x, v1 = av.y + rv.y, v2 = av.z + rv.z, v3 = av.w + rv.w;
  float s = v0 + v1 + v2 + v3;
#pragma unroll
  for (int d = 1; d < 64; d <<= 1) s += __shfl_xor(s, d, 64);
  if ((tid & 63) == 0) red[tid >> 6] = s;
  __syncthreads();
  float mean = (red[0] + red[1]) * (1.f / 512.f);
  __syncthreads();
  float d0 = v0 - mean, d1 = v1 - mean, d2 = v2 - mean, d3 = v3 - mean;
  float sq = d0 * d0 + d1 * d1 + d2 * d2 + d3 * d3;
#pragma unroll
  for (int d = 1; d < 64; d <<= 1) sq += __shfl_xor(sq, d, 64);
  if ((tid & 63) == 0) red[tid >> 6] = sq;
  __syncthreads();
  float inv = rsqrtf((red[0] + red[1]) * (1.f / 512.f) + 1e-5f);
  float4 gv = *(const float4*)(g + tid * 4);
  float4 bv = *(const float4*)(b + tid * 4);
  float4 o;
  o.x = d0 * inv * gv.x + bv.x;
  o.y = d1 * inv * gv.y + bv.y;
  o.z = d2 * inv * gv.z + bv.z;
  o.w = d3 * inv * gv.w + bv.w;
  *(float4*)(out + off) = o;
  if (outh) {
    uint2v t;
    t[0] = cvtpk(o.x, o.y);
    t[1] = cvtpk(o.z, o.w);
    *(uint2v*)(outh + off) = t;
  }
}

// ---------------- emission scores feats = x2 * Wt^T + bt ----------------
__global__ __launch_bounds__(256) void k_feats(const float* __restrict__ x2,
                                               const float* __restrict__ Wt,
                                               const float* __restrict__ bt,
                                               float* __restrict__ feats) {
  const int tid = threadIdx.x;
  const int s = blockIdx.x * 8 + (tid >> 5);
  const int l = tid & 31;
  const float* xr = x2 + (size_t)s * D_MODEL;
  const float* wr = Wt + (size_t)l * D_MODEL;
  float acc = 0.f;
#pragma unroll 8
  for (int k = 0; k < D_MODEL; k += 4) {
    float4 xv = *(const float4*)(xr + k);
    float4 wv = *(const float4*)(wr + k);
    acc += xv.x * wv.x + xv.y * wv.y + xv.z * wv.z + xv.w * wv.w;
  }
  feats[s * L_TAGS + l] = acc + bt[l];
}

// ============ Viterbi via chunked max-plus scan ============
// phase 1: chunk products (column-wise), 64 chunks x 16 col-pair blocks.
__global__ __launch_bounds__(64) void k_scan1(const float* __restrict__ feats,
                                              const float* __restrict__ T,
                                              float* __restrict__ P) {
  __shared__ float S[2][32];
  const int c = blockIdx.x >> 4;
  const int l = threadIdx.x;
  const int n = l & 31, pl = l >> 5;
  const int p = (blockIdx.x & 15) * 2 + pl;
  float Trow[32];
#pragma unroll
  for (int q = 0; q < 32; ++q) Trow[q] = T[n * 32 + q];
  const int tbase = c * 32;
  float er[4];
#pragma unroll
  for (int i = 0; i < 4; ++i) er[i] = feats[(tbase + i) * 32 + n];
  float a = T[n * 32 + p] + er[0];
  S[pl][n] = a;
  const float* fp = feats + (size_t)(tbase + 4) * 32 + n;
  er[0] = fp[0]; fp += 32;
  for (int u = 1; u < 32; ++u) {
    float e = er[u & 3];
    float enew = fp[0]; fp += 32;
    const float4* Sv = (const float4*)&S[pl][0];
    float g[32];
#pragma unroll
    for (int j4 = 0; j4 < 8; ++j4) {
      float4 sv = Sv[j4];
      g[j4 * 4 + 0] = sv.x + Trow[j4 * 4 + 0];
      g[j4 * 4 + 1] = sv.y + Trow[j4 * 4 + 1];
      g[j4 * 4 + 2] = sv.z + Trow[j4 * 4 + 2];
      g[j4 * 4 + 3] = sv.w + Trow[j4 * 4 + 3];
    }
#pragma unroll
    for (int st = 1; st < 32; st <<= 1)
#pragma unroll
      for (int j = 0; j < 32; j += 2 * st) g[j] = fmaxf(g[j], g[j + st]);
    a = g[0] + e;
    S[pl][n] = a;
    er[u & 3] = enew;
  }
  P[(size_t)c * 1024 + n * 32 + p] = a;
}

// phase 2: boundary alphas + terminal score/argmax.
__global__ __launch_bounds__(64) void k_scan2(const float* __restrict__ P,
                                              const float* __restrict__ T,
                                              float* __restrict__ alphas,
                                              float* __restrict__ out,
                                              int* __restrict__ bestp) {
  __shared__ float Sa[32];
  const int l = threadIdx.x, n = l & 31, half = l >> 5;
  float a = (n == START_TAG) ? 0.f : NEGV;
  const float* pbase = P + n * 32 + half * 16;
  float4 pr[4];
#pragma unroll
  for (int j = 0; j < 4; ++j) pr[j] = *(const float4*)(pbase + j * 4);
  for (int c = 0; c < 64; ++c) {
    float4 nx[4];
#pragma unroll
    for (int j = 0; j < 4; ++j)
      nx[j] = *(const float4*)(pbase + (size_t)(c + 1) * 1024 + j * 4);
    alphas[(size_t)(c * 32) * 32 + n] = a;
    Sa[n] = a;
    const float4* Sv = (const float4*)&Sa[half * 16];
    float g[16];
#pragma unroll
    for (int j = 0; j < 4; ++j) {
      float4 sv = Sv[j];
      g[j * 4 + 0] = pr[j].x + sv.x;
      g[j * 4 + 1] = pr[j].y + sv.y;
      g[j * 4 + 2] = pr[j].z + sv.z;
      g[j * 4 + 3] = pr[j].w + sv.w;
    }
#pragma unroll
    for (int st = 1; st < 16; st <<= 1)
#pragma unroll
      for (int j = 0; j < 16; j += 2 * st) g[j] = fmaxf(g[j], g[j + st]);
    uint2v r = __builtin_amdgcn_permlane32_swap(__float_as_uint(g[0]),
                                                __float_as_uint(g[0]), false, false);
    a = fmaxf(__uint_as_float(r[0]), __uint_as_float(r[1]));
#pragma unroll
    for (int j = 0; j < 4; ++j) pr[j] = nx[j];
  }
  float term = a + T[STOP_TAG * 32 + n];
  float bv = term;
  int bi = n;
#pragma unroll
  for (int d = 1; d < 32; d <<= 1) {
    float ov = __shfl_xor(bv, d, 64);
    int oi = __shfl_xor(bi, d, 64);
    if (ov > bv || (ov == bv && oi < bi)) { bv = ov; bi = oi; }
  }
  if (l == 0) { out[0] = bv; *bestp = bi; }
}

// phase 3 FUSED: per-chunk alphas + backpointers (argmax) + candidate walk.
// One wave per chunk; bp chunk lives entirely in LDS; emits cand (1KB) + amap.
__global__ __launch_bounds__(64) void k_scan3(const float* __restrict__ feats,
                                              const float* __restrict__ T,
                                              const float* __restrict__ alphas,
                                              unsigned char* __restrict__ cand,
                                              unsigned char* __restrict__ amap) {
  __shared__ float Sa[32];
  __shared__ unsigned char bpl[32][32];   // bpl[u][n]
  __shared__ unsigned cnd[256];
  const int c = blockIdx.x, l = threadIdx.x, n = l & 31, half = l >> 5;
  float Tr[16];
#pragma unroll
  for (int j = 0; j < 16; ++j) Tr[j] = T[n * 32 + half * 16 + j];
  const int tbase = c * 32;
  float a = alphas[(size_t)tbase * 32 + n];   // boundary from scan2
  float er[4];
#pragma unroll
  for (int i = 0; i < 4; ++i) er[i] = feats[(tbase + i) * 32 + n];
  const float* fp = feats + (size_t)(tbase + 4) * 32 + n;
  Sa[n] = a;   // single wave: DS ops are in-order, no barriers needed
  for (int u = 0; u < 32; ++u) {
    float e = er[u & 3];
    float enew = fp[0]; fp += 32;   // overreads past feats land in alphas: harmless
    const float4* Sv = (const float4*)&Sa[half * 16];
    float4 s0 = Sv[0], s1 = Sv[1], s2 = Sv[2], s3 = Sv[3];
    float v[16] = {s0.x + Tr[0],  s0.y + Tr[1],  s0.z + Tr[2],  s0.w + Tr[3],
                   s1.x + Tr[4],  s1.y + Tr[5],  s1.z + Tr[6],  s1.w + Tr[7],
                   s2.x + Tr[8],  s2.y + Tr[9],  s2.z + Tr[10], s2.w + Tr[11],
                   s3.x + Tr[12], s3.y + Tr[13], s3.z + Tr[14], s3.w + Tr[15]};
    int id[16];
#pragma unroll
    for (int j = 0; j < 16; ++j) id[j] = half * 16 + j;
    // tournament keeping lowest index on ties (j < j+st in p-order)
#pragma unroll
    for (int st = 1; st < 16; st <<= 1)
#pragma unroll
      for (int j = 0; j < 16; j += 2 * st)
        if (v[j + st] > v[j]) { v[j] = v[j + st]; id[j] = id[j + st]; }
    uint2v rv = __builtin_amdgcn_permlane32_swap(__float_as_uint(v[0]),
                                                 __float_as_uint(v[0]), false, false);
    uint2v ri = __builtin_amdgcn_permlane32_swap((unsigned)id[0], (unsigned)id[0],
                                                 false, false);
    float v0 = __uint_as_float(rv[0]), v1 = __uint_as_float(rv[1]);
    int i0 = (int)ri[0], i1 = (int)ri[1];
    // half0 (i0, p<16) wins ties -> lowest index
    float wv = (v1 > v0) ? v1 : v0;
    int wi = (v1 > v0) ? i1 : i0;
    bpl[u][n] = (unsigned char)wi;
    a = wv + e;
    Sa[n] = a;
    er[u & 3] = enew;
  }
  // candidate walk (both halves do identical work; same-value byte writes benign)
  unsigned char* cnb = (unsigned char*)cnd;
  int tg = n;
  cnb[n * 32 + 31] = (unsigned char)n;
  for (int j = 31; j >= 1; --j) {
    tg = bpl[j][tg];
    cnb[n * 32 + (j - 1)] = (unsigned char)tg;
  }
  if (half == 0) amap[c * 32 + n] = bpl[0][tg];
#pragma unroll
  for (int i = 0; i < 4; ++i)
    ((unsigned*)(cand + (size_t)c * 1024))[l * 4 + i] = cnd[l * 4 + i];
}

// traceback phase 2: compose chunk maps + emit path.
__global__ __launch_bounds__(256) void k_trace2(const unsigned char* __restrict__ amap,
                                                const unsigned char* __restrict__ cand,
                                                const int* __restrict__ bestp,
                                                float* __restrict__ outp) {
  __shared__ unsigned char Am[64][32];
  __shared__ unsigned char et[64];
  const int tid = threadIdx.x;
  ((unsigned*)&Am[0][0])[tid] = ((const unsigned*)amap)[tid];
  ((unsigned*)&Am[32][0])[tid] = ((const unsigned*)amap)[tid + 256];
  __syncthreads();
  for (int d = 1; d < 64; d <<= 1) {
    unsigned char tmpv[8];
#pragma unroll
    for (int i = 0; i < 8; ++i) {
      int id = tid + 256 * i;
      int cc = id >> 5, e = id & 31;
      tmpv[i] = (cc + d < 64) ? Am[cc][Am[cc + d][e]] : Am[cc][e];
    }
    __syncthreads();
#pragma unroll
    for (int i = 0; i < 8; ++i) {
      int id = tid + 256 * i;
      Am[id >> 5][id & 31] = tmpv[i];
    }
    __syncthreads();
  }
  const int best = *bestp;
  if (tid < 64) et[tid] = (tid == 63) ? (unsigned char)best : Am[tid + 1][best];
  __syncthreads();
#pragma unroll
  for (int i = 0; i < 8; ++i) {
    int t = tid + 256 * i;
    int cc = t >> 5, j = t & 31;
    outp[1 + t] = (float)cand[(size_t)cc * 1024 + (size_t)et[cc] * 32 + j];
  }
}

extern "C" void kernel_launch(void* const* d_in, const int* in_sizes, int n_in,
                              void* d_out, int out_size, void* d_ws, size_t ws_size,
                              hipStream_t stream) {
  (void)in_sizes; (void)n_in; (void)out_size; (void)ws_size;
  const int* sent = (const int*)d_in[0];
  const float* embed = (const float*)d_in[1];
  const float* Wqkv = (const float*)d_in[2];
  const float* bqkv = (const float*)d_in[3];
  const float* Wo = (const float*)d_in[4];
  const float* bo = (const float*)d_in[5];
  const float* g1 = (const float*)d_in[6];
  const float* b1n = (const float*)d_in[7];
  const float* W1 = (const float*)d_in[8];
  const float* b1f = (const float*)d_in[9];
  const float* W2 = (const float*)d_in[10];
  const float* b2f = (const float*)d_in[11];
  const float* g2 = (const float*)d_in[12];
  const float* b2n = (const float*)d_in[13];
  const float* Wt = (const float*)d_in[14];
  const float* bt = (const float*)d_in[15];
  const float* T = (const float*)d_in[16];
  float* out = (float*)d_out;

  float* ws = (float*)d_ws;
  const size_t M1 = 1u << 20;  // 1M floats = 4MB
  short* qkvh = (short*)ws;                 // bf16 [2048][1536] = 6MB
  short* obh = (short*)(ws + 2 * M1);       // bf16 [2048][512]  = 2MB
  float* yb = ws + 3 * M1;                  // f32  [2048][512]  = 4MB
  float* x1 = ws + 4 * M1;                  // f32
  short* x1h = (short*)(ws + 5 * M1);       // bf16
  short* ffbh = (short*)(ws + 6 * M1);      // bf16 [2048][2048] = 8MB
  float* zb = ws + 8 * M1;                  // f32
  float* x2 = ws + 9 * M1;                  // f32
  short* wqkvh = (short*)(ws + 10 * M1);    // 786432 shorts
  short* woh = wqkvh + 786432;              // 262144
  short* w1h = woh + 262144;                // 1048576
  short* w2h = w1h + 1048576;               // 1048576
  float* feats = ws + 11 * M1;              // [2048][32]
  float* alphas = feats + 2048 * 32 + 64;   // [2049][32] (boundaries used)
  float* P = alphas + 2049 * 32 + 64;       // [65][1024]
  int* bestp = (int*)(P + 65 * 1024 + 64);
  unsigned char* cand = (unsigned char*)(bestp + 64);  // [2048][32] u8
  unsigned char* amap = cand + 2048 * 32;              // [64][32] u8

  k_f2h4<<<dim3(1536), dim3(256), 0, stream>>>(Wqkv, wqkvh, Wo, woh, W1, w1h, W2, w2h);
  k_gemm_qkv<<<dim3(12, 16), dim3(256), 0, stream>>>(sent, embed, wqkvh, bqkv, qkvh, 1536, 512);
  k_attn<<<dim3(256), dim3(256), 0, stream>>>(qkvh, obh);
  k_gemm_bf<2, false, false><<<dim3(8, 32), dim3(256), 0, stream>>>(obh, woh, bo, yb, 2048, 512, 512);
  k_ln<<<dim3(2048), dim3(128), 0, stream>>>(nullptr, sent, embed, yb, g1, b1n, x1, x1h);
  k_gemm_bf<4, true, true><<<dim3(16, 16), dim3(256), 0, stream>>>(x1h, w1h, b1f, ffbh, 2048, 2048, 512);
  k_gemm_bf<2, false, false><<<dim3(8, 32), dim3(256), 0, stream>>>(ffbh, w2h, b2f, zb, 2048, 512, 2048);
  k_ln<<<dim3(2048), dim3(128), 0, stream>>>(x1, nullptr, nullptr, zb, g2, b2n, x2, (short*)nullptr);
  k_feats<<<dim3(256), dim3(256), 0, stream>>>(x2, Wt, bt, feats);
  k_scan1<<<dim3(1024), dim3(64), 0, stream>>>(feats, T, P);
  k_scan2<<<dim3(1), dim3(64), 0, stream>>>(P, T, alphas, out, bestp);
  k_scan3<<<dim3(64), dim3(64), 0, stream>>>(feats, T, alphas, cand, amap);
  k_trace2<<<dim3(1), dim3(256), 0, stream>>>(amap, cand, bestp, out);
}

// Round 12
// 179.092 us; speedup vs baseline: 5.1867x; 1.0458x over previous
//
#include <hip/hip_runtime.h>
#include <cstddef>

#define S_LEN 2048
#define D_MODEL 512
#define NHEAD 8
#define DH 64
#define FF_DIM 2048
#define L_TAGS 32
#define START_TAG 30
#define STOP_TAG 31
#define NEGV (-10000.0f)
#define QSCALE 0.18033688f   // 0.125 * log2(e)

typedef unsigned int uint2v __attribute__((ext_vector_type(2)));
typedef __attribute__((ext_vector_type(8))) short short8v;   // 8 bf16 = 4 VGPR
typedef __attribute__((ext_vector_type(4))) float f32x4;

union U8 { uint4 u; short8v s; };

__device__ __forceinline__ unsigned short f2bf(float f) {
  unsigned u = __float_as_uint(f);
  u += 0x7fff + ((u >> 16) & 1);   // RTNE
  return (unsigned short)(u >> 16);
}
__device__ __forceinline__ unsigned cvtpk(float lo, float hi) {
  unsigned r;
  asm("v_cvt_pk_bf16_f32 %0, %1, %2" : "=v"(r) : "v"(lo), "v"(hi));
  return r;
}

// ---------------- fused f32 -> bf16 weight converts (4 tensors, 1 launch) ----------------
__global__ __launch_bounds__(256) void k_f2h4(const float* __restrict__ s0, short* __restrict__ d0,
                                              const float* __restrict__ s1, short* __restrict__ d1,
                                              const float* __restrict__ s2, short* __restrict__ d2,
                                              const float* __restrict__ s3, short* __restrict__ d3) {
  const int b = blockIdx.x;
  const float* src; short* dst; int i;
  if (b < 384)       { src = s0; dst = d0; i = b * 256 + threadIdx.x; }
  else if (b < 512)  { src = s1; dst = d1; i = (b - 384) * 256 + threadIdx.x; }
  else if (b < 1024) { src = s2; dst = d2; i = (b - 512) * 256 + threadIdx.x; }
  else               { src = s3; dst = d3; i = (b - 1024) * 256 + threadIdx.x; }
  f32x4 a = *(const f32x4*)(src + (size_t)i * 8);
  f32x4 c = *(const f32x4*)(src + (size_t)i * 8 + 4);
  U8 t;
  t.u.x = cvtpk(a[0], a[1]); t.u.y = cvtpk(a[2], a[3]);
  t.u.z = cvtpk(c[0], c[1]); t.u.w = cvtpk(c[2], c[3]);
  *(short8v*)(dst + (size_t)i * 8) = t.s;
}

// ======== QKV GEMM with fused embedding gather (XCD-chunked swizzle) ========
__global__ __launch_bounds__(256, 2) void k_gemm_qkv(const int* __restrict__ sent,
                                                     const float* __restrict__ embed,
                                                     const short* __restrict__ B,
                                                     const float* __restrict__ bias,
                                                     short* __restrict__ C,
                                                     int N, int K) {
  __shared__ __align__(16) short As[2][128 * 64];
  __shared__ __align__(16) short Bs[2][128 * 64];
  const int tid = threadIdx.x;
  const int nwg = gridDim.x * gridDim.y;
  int lin = blockIdx.x + gridDim.x * blockIdx.y;
  int wk = (lin & 7) * (nwg >> 3) + (lin >> 3);   // nwg % 8 == 0
  const int bxs = wk % gridDim.x, bys = wk / gridDim.x;
  const int bm = bys * 128, bn = bxs * 128;
  const int w = tid >> 6, lane = tid & 63;
  const int wr = w >> 1, wc = w & 1;
  const int fr = lane & 15, kg = lane >> 4;
  const int srow = tid >> 1, sc0 = (tid & 1) * 4;
  const int swz = srow & 7;
  const float* gA = embed + (size_t)sent[bm + srow] * K + sc0 * 8;
  const short* gB = B + (size_t)(bn + srow) * K + sc0 * 8;
  f32x4 ra[8];
  short8v rb[4];
  f32x4 acc[4][4] = {};

  auto loadg = [&](int k0) {
#pragma unroll
    for (int c = 0; c < 4; ++c) {
      ra[2 * c] = *(const f32x4*)(gA + k0 + c * 8);
      ra[2 * c + 1] = *(const f32x4*)(gA + k0 + c * 8 + 4);
      rb[c] = *(const short8v*)(gB + k0 + c * 8);
    }
  };
  auto storeb = [&](int b) {
    short* dA = &As[b][srow * 64];
    short* dB = &Bs[b][srow * 64];
#pragma unroll
    for (int c = 0; c < 4; ++c) {
      U8 ta;
      ta.u.x = cvtpk(ra[2 * c][0], ra[2 * c][1]);
      ta.u.y = cvtpk(ra[2 * c][2], ra[2 * c][3]);
      ta.u.z = cvtpk(ra[2 * c + 1][0], ra[2 * c + 1][1]);
      ta.u.w = cvtpk(ra[2 * c + 1][2], ra[2 * c + 1][3]);
      *(short8v*)(dA + (((sc0 + c) ^ swz) << 3)) = ta.s;
      *(short8v*)(dB + (((sc0 + c) ^ swz) << 3)) = rb[c];
    }
  };

  loadg(0);
  storeb(0);
  __syncthreads();
  int cur = 0;
  const int fswz = fr & 7;
  for (int k0 = 0; k0 < K; k0 += 64) {
    const bool more = (k0 + 64) < K;
    if (more) loadg(k0 + 64);
    const short* rA = &As[cur][(wr * 64 + fr) * 64];
    const short* rB = &Bs[cur][(wc * 64 + fr) * 64];
#pragma unroll
    for (int ks = 0; ks < 2; ++ks) {
      const int co = ((ks * 4 + kg) ^ fswz) << 3;
      short8v af[4], bf[4];
#pragma unroll
      for (int rt = 0; rt < 4; ++rt) af[rt] = *(const short8v*)(rA + rt * 16 * 64 + co);
#pragma unroll
      for (int ct = 0; ct < 4; ++ct) bf[ct] = *(const short8v*)(rB + ct * 16 * 64 + co);
#pragma unroll
      for (int rt = 0; rt < 4; ++rt)
#pragma unroll
        for (int ct = 0; ct < 4; ++ct)
          acc[rt][ct] = __builtin_amdgcn_mfma_f32_16x16x32_bf16(af[rt], bf[ct], acc[rt][ct], 0, 0, 0);
    }
    if (more) storeb(cur ^ 1);
    __syncthreads();
    cur ^= 1;
  }
#pragma unroll
  for (int rt = 0; rt < 4; ++rt) {
#pragma unroll
    for (int ct = 0; ct < 4; ++ct) {
      f32x4 v = acc[rt][ct];
      const int row0 = bm + wr * 64 + rt * 16 + kg * 4;
      const int col = bn + wc * 64 + ct * 16 + fr;
      const float bs = bias[col];
#pragma unroll
      for (int j = 0; j < 4; ++j)
        C[(size_t)(row0 + j) * N + col] = (short)f2bf(v[j] + bs);
    }
  }
}

// ======== bf16 MFMA GEMM (XCD-chunked swizzle) ========
template <int RT, bool RELU, bool OBF>
__global__ __launch_bounds__(256, 2) void k_gemm_bf(const short* __restrict__ A,
                                                    const short* __restrict__ B,
                                                    const float* __restrict__ bias,
                                                    void* __restrict__ Cp,
                                                    int M, int N, int K) {
  constexpr int BM = RT * 32;
  constexpr int CH = (BM * 8) / 256;
  __shared__ __align__(16) short As[2][BM * 64];
  __shared__ __align__(16) short Bs[2][BM * 64];
  const int tid = threadIdx.x;
  const int nwg = gridDim.x * gridDim.y;
  int lin = blockIdx.x + gridDim.x * blockIdx.y;
  int wk = (lin & 7) * (nwg >> 3) + (lin >> 3);   // nwg % 8 == 0
  const int bxs = wk % gridDim.x, bys = wk / gridDim.x;
  const int bm = bys * BM, bn = bxs * BM;
  const int w = tid >> 6, lane = tid & 63;
  const int wr = w >> 1, wc = w & 1;
  const int fr = lane & 15, kg = lane >> 4;
  const int srow = (RT == 4) ? (tid >> 1) : (tid >> 2);
  const int sc0 = (RT == 4) ? ((tid & 1) * 4) : ((tid & 3) * 2);
  const int swz = srow & 7;
  const short* gA = A + (size_t)(bm + srow) * K + sc0 * 8;
  const short* gB = B + (size_t)(bn + srow) * K + sc0 * 8;
  short8v ra[CH], rb[CH];
  f32x4 acc[RT][RT] = {};

  auto loadg = [&](int k0) {
#pragma unroll
    for (int c = 0; c < CH; ++c) {
      ra[c] = *(const short8v*)(gA + k0 + c * 8);
      rb[c] = *(const short8v*)(gB + k0 + c * 8);
    }
  };
  auto storeb = [&](int b) {
    short* dA = &As[b][srow * 64];
    short* dB = &Bs[b][srow * 64];
#pragma unroll
    for (int c = 0; c < CH; ++c) {
      *(short8v*)(dA + (((sc0 + c) ^ swz) << 3)) = ra[c];
      *(short8v*)(dB + (((sc0 + c) ^ swz) << 3)) = rb[c];
    }
  };

  loadg(0);
  storeb(0);
  __syncthreads();
  int cur = 0;
  const int fswz = fr & 7;
  for (int k0 = 0; k0 < K; k0 += 64) {
    const bool more = (k0 + 64) < K;
    if (more) loadg(k0 + 64);
    const short* rA = &As[cur][(wr * (RT * 16) + fr) * 64];
    const short* rB = &Bs[cur][(wc * (RT * 16) + fr) * 64];
#pragma unroll
    for (int ks = 0; ks < 2; ++ks) {
      const int co = ((ks * 4 + kg) ^ fswz) << 3;
      short8v af[RT], bf[RT];
#pragma unroll
      for (int rt = 0; rt < RT; ++rt) af[rt] = *(const short8v*)(rA + rt * 16 * 64 + co);
#pragma unroll
      for (int ct = 0; ct < RT; ++ct) bf[ct] = *(const short8v*)(rB + ct * 16 * 64 + co);
#pragma unroll
      for (int rt = 0; rt < RT; ++rt)
#pragma unroll
        for (int ct = 0; ct < RT; ++ct)
          acc[rt][ct] = __builtin_amdgcn_mfma_f32_16x16x32_bf16(af[rt], bf[ct], acc[rt][ct], 0, 0, 0);
    }
    if (more) storeb(cur ^ 1);
    __syncthreads();
    cur ^= 1;
  }
#pragma unroll
  for (int rt = 0; rt < RT; ++rt) {
#pragma unroll
    for (int ct = 0; ct < RT; ++ct) {
      f32x4 v = acc[rt][ct];
      const int row0 = bm + wr * (RT * 16) + rt * 16 + kg * 4;
      const int col = bn + wc * (RT * 16) + ct * 16 + fr;
      const float bs = bias[col];
#pragma unroll
      for (int j = 0; j < 4; ++j) {
        float o = v[j] + bs;
        if (RELU) o = fmaxf(o, 0.f);
        if (OBF)
          ((short*)Cp)[(size_t)(row0 + j) * N + col] = (short)f2bf(o);
        else
          ((float*)Cp)[(size_t)(row0 + j) * N + col] = o;
      }
    }
  }
}

// ======== fused attention v5: exp2-folded softmax ========
// Q pre-scaled by 0.125*log2e once; softmax in log2 units (v_exp_f32 = 2^x).
__global__ __launch_bounds__(256) void k_attn(const short* __restrict__ qkv,
                                              short* __restrict__ ob) {
  __shared__ __align__(16) short Ks[2][64 * 64];
  __shared__ __align__(16) short Vt[2][64 * 72];
  __shared__ __align__(16) short Pl[4][16 * 72];
  const int tid = threadIdx.x;
  const int b = blockIdx.x;
  const int h = b & 7;
  const int bq = (b >> 3) * 64;
  const int wq = tid >> 6, lane = tid & 63;
  const int fr = lane & 15, kg = lane >> 4;
  auto scale8 = [](short8v q) -> short8v {
    unsigned wv[4];
#pragma unroll
    for (int i = 0; i < 4; ++i) {
      float lo = __uint_as_float(((unsigned)(unsigned short)q[2 * i]) << 16) * QSCALE;
      float hi = __uint_as_float(((unsigned)(unsigned short)q[2 * i + 1]) << 16) * QSCALE;
      wv[i] = cvtpk(lo, hi);
    }
    U8 t;
    t.u.x = wv[0]; t.u.y = wv[1]; t.u.z = wv[2]; t.u.w = wv[3];
    return t.s;
  };
  short8v qf[2];
  {
    const short* qsrc = qkv + (size_t)(bq + wq * 16 + fr) * 1536 + h * DH;
    qf[0] = scale8(*(const short8v*)(qsrc + kg * 8));
    qf[1] = scale8(*(const short8v*)(qsrc + 32 + kg * 8));
  }
  float m[4], l[4];
  f32x4 oac[4] = {};
#pragma unroll
  for (int j = 0; j < 4; ++j) { m[j] = -1e30f; l[j] = 0.f; }

  const int srow = tid >> 2, sc0 = (tid & 3) * 2;
  const int kpair = tid & 31, dgrp = tid >> 5;
  short8v kr0, kr1, va, vb;
  auto loadt = [&](int kt) {
    const short* kbase = qkv + (size_t)(kt * 64 + srow) * 1536 + 512 + h * DH;
    kr0 = *(const short8v*)(kbase + sc0 * 8);
    kr1 = *(const short8v*)(kbase + sc0 * 8 + 8);
    const short* vbase = qkv + (size_t)(kt * 64 + 2 * kpair) * 1536 + 1024 + h * DH + dgrp * 8;
    va = *(const short8v*)(vbase);
    vb = *(const short8v*)(vbase + 1536);
  };
  auto storet = [&](int cu) {
    short* dk = &Ks[cu][srow * 64];
    *(short8v*)(dk + ((sc0 ^ (srow & 7)) << 3)) = kr0;
    *(short8v*)(dk + (((sc0 + 1) ^ (srow & 7)) << 3)) = kr1;
#pragma unroll
    for (int i = 0; i < 8; ++i) {
      unsigned u = ((unsigned)(unsigned short)va[i]) |
                   (((unsigned)(unsigned short)vb[i]) << 16);
      *(unsigned*)&Vt[cu][(dgrp * 8 + i) * 72 + 2 * kpair] = u;
    }
  };

  loadt(0);
  int cur = 0;
  for (int kt = 0; kt < 32; ++kt) {
    storet(cur);
    __syncthreads();
    if (kt < 31) loadt(kt + 1);
    f32x4 sac[4] = {};
#pragma unroll
    for (int ks = 0; ks < 2; ++ks) {
#pragma unroll
      for (int ct = 0; ct < 4; ++ct) {
        const int row = ct * 16 + fr;
        short8v bfr = *(const short8v*)&Ks[cur][row * 64 + (((ks * 4 + kg) ^ (row & 7)) << 3)];
        sac[ct] = __builtin_amdgcn_mfma_f32_16x16x32_bf16(qf[ks], bfr, sac[ct], 0, 0, 0);
      }
    }
    // online softmax in log2 units
    float pv[4][4];
#pragma unroll
    for (int j = 0; j < 4; ++j) {
      float v = fmaxf(fmaxf(sac[0][j], sac[1][j]), fmaxf(sac[2][j], sac[3][j]));
#pragma unroll
      for (int off = 1; off < 16; off <<= 1) v = fmaxf(v, __shfl_xor(v, off, 64));
      float mn = fmaxf(m[j], v);
      float f = __builtin_amdgcn_exp2f(m[j] - mn);
      m[j] = mn;
      float rs = 0.f;
#pragma unroll
      for (int ct = 0; ct < 4; ++ct) {
        pv[ct][j] = __builtin_amdgcn_exp2f(sac[ct][j] - mn);
        rs += pv[ct][j];
      }
#pragma unroll
      for (int off = 1; off < 16; off <<= 1) rs += __shfl_xor(rs, off, 64);
      l[j] = l[j] * f + rs;
#pragma unroll
      for (int ct = 0; ct < 4; ++ct) oac[ct][j] *= f;
    }
#pragma unroll
    for (int ct = 0; ct < 4; ++ct)
#pragma unroll
      for (int j = 0; j < 4; ++j)
        Pl[wq][(kg * 4 + j) * 72 + ct * 16 + fr] = (short)f2bf(pv[ct][j]);
#pragma unroll
    for (int ks = 0; ks < 2; ++ks) {
      short8v paf = *(const short8v*)&Pl[wq][fr * 72 + ks * 32 + kg * 8];
#pragma unroll
      for (int ct = 0; ct < 4; ++ct) {
        short8v vf = *(const short8v*)&Vt[cur][(ct * 16 + fr) * 72 + ks * 32 + kg * 8];
        oac[ct] = __builtin_amdgcn_mfma_f32_16x16x32_bf16(paf, vf, oac[ct], 0, 0, 0);
      }
    }
    cur ^= 1;
  }
#pragma unroll
  for (int j = 0; j < 4; ++j) {
    float inv = 1.f / l[j];
    const int q = bq + wq * 16 + kg * 4 + j;
#pragma unroll
    for (int ct = 0; ct < 4; ++ct)
      ob[(size_t)q * D_MODEL + h * DH + ct * 16 + fr] = (short)f2bf(oac[ct][j] * inv);
  }
}

// ---------------- residual + layernorm (ln1: gathered residual, dual output) ----------------
__global__ __launch_bounds__(128) void k_ln(const float* __restrict__ a,
                                            const int* __restrict__ sent,
                                            const float* __restrict__ embed,
                                            const float* __restrict__ r,
                                            const float* __restrict__ g,
                                            const float* __restrict__ b,
                                            float* __restrict__ out,
                                            short* __restrict__ outh) {
  __shared__ float red[2];
  const int row = blockIdx.x, tid = threadIdx.x;
  const size_t off = (size_t)row * D_MODEL + tid * 4;
  float4 av;
  if (sent)
    av = *(const float4*)(embed + (size_t)sent[row] * D_MODEL + tid * 4);
  else
    av = *(const float4*)(a + off);
  float4 rv = *(const float4*)(r + off);
  float v0 = av.x + rv.x, v1 = av.y + rv.y, v2 = av.z + rv.z, v3 = av.w + rv.w;
  float s = v0 + v1 + v2 + v3;
#pragma unroll
  for (int d = 1; d < 64; d <<= 1) s += __shfl_xor(s, d, 64);
  if ((tid & 63) == 0) red[tid >> 6] = s;
  __syncthreads();
  float mean = (red[0] + red[1]) * (1.f / 512.f);
  __syncthreads();
  float d0 = v0 - mean, d1 = v1 - mean, d2 = v2 - mean, d3 = v3 - mean;
  float sq = d0 * d0 + d1 * d1 + d2 * d2 + d3 * d3;
#pragma unroll
  for (int d = 1; d < 64; d <<= 1) sq += __shfl_xor(sq, d, 64);
  if ((tid & 63) == 0) red[tid >> 6] = sq;
  __syncthreads();
  float inv = rsqrtf((red[0] + red[1]) * (1.f / 512.f) + 1e-5f);
  float4 gv = *(const float4*)(g + tid * 4);
  float4 bv = *(const float4*)(b + tid * 4);
  float4 o;
  o.x = d0 * inv * gv.x + bv.x;
  o.y = d1 * inv * gv.y + bv.y;
  o.z = d2 * inv * gv.z + bv.z;
  o.w = d3 * inv * gv.w + bv.w;
  *(float4*)(out + off) = o;
  if (outh) {
    uint2v t;
    t[0] = cvtpk(o.x, o.y);
    t[1] = cvtpk(o.z, o.w);
    *(uint2v*)(outh + off) = t;
  }
}

// ---------------- FUSED ln2 + emission: feats = LN(x1+zb) @ Wt^T + bt ----------------
// LN stays in registers; feats via per-tag dot + 64-lane shuffle reduce.
__global__ __launch_bounds__(128) void k_lnfeats(const float* __restrict__ a,
                                                 const float* __restrict__ r,
                                                 const float* __restrict__ g,
                                                 const float* __restrict__ b,
                                                 const float* __restrict__ Wt,
                                                 const float* __restrict__ bt,
                                                 float* __restrict__ feats) {
  __shared__ float red[2];
  __shared__ float part[2][32];
  const int row = blockIdx.x, tid = threadIdx.x;
  const size_t off = (size_t)row * D_MODEL + tid * 4;
  float4 av = *(const float4*)(a + off);
  float4 rv = *(const float4*)(r + off);
  float v0 = av.x + rv.x, v1 = av.y + rv.y, v2 = av.z + rv.z, v3 = av.w + rv.w;
  float s = v0 + v1 + v2 + v3;
#pragma unroll
  for (int d = 1; d < 64; d <<= 1) s += __shfl_xor(s, d, 64);
  if ((tid & 63) == 0) red[tid >> 6] = s;
  __syncthreads();
  float mean = (red[0] + red[1]) * (1.f / 512.f);
  __syncthreads();
  float d0 = v0 - mean, d1 = v1 - mean, d2 = v2 - mean, d3 = v3 - mean;
  float sq = d0 * d0 + d1 * d1 + d2 * d2 + d3 * d3;
#pragma unroll
  for (int d = 1; d < 64; d <<= 1) sq += __shfl_xor(sq, d, 64);
  if ((tid & 63) == 0) red[tid >> 6] = sq;
  __syncthreads();
  float inv = rsqrtf((red[0] + red[1]) * (1.f / 512.f) + 1e-5f);
  float4 gv = *(const float4*)(g + tid * 4);
  float4 bv = *(const float4*)(b + tid * 4);
  float4 o;
  o.x = d0 * inv * gv.x + bv.x;
  o.y = d1 * inv * gv.y + bv.y;
  o.z = d2 * inv * gv.z + bv.z;
  o.w = d3 * inv * gv.w + bv.w;
  // emission dot products: thread owns cols [4t, 4t+3]
  const int lane = tid & 63, wv = tid >> 6;
#pragma unroll
  for (int l = 0; l < 32; ++l) {
    float4 wr4 = *(const float4*)(Wt + (size_t)l * D_MODEL + tid * 4);
    float p = o.x * wr4.x + o.y * wr4.y + o.z * wr4.z + o.w * wr4.w;
#pragma unroll
    for (int d = 1; d < 64; d <<= 1) p += __shfl_xor(p, d, 64);
    if (lane == 0) part[wv][l] = p;
  }
  __syncthreads();
  if (tid < 32) feats[(size_t)row * L_TAGS + tid] = part[0][tid] + part[1][tid] + bt[tid];
}

// ============ Viterbi via chunked max-plus scan ============
__global__ __launch_bounds__(64) void k_scan1(const float* __restrict__ feats,
                                              const float* __restrict__ T,
                                              float* __restrict__ P) {
  __shared__ float S[2][32];
  const int c = blockIdx.x >> 4;
  const int l = threadIdx.x;
  const int n = l & 31, pl = l >> 5;
  const int p = (blockIdx.x & 15) * 2 + pl;
  float Trow[32];
#pragma unroll
  for (int q = 0; q < 32; ++q) Trow[q] = T[n * 32 + q];
  const int tbase = c * 32;
  float er[4];
#pragma unroll
  for (int i = 0; i < 4; ++i) er[i] = feats[(tbase + i) * 32 + n];
  float a = T[n * 32 + p] + er[0];
  S[pl][n] = a;
  const float* fp = feats + (size_t)(tbase + 4) * 32 + n;
  er[0] = fp[0]; fp += 32;
  for (int u = 1; u < 32; ++u) {
    float e = er[u & 3];
    float enew = fp[0]; fp += 32;
    const float4* Sv = (const float4*)&S[pl][0];
    float g[32];
#pragma unroll
    for (int j4 = 0; j4 < 8; ++j4) {
      float4 sv = Sv[j4];
      g[j4 * 4 + 0] = sv.x + Trow[j4 * 4 + 0];
      g[j4 * 4 + 1] = sv.y + Trow[j4 * 4 + 1];
      g[j4 * 4 + 2] = sv.z + Trow[j4 * 4 + 2];
      g[j4 * 4 + 3] = sv.w + Trow[j4 * 4 + 3];
    }
#pragma unroll
    for (int st = 1; st < 32; st <<= 1)
#pragma unroll
      for (int j = 0; j < 32; j += 2 * st) g[j] = fmaxf(g[j], g[j + st]);
    a = g[0] + e;
    S[pl][n] = a;
    er[u & 3] = enew;
  }
  P[(size_t)c * 1024 + n * 32 + p] = a;
}

__global__ __launch_bounds__(64) void k_scan2(const float* __restrict__ P,
                                              const float* __restrict__ T,
                                              float* __restrict__ alphas,
                                              float* __restrict__ out,
                                              int* __restrict__ bestp) {
  __shared__ float Sa[32];
  const int l = threadIdx.x, n = l & 31, half = l >> 5;
  float a = (n == START_TAG) ? 0.f : NEGV;
  const float* pbase = P + n * 32 + half * 16;
  float4 pr[4];
#pragma unroll
  for (int j = 0; j < 4; ++j) pr[j] = *(const float4*)(pbase + j * 4);
  for (int c = 0; c < 64; ++c) {
    float4 nx[4];
#pragma unroll
    for (int j = 0; j < 4; ++j)
      nx[j] = *(const float4*)(pbase + (size_t)(c + 1) * 1024 + j * 4);
    alphas[(size_t)(c * 32) * 32 + n] = a;
    Sa[n] = a;
    const float4* Sv = (const float4*)&Sa[half * 16];
    float g[16];
#pragma unroll
    for (int j = 0; j < 4; ++j) {
      float4 sv = Sv[j];
      g[j * 4 + 0] = pr[j].x + sv.x;
      g[j * 4 + 1] = pr[j].y + sv.y;
      g[j * 4 + 2] = pr[j].z + sv.z;
      g[j * 4 + 3] = pr[j].w + sv.w;
    }
#pragma unroll
    for (int st = 1; st < 16; st <<= 1)
#pragma unroll
      for (int j = 0; j < 16; j += 2 * st) g[j] = fmaxf(g[j], g[j + st]);
    uint2v r = __builtin_amdgcn_permlane32_swap(__float_as_uint(g[0]),
                                                __float_as_uint(g[0]), false, false);
    a = fmaxf(__uint_as_float(r[0]), __uint_as_float(r[1]));
#pragma unroll
    for (int j = 0; j < 4; ++j) pr[j] = nx[j];
  }
  float term = a + T[STOP_TAG * 32 + n];
  float bv = term;
  int bi = n;
#pragma unroll
  for (int d = 1; d < 32; d <<= 1) {
    float ov = __shfl_xor(bv, d, 64);
    int oi = __shfl_xor(bi, d, 64);
    if (ov > bv || (ov == bv && oi < bi)) { bv = ov; bi = oi; }
  }
  if (l == 0) { out[0] = bv; *bestp = bi; }
}

// phase 3 FUSED: per-chunk alphas + backpointers + candidate walk.
__global__ __launch_bounds__(64) void k_scan3(const float* __restrict__ feats,
                                              const float* __restrict__ T,
                                              const float* __restrict__ alphas,
                                              unsigned char* __restrict__ cand,
                                              unsigned char* __restrict__ amap) {
  __shared__ float Sa[32];
  __shared__ unsigned char bpl[32][32];
  __shared__ unsigned cnd[256];
  const int c = blockIdx.x, l = threadIdx.x, n = l & 31, half = l >> 5;
  float Tr[16];
#pragma unroll
  for (int j = 0; j < 16; ++j) Tr[j] = T[n * 32 + half * 16 + j];
  const int tbase = c * 32;
  float a = alphas[(size_t)tbase * 32 + n];
  float er[4];
#pragma unroll
  for (int i = 0; i < 4; ++i) er[i] = feats[(tbase + i) * 32 + n];
  const float* fp = feats + (size_t)(tbase + 4) * 32 + n;
  Sa[n] = a;
  for (int u = 0; u < 32; ++u) {
    float e = er[u & 3];
    float enew = fp[0]; fp += 32;
    const float4* Sv = (const float4*)&Sa[half * 16];
    float4 s0 = Sv[0], s1 = Sv[1], s2 = Sv[2], s3 = Sv[3];
    float v[16] = {s0.x + Tr[0],  s0.y + Tr[1],  s0.z + Tr[2],  s0.w + Tr[3],
                   s1.x + Tr[4],  s1.y + Tr[5],  s1.z + Tr[6],  s1.w + Tr[7],
                   s2.x + Tr[8],  s2.y + Tr[9],  s2.z + Tr[10], s2.w + Tr[11],
                   s3.x + Tr[12], s3.y + Tr[13], s3.z + Tr[14], s3.w + Tr[15]};
    int id[16];
#pragma unroll
    for (int j = 0; j < 16; ++j) id[j] = half * 16 + j;
#pragma unroll
    for (int st = 1; st < 16; st <<= 1)
#pragma unroll
      for (int j = 0; j < 16; j += 2 * st)
        if (v[j + st] > v[j]) { v[j] = v[j + st]; id[j] = id[j + st]; }
    uint2v rv = __builtin_amdgcn_permlane32_swap(__float_as_uint(v[0]),
                                                 __float_as_uint(v[0]), false, false);
    uint2v ri = __builtin_amdgcn_permlane32_swap((unsigned)id[0], (unsigned)id[0],
                                                 false, false);
    float v0 = __uint_as_float(rv[0]), v1 = __uint_as_float(rv[1]);
    int i0 = (int)ri[0], i1 = (int)ri[1];
    float wvv = (v1 > v0) ? v1 : v0;
    int wi = (v1 > v0) ? i1 : i0;
    bpl[u][n] = (unsigned char)wi;
    a = wvv + e;
    Sa[n] = a;
    er[u & 3] = enew;
  }
  unsigned char* cnb = (unsigned char*)cnd;
  int tg = n;
  cnb[n * 32 + 31] = (unsigned char)n;
  for (int j = 31; j >= 1; --j) {
    tg = bpl[j][tg];
    cnb[n * 32 + (j - 1)] = (unsigned char)tg;
  }
  if (half == 0) amap[c * 32 + n] = bpl[0][tg];
#pragma unroll
  for (int i = 0; i < 4; ++i)
    ((unsigned*)(cand + (size_t)c * 1024))[l * 4 + i] = cnd[l * 4 + i];
}

// traceback: compose chunk maps + emit path.
__global__ __launch_bounds__(256) void k_trace2(const unsigned char* __restrict__ amap,
                                                const unsigned char* __restrict__ cand,
                                                const int* __restrict__ bestp,
                                                float* __restrict__ outp) {
  __shared__ unsigned char Am[64][32];
  __shared__ unsigned char et[64];
  const int tid = threadIdx.x;
  ((unsigned*)&Am[0][0])[tid] = ((const unsigned*)amap)[tid];
  ((unsigned*)&Am[32][0])[tid] = ((const unsigned*)amap)[tid + 256];
  __syncthreads();
  for (int d = 1; d < 64; d <<= 1) {
    unsigned char tmpv[8];
#pragma unroll
    for (int i = 0; i < 8; ++i) {
      int id = tid + 256 * i;
      int cc = id >> 5, e = id & 31;
      tmpv[i] = (cc + d < 64) ? Am[cc][Am[cc + d][e]] : Am[cc][e];
    }
    __syncthreads();
#pragma unroll
    for (int i = 0; i < 8; ++i) {
      int id = tid + 256 * i;
      Am[id >> 5][id & 31] = tmpv[i];
    }
    __syncthreads();
  }
  const int best = *bestp;
  if (tid < 64) et[tid] = (tid == 63) ? (unsigned char)best : Am[tid + 1][best];
  __syncthreads();
#pragma unroll
  for (int i = 0; i < 8; ++i) {
    int t = tid + 256 * i;
    int cc = t >> 5, j = t & 31;
    outp[1 + t] = (float)cand[(size_t)cc * 1024 + (size_t)et[cc] * 32 + j];
  }
}

extern "C" void kernel_launch(void* const* d_in, const int* in_sizes, int n_in,
                              void* d_out, int out_size, void* d_ws, size_t ws_size,
                              hipStream_t stream) {
  (void)in_sizes; (void)n_in; (void)out_size; (void)ws_size;
  const int* sent = (const int*)d_in[0];
  const float* embed = (const float*)d_in[1];
  const float* Wqkv = (const float*)d_in[2];
  const float* bqkv = (const float*)d_in[3];
  const float* Wo = (const float*)d_in[4];
  const float* bo = (const float*)d_in[5];
  const float* g1 = (const float*)d_in[6];
  const float* b1n = (const float*)d_in[7];
  const float* W1 = (const float*)d_in[8];
  const float* b1f = (const float*)d_in[9];
  const float* W2 = (const float*)d_in[10];
  const float* b2f = (const float*)d_in[11];
  const float* g2 = (const float*)d_in[12];
  const float* b2n = (const float*)d_in[13];
  const float* Wt = (const float*)d_in[14];
  const float* bt = (const float*)d_in[15];
  const float* T = (const float*)d_in[16];
  float* out = (float*)d_out;

  float* ws = (float*)d_ws;
  const size_t M1 = 1u << 20;  // 1M floats = 4MB
  short* qkvh = (short*)ws;                 // bf16 [2048][1536]
  short* obh = (short*)(ws + 2 * M1);       // bf16 [2048][512]
  float* yb = ws + 3 * M1;                  // f32  [2048][512]
  float* x1 = ws + 4 * M1;                  // f32
  short* x1h = (short*)(ws + 5 * M1);       // bf16
  short* ffbh = (short*)(ws + 6 * M1);      // bf16 [2048][2048]
  float* zb = ws + 8 * M1;                  // f32
  short* wqkvh = (short*)(ws + 10 * M1);
  short* woh = wqkvh + 786432;
  short* w1h = woh + 262144;
  short* w2h = w1h + 1048576;
  float* feats = ws + 11 * M1;
  float* alphas = feats + 2048 * 32 + 64;
  float* P = alphas + 2049 * 32 + 64;
  int* bestp = (int*)(P + 65 * 1024 + 64);
  unsigned char* cand = (unsigned char*)(bestp + 64);
  unsigned char* amap = cand + 2048 * 32;

  k_f2h4<<<dim3(1536), dim3(256), 0, stream>>>(Wqkv, wqkvh, Wo, woh, W1, w1h, W2, w2h);
  k_gemm_qkv<<<dim3(12, 16), dim3(256), 0, stream>>>(sent, embed, wqkvh, bqkv, qkvh, 1536, 512);
  k_attn<<<dim3(256), dim3(256), 0, stream>>>(qkvh, obh);
  k_gemm_bf<2, false, false><<<dim3(8, 32), dim3(256), 0, stream>>>(obh, woh, bo, yb, 2048, 512, 512);
  k_ln<<<dim3(2048), dim3(128), 0, stream>>>(nullptr, sent, embed, yb, g1, b1n, x1, x1h);
  k_gemm_bf<4, true, true><<<dim3(16, 16), dim3(256), 0, stream>>>(x1h, w1h, b1f, ffbh, 2048, 2048, 512);
  k_gemm_bf<2, false, false><<<dim3(8, 32), dim3(256), 0, stream>>>(ffbh, w2h, b2f, zb, 2048, 512, 2048);
  k_lnfeats<<<dim3(2048), dim3(128), 0, stream>>>(x1, zb, g2, b2n, Wt, bt, feats);
  k_scan1<<<dim3(1024), dim3(64), 0, stream>>>(feats, T, P);
  k_scan2<<<dim3(1), dim3(64), 0, stream>>>(P, T, alphas, out, bestp);
  k_scan3<<<dim3(64), dim3(64), 0, stream>>>(feats, T, alphas, cand, amap);
  k_trace2<<<dim3(1), dim3(256), 0, stream>>>(amap, cand, bestp, out);
}